// Round 10
// baseline (491.150 us; speedup 1.0000x reference)
//
#include <hip/hip_runtime.h>

typedef unsigned short u16;
typedef unsigned int u32;

using bfrag  = __attribute__((ext_vector_type(8))) short;   // 8 bf16 (4 VGPRs)
using f32x4  = __attribute__((ext_vector_type(4))) float;   // 4 fp32 acc
using f32x16 = __attribute__((ext_vector_type(16))) float;  // 16 fp32 acc (32x32 MFMA)

// ---------- bf16 / f16 helpers ----------
__device__ __forceinline__ float b2f(u16 u) {
  union { u32 i; float f; } c; c.i = ((u32)u) << 16; return c.f;
}
__device__ __forceinline__ float bflo(u32 u) { union { u32 i; float f; } c; c.i = u << 16; return c.f; }
__device__ __forceinline__ float bfhi(u32 u) { union { u32 i; float f; } c; c.i = u & 0xffff0000u; return c.f; }
__device__ __forceinline__ u16 f2b(float f) {  // round-to-nearest-even
  union { float f; u32 i; } c; c.f = f;
  u32 x = c.i;
  u32 r = x + 0x7fffu + ((x >> 16) & 1u);
  return (u16)(r >> 16);
}
__device__ __forceinline__ u32 packb2(float x, float y) {
  return ((u32)f2b(x)) | (((u32)f2b(y)) << 16);
}
__device__ __forceinline__ u16 f2h(float x) {
  union { _Float16 h; u16 u; } c; c.h = (_Float16)x; return c.u;
}
__device__ __forceinline__ float h2lo(u32 u) { union { u32 i; _Float16 h[2]; } c; c.i = u; return (float)c.h[0]; }
__device__ __forceinline__ float h2hi(u32 u) { union { u32 i; _Float16 h[2]; } c; c.i = u; return (float)c.h[1]; }
__device__ __forceinline__ int rfl(int v) { return __builtin_amdgcn_readfirstlane(v); }

// ---------- CSR build ----------
__global__ __launch_bounds__(256) void count_deg(const int* __restrict__ eidx,
                                                 int* __restrict__ degi, int E) {
  int e = blockIdx.x * 256 + threadIdx.x;
  if (e >= E) return;
  atomicAdd(&degi[eidx[E + e]], 1);
  atomicAdd(&degi[eidx[e]], 1);
}

__global__ __launch_bounds__(256) void scan1(const int* __restrict__ degi,
                                             int* __restrict__ bsum, int N) {
  __shared__ int sh[256];
  int t = threadIdx.x;
  int gid = blockIdx.x * 256 + t;
  sh[t] = (gid < N) ? degi[gid] : 0;
  __syncthreads();
  for (int off = 128; off > 0; off >>= 1) {
    if (t < off) sh[t] += sh[t + off];
    __syncthreads();
  }
  if (t == 0) bsum[blockIdx.x] = sh[0];
}

__global__ __launch_bounds__(256) void scan2(int* __restrict__ bsum,
                                             int* __restrict__ rowptr, int nb, int N) {
  __shared__ int sh[256];
  int t = threadIdx.x;
  int v = (t < nb) ? bsum[t] : 0;
  sh[t] = v;
  __syncthreads();
  for (int off = 1; off < 256; off <<= 1) {
    int x = sh[t];
    int add = (t >= off) ? sh[t - off] : 0;
    __syncthreads();
    sh[t] = x + add;
    __syncthreads();
  }
  if (t < nb) bsum[t] = sh[t] - v;
  if (t == nb - 1) rowptr[N] = sh[t];
}

__global__ __launch_bounds__(256) void scan3(const int* __restrict__ degi,
                                             const int* __restrict__ bsum,
                                             int* __restrict__ rowptr,
                                             int* __restrict__ cursor,
                                             float* __restrict__ dis, int N) {
  __shared__ int sh[256];
  int t = threadIdx.x;
  int gid = blockIdx.x * 256 + t;
  int d = (gid < N) ? degi[gid] : 0;
  sh[t] = d;
  __syncthreads();
  for (int off = 1; off < 256; off <<= 1) {
    int x = sh[t];
    int add = (t >= off) ? sh[t - off] : 0;
    __syncthreads();
    sh[t] = x + add;
    __syncthreads();
  }
  if (gid < N) {
    int run = bsum[blockIdx.x] + sh[t] - d;
    rowptr[gid] = run;
    cursor[gid] = run;
    dis[gid] = d > 0 ? rsqrtf((float)d) : 0.0f;
  }
}

__global__ __launch_bounds__(256) void fill_csr(const int* __restrict__ eidx,
                                                int* __restrict__ cursor,
                                                const float* __restrict__ dis,
                                                int2* __restrict__ cw,
                                                int2* __restrict__ ce, int E) {
  int i = blockIdx.x * 256 + threadIdx.x;
  int E2 = 2 * E;
  if (i >= E2) return;
  int e = (i < E) ? i : i - E;
  int s, d;
  if (i < E) { s = eidx[e]; d = eidx[E + e]; }
  else       { s = eidx[E + e]; d = eidx[e]; }
  int pos = atomicAdd(&cursor[d], 1);
  cw[pos] = make_int2(s, __float_as_int(dis[s]));
  ce[pos] = make_int2(s, e);
}

// ---------- weight prep: 14x fp32 [128][128] -> bf16 [n][k]; also zeros degi ----------
__global__ __launch_bounds__(256) void prep_wt(
    const float* __restrict__ ea0_w2, const float* __restrict__ tag0_w,
    const float* __restrict__ ea1_w1, const float* __restrict__ ea1_w2,
    const float* __restrict__ tag1_w, const float* __restrict__ ea2_w1,
    u16* __restrict__ Wt, int* __restrict__ degi, int N) {
  int gid = blockIdx.x * 256 + threadIdx.x;
  if (gid < N) degi[gid] = 0;
  int mat = blockIdx.x >> 3, chunk = blockIdx.x & 7;
  const float* src;
  if      (mat == 0)  src = ea0_w2;
  else if (mat <= 4)  src = tag0_w + (mat - 1) * 16384;
  else if (mat == 5)  src = ea1_w1;
  else if (mat == 6)  src = ea1_w1 + 16384;
  else if (mat == 7)  src = ea1_w2;
  else if (mat <= 11) src = tag1_w + (mat - 8) * 16384;
  else if (mat == 12) src = ea2_w1;
  else                src = ea2_w1 + 16384;
  u16* dst = Wt + mat * 16384;
  int t = threadIdx.x;
  for (int i = 0; i < 8; ++i) {
    int idx = chunk * 2048 + i * 256 + t;
    int k = idx >> 7, n = idx & 127;
    dst[n * 128 + k] = f2b(src[idx]);
  }
}

__global__ __launch_bounds__(256) void prep_wt_ea(
    const float* __restrict__ wA, const float* __restrict__ wB,
    const float* __restrict__ wC, u16* __restrict__ W3) {
  int tab = blockIdx.x;
  const float* src = (tab == 0) ? wA : (tab == 1) ? wB : wC;
  u16* dst = W3 + tab * 2048;
  int t = threadIdx.x;
  for (int i = 0; i < 8; ++i) {
    int idx = i * 256 + t;
    int n = idx >> 4, k = idx & 15;
    dst[idx] = f2b(src[k * 128 + n]);
  }
}

// ---------- edge projection via MFMA 32x32x16: P_l[e,:] = ea[e,:16] @ W_l  (f16) ----------
__global__ __launch_bounds__(256) void ea_proj_mfma(
    const float* __restrict__ ea, const u16* __restrict__ W3,
    u16* __restrict__ P0, u16* __restrict__ P1, u16* __restrict__ P2, int E) {
  __shared__ u16 Alds[64 * 16];
  __shared__ u16 Wlds[3 * 2048];
  int t = threadIdx.x;
  int base = blockIdx.x * 64;
  int rows = E - base; if (rows > 64) rows = 64;
#pragma unroll
  for (int i = 0; i < 3; ++i)
    *(uint4*)(Wlds + (i * 256 + t) * 8) = *(const uint4*)(W3 + (i * 256 + t) * 8);
#pragma unroll
  for (int i = 0; i < 4; ++i) {
    int idx = (i * 256 + t) * 4;
    float4 v = make_float4(0.f, 0.f, 0.f, 0.f);
    if ((idx >> 4) < rows) v = *(const float4*)(ea + (size_t)base * 16 + idx);
    ushort4 h;
    h.x = f2b(v.x); h.y = f2b(v.y); h.z = f2b(v.z); h.w = f2b(v.w);
    *(ushort4*)(Alds + idx) = h;
  }
  __syncthreads();
  int wave = t >> 6, lane = t & 63;
  int rowt = (wave >> 1) * 32;
  int colt = (wave & 1) * 64;
  int mm = lane & 31, kh = lane >> 5;
  bfrag a = *(const bfrag*)(Alds + (rowt + mm) * 16 + kh * 8);
#pragma unroll
  for (int tab = 0; tab < 3; ++tab) {
    const u16* wl = Wlds + tab * 2048;
    bfrag b0 = *(const bfrag*)(wl + (colt + mm) * 16 + kh * 8);
    bfrag b1 = *(const bfrag*)(wl + (colt + 32 + mm) * 16 + kh * 8);
    f32x16 acc0, acc1;
#pragma unroll
    for (int z = 0; z < 16; ++z) { acc0[z] = 0.f; acc1[z] = 0.f; }
    acc0 = __builtin_amdgcn_mfma_f32_32x32x16_bf16(a, b0, acc0, 0, 0, 0);
    acc1 = __builtin_amdgcn_mfma_f32_32x32x16_bf16(a, b1, acc1, 0, 0, 0);
    u16* P = (tab == 0) ? P0 : (tab == 1) ? P1 : P2;
#pragma unroll
    for (int reg = 0; reg < 16; ++reg) {
      int row = rowt + (reg & 3) + 8 * (reg >> 2) + 4 * kh;
      if (row < rows) {
        size_t off = (size_t)(base + row) * 128;
        P[off + colt + mm]      = f2h(acc0[reg]);
        P[off + colt + 32 + mm] = f2h(acc1[reg]);
      }
    }
  }
}

// ---------- fused head: h16 = relu(mask@w1+b1)@w2 + b2 + x;  pb = h16@Wd + b1', q = h16@Ws ----------
__global__ __launch_bounds__(128) void gemm_head(
    const float* __restrict__ mask, const float* __restrict__ x,
    const float* __restrict__ m_w1, const float* __restrict__ m_b1,
    const float* __restrict__ m_w2, const float* __restrict__ m_b2,
    const float* __restrict__ ea0_w1, const float* __restrict__ ea0_b1,
    u16* __restrict__ pb, u16* __restrict__ q, int M) {
  const int ROWS = 8;
  int t = threadIdx.x;
  int base = blockIdx.x * ROWS;
  __shared__ float Ml[ROWS * 16];
  __shared__ float T1[ROWS * 128];
  __shared__ float H[ROWS * 16];
  for (int i = t; i < ROWS * 16; i += 128) {
    int r = i >> 4, k = i & 15;
    int row = base + r;
    Ml[i] = (row < M) ? mask[(size_t)row * 16 + k] : 0.f;
  }
  __syncthreads();
  {
    float acc[ROWS];
#pragma unroll
    for (int r = 0; r < ROWS; ++r) acc[r] = m_b1[t];
    for (int k = 0; k < 16; ++k) {
      float w = m_w1[k * 128 + t];
#pragma unroll
      for (int r = 0; r < ROWS; ++r) acc[r] += Ml[r * 16 + k] * w;
    }
#pragma unroll
    for (int r = 0; r < ROWS; ++r) T1[r * 128 + t] = fmaxf(acc[r], 0.f);
  }
  __syncthreads();
  {
    int r = t >> 4, u = t & 15;
    float acc = m_b2[u];
    for (int k = 0; k < 128; ++k) acc += T1[r * 128 + k] * m_w2[k * 16 + u];
    int row = base + r;
    float xv = (row < M) ? x[(size_t)row * 16 + u] : 0.f;
    H[r * 16 + u] = acc + xv;
  }
  __syncthreads();
  {
    float aP[ROWS], aQ[ROWS];
    float b1v = ea0_b1[t];
#pragma unroll
    for (int r = 0; r < ROWS; ++r) { aP[r] = b1v; aQ[r] = 0.f; }
    for (int k = 0; k < 16; ++k) {
      float wd = ea0_w1[k * 128 + t];
      float ws = ea0_w1[(16 + k) * 128 + t];
#pragma unroll
      for (int r = 0; r < ROWS; ++r) {
        float h = H[r * 16 + k];
        aP[r] += h * wd;
        aQ[r] += h * ws;
      }
    }
#pragma unroll
    for (int r = 0; r < ROWS; ++r) {
      int row = base + r;
      if (row < M) {
        pb[(size_t)row * 128 + t] = f2b(aP[r]);
        q[(size_t)row * 128 + t]  = f2b(aQ[r]);
      }
    }
  }
}

// ---------- MFMA GEMM: C[M,128] = A[M,128]bf16 @ W (+bias/deg*bias +relu) ----------
template<bool OUTBF16>
__global__ __launch_bounds__(256) void gemm_mfma(
    const u16* __restrict__ A, const u16* __restrict__ Wt,
    void* __restrict__ Cout, const float* __restrict__ bias,
    const int* __restrict__ degi, int M, int relu) {
  __shared__ u16 Alds[64 * 136];
  __shared__ u16 Wlds[128 * 136];
  int t = threadIdx.x;
  int base = blockIdx.x * 64;
#pragma unroll
  for (int i = 0; i < 8; ++i) {
    int idx = (i * 256 + t) * 8;
    int n = idx >> 7, k = idx & 127;
    uint4 v = *(const uint4*)(Wt + idx);
    *(uint4*)(Wlds + n * 136 + k) = v;
  }
#pragma unroll
  for (int i = 0; i < 4; ++i) {
    int idx = (i * 256 + t) * 8;
    int r = idx >> 7, k = idx & 127;
    int row = base + r;
    uint4 v = make_uint4(0, 0, 0, 0);
    if (row < M) v = *(const uint4*)(A + (size_t)row * 128 + k);
    *(uint4*)(Alds + r * 136 + k) = v;
  }
  __syncthreads();
  int wave = t >> 6, lane = t & 63;
  int m = lane & 15, quad = lane >> 4;
  int arow = wave * 16 + m;
  bfrag a[4];
#pragma unroll
  for (int ks = 0; ks < 4; ++ks)
    a[ks] = *(const bfrag*)(Alds + arow * 136 + ks * 32 + quad * 8);
  f32x4 acc[8];
#pragma unroll
  for (int nt = 0; nt < 8; ++nt) acc[nt] = (f32x4){0.f, 0.f, 0.f, 0.f};
#pragma unroll
  for (int nt = 0; nt < 8; ++nt) {
    int n = nt * 16 + m;
#pragma unroll
    for (int ks = 0; ks < 4; ++ks) {
      bfrag b = *(const bfrag*)(Wlds + n * 136 + ks * 32 + quad * 8);
      acc[nt] = __builtin_amdgcn_mfma_f32_16x16x32_bf16(a[ks], b, acc[nt], 0, 0, 0);
    }
  }
#pragma unroll
  for (int nt = 0; nt < 8; ++nt) {
    int col = nt * 16 + m;
#pragma unroll
    for (int r = 0; r < 4; ++r) {
      int row = base + wave * 16 + quad * 4 + r;
      if (row < M) {
        float v = acc[nt][r];
        if (bias) { float b = bias[col]; v += degi ? b * (float)degi[row] : b; }
        if (relu) v = fmaxf(v, 0.f);
        if (OUTBF16) ((u16*)Cout)[(size_t)row * 128 + col] = f2b(v);
        else         ((float*)Cout)[(size_t)row * 128 + col] = v;
      }
    }
  }
}

// ---------- dual MFMA GEMM: C0 = A@W0 (+bias0), C1 = A@W1 (both bf16) ----------
__global__ __launch_bounds__(256) void gemm_mfma_dual(
    const u16* __restrict__ A, const u16* __restrict__ W0t, const u16* __restrict__ W1t,
    u16* __restrict__ C0, u16* __restrict__ C1, const float* __restrict__ bias0, int M) {
  __shared__ u16 Alds[64 * 136];
  __shared__ u16 Wlds[128 * 136];
  int t = threadIdx.x;
  int base = blockIdx.x * 64;
#pragma unroll
  for (int i = 0; i < 8; ++i) {
    int idx = (i * 256 + t) * 8;
    int n = idx >> 7, k = idx & 127;
    uint4 v = *(const uint4*)(W0t + idx);
    *(uint4*)(Wlds + n * 136 + k) = v;
  }
#pragma unroll
  for (int i = 0; i < 4; ++i) {
    int idx = (i * 256 + t) * 8;
    int r = idx >> 7, k = idx & 127;
    int row = base + r;
    uint4 v = make_uint4(0, 0, 0, 0);
    if (row < M) v = *(const uint4*)(A + (size_t)row * 128 + k);
    *(uint4*)(Alds + r * 136 + k) = v;
  }
  __syncthreads();
  int wave = t >> 6, lane = t & 63;
  int m = lane & 15, quad = lane >> 4;
  int arow = wave * 16 + m;
  bfrag a[4];
#pragma unroll
  for (int ks = 0; ks < 4; ++ks)
    a[ks] = *(const bfrag*)(Alds + arow * 136 + ks * 32 + quad * 8);
  f32x4 acc0[8], acc1[8];
#pragma unroll
  for (int nt = 0; nt < 8; ++nt) { acc0[nt] = (f32x4){0,0,0,0}; acc1[nt] = (f32x4){0,0,0,0}; }
#pragma unroll
  for (int nt = 0; nt < 8; ++nt) {
    int n = nt * 16 + m;
#pragma unroll
    for (int ks = 0; ks < 4; ++ks) {
      bfrag b = *(const bfrag*)(Wlds + n * 136 + ks * 32 + quad * 8);
      acc0[nt] = __builtin_amdgcn_mfma_f32_16x16x32_bf16(a[ks], b, acc0[nt], 0, 0, 0);
    }
  }
  __syncthreads();
#pragma unroll
  for (int i = 0; i < 8; ++i) {
    int idx = (i * 256 + t) * 8;
    int n = idx >> 7, k = idx & 127;
    uint4 v = *(const uint4*)(W1t + idx);
    *(uint4*)(Wlds + n * 136 + k) = v;
  }
  __syncthreads();
#pragma unroll
  for (int nt = 0; nt < 8; ++nt) {
    int n = nt * 16 + m;
#pragma unroll
    for (int ks = 0; ks < 4; ++ks) {
      bfrag b = *(const bfrag*)(Wlds + n * 136 + ks * 32 + quad * 8);
      acc1[nt] = __builtin_amdgcn_mfma_f32_16x16x32_bf16(a[ks], b, acc1[nt], 0, 0, 0);
    }
  }
#pragma unroll
  for (int nt = 0; nt < 8; ++nt) {
    int col = nt * 16 + m;
#pragma unroll
    for (int r = 0; r < 4; ++r) {
      int row = base + wave * 16 + quad * 4 + r;
      if (row < M) {
        float v0 = acc0[nt][r];
        if (bias0) v0 += bias0[col];
        C0[(size_t)row * 128 + col] = f2b(v0);
        C1[(size_t)row * 128 + col] = f2b(acc1[nt][r]);
      }
    }
  }
}

// ---------- quad MFMA GEMM (TAG): G_k = A @ W_k, k=0..3 ----------
__global__ __launch_bounds__(256) void gemm_mfma_quad(
    const u16* __restrict__ A, const u16* __restrict__ Wt4,
    u16* __restrict__ G0, u16* __restrict__ G1,
    u16* __restrict__ G2, u16* __restrict__ G3, int M) {
  __shared__ u16 Alds[64 * 136];
  __shared__ u16 Wlds[128 * 136];
  int t = threadIdx.x;
  int base = blockIdx.x * 64;
#pragma unroll
  for (int i = 0; i < 4; ++i) {
    int idx = (i * 256 + t) * 8;
    int r = idx >> 7, k = idx & 127;
    int row = base + r;
    uint4 v = make_uint4(0, 0, 0, 0);
    if (row < M) v = *(const uint4*)(A + (size_t)row * 128 + k);
    *(uint4*)(Alds + r * 136 + k) = v;
  }
  __syncthreads();
  int wave = t >> 6, lane = t & 63;
  int m = lane & 15, quad = lane >> 4;
  int arow = wave * 16 + m;
  bfrag a[4];
#pragma unroll
  for (int ks = 0; ks < 4; ++ks)
    a[ks] = *(const bfrag*)(Alds + arow * 136 + ks * 32 + quad * 8);
#pragma unroll
  for (int mat = 0; mat < 4; ++mat) {
    __syncthreads();
#pragma unroll
    for (int i = 0; i < 8; ++i) {
      int idx = (i * 256 + t) * 8;
      int n = idx >> 7, k = idx & 127;
      uint4 v = *(const uint4*)(Wt4 + mat * 16384 + idx);
      *(uint4*)(Wlds + n * 136 + k) = v;
    }
    __syncthreads();
    f32x4 acc[8];
#pragma unroll
    for (int nt = 0; nt < 8; ++nt) acc[nt] = (f32x4){0.f, 0.f, 0.f, 0.f};
#pragma unroll
    for (int nt = 0; nt < 8; ++nt) {
      int n = nt * 16 + m;
#pragma unroll
      for (int ks = 0; ks < 4; ++ks) {
        bfrag b = *(const bfrag*)(Wlds + n * 136 + ks * 32 + quad * 8);
        acc[nt] = __builtin_amdgcn_mfma_f32_16x16x32_bf16(a[ks], b, acc[nt], 0, 0, 0);
      }
    }
    u16* G = (mat == 0) ? G0 : (mat == 1) ? G1 : (mat == 2) ? G2 : G3;
#pragma unroll
    for (int nt = 0; nt < 8; ++nt) {
      int col = nt * 16 + m;
#pragma unroll
      for (int r = 0; r < 4; ++r) {
        int row = base + wave * 16 + quad * 4 + r;
        if (row < M) G[(size_t)row * 128 + col] = f2b(acc[nt][r]);
      }
    }
  }
}

// ---------- VALU GEMM (final 128->16) ----------
__global__ __launch_bounds__(128) void gemm_tail(
    const u16* __restrict__ A, const float* __restrict__ W, float* __restrict__ Cout,
    const float* __restrict__ bias, const int* __restrict__ degi, int M) {
  const int ROWS = 8;
  int t = threadIdx.x;
  int base = blockIdx.x * ROWS;
  __shared__ float Al[ROWS * 128];
  for (int i = t; i < ROWS * 128; i += 128) {
    int r = i >> 7, k = i & 127;
    int row = base + r;
    Al[i] = (row < M) ? b2f(A[(size_t)row * 128 + k]) : 0.f;
  }
  __syncthreads();
  int r = t >> 4, u = t & 15;
  int row = base + r;
  float acc = 0.f;
  for (int k = 0; k < 128; ++k) acc += Al[r * 128 + k] * W[k * 16 + u];
  if (row < M) {
    Cout[(size_t)row * 16 + u] = acc + bias[u] * (float)degi[row];
  }
}

// ---------- TAG gather v6: 2 waves/node (edge-range split) + LDS combine ----------
// out[n] = Cin[n] + dis[n] * sum_e w_e * g[src_e]   (+bias, relu if FINAL)
template<bool FINAL>
__global__ __launch_bounds__(256) void tag_gather6(
    const u16* __restrict__ g, const u16* __restrict__ Cin,
    const float* __restrict__ bias, const float* __restrict__ dis,
    const int* __restrict__ rowptr, const int2* __restrict__ cw,
    u16* __restrict__ out, int N) {
  __shared__ float part[4][128];
  int wave = threadIdx.x >> 6, lane = threadIdx.x & 63;
  int node = blockIdx.x * 2 + (wave >> 1);
  int h = wave & 1;
  float a0 = 0, a1 = 0, b0 = 0, b1 = 0;
  int e = 0, e1 = 0;
  if (node < N) {
    int s = rfl(rowptr[node]);
    int t = rfl(rowptr[node + 1]);
    int mid = (s + t) >> 1;
    e  = h ? mid : s;
    e1 = h ? t : mid;
  }
  for (; e + 4 <= e1; e += 4) {
    int4 r01 = *(const int4*)(cw + e);
    int4 r23 = *(const int4*)(cw + e + 2);
    int s0 = rfl(r01.x); float w0 = __uint_as_float(rfl(r01.y));
    int s1 = rfl(r01.z); float w1 = __uint_as_float(rfl(r01.w));
    int s2 = rfl(r23.x); float w2 = __uint_as_float(rfl(r23.y));
    int s3 = rfl(r23.z); float w3 = __uint_as_float(rfl(r23.w));
    u32 h0 = *((const u32*)(g + (size_t)s0 * 128) + lane);
    u32 h1 = *((const u32*)(g + (size_t)s1 * 128) + lane);
    u32 h2 = *((const u32*)(g + (size_t)s2 * 128) + lane);
    u32 h3 = *((const u32*)(g + (size_t)s3 * 128) + lane);
    a0 += w0 * bflo(h0); a1 += w0 * bfhi(h0);
    b0 += w1 * bflo(h1); b1 += w1 * bfhi(h1);
    a0 += w2 * bflo(h2); a1 += w2 * bfhi(h2);
    b0 += w3 * bflo(h3); b1 += w3 * bfhi(h3);
  }
  for (; e < e1; ++e) {
    int2 r = cw[e];
    int s0 = rfl(r.x); float w0 = __uint_as_float(rfl(r.y));
    u32 h0 = *((const u32*)(g + (size_t)s0 * 128) + lane);
    a0 += w0 * bflo(h0); a1 += w0 * bfhi(h0);
  }
  part[wave][2 * lane]     = a0 + b0;
  part[wave][2 * lane + 1] = a1 + b1;
  __syncthreads();
  if (h == 0 && node < N) {
    float r0v = part[wave][2 * lane]     + part[wave + 1][2 * lane];
    float r1v = part[wave][2 * lane + 1] + part[wave + 1][2 * lane + 1];
    float dn = dis[node];
    u32 cin = *((const u32*)(Cin + (size_t)node * 128) + lane);
    r0v = dn * r0v + bflo(cin);
    r1v = dn * r1v + bfhi(cin);
    if (FINAL) {
      float2 bv = *(const float2*)(bias + 2 * lane);
      r0v = fmaxf(r0v + bv.x, 0.f);
      r1v = fmaxf(r1v + bv.y, 0.f);
    }
    *((u32*)(out + (size_t)node * 128) + lane) = packb2(r0v, r1v);
  }
}

// ---------- EA gather v6: 2 waves/node + LDS combine; Hsum[n]=sum relu(pb+q[src]+P[e]) ----------
__global__ __launch_bounds__(256) void ea_gather6(
    const u16* __restrict__ pb, const u16* __restrict__ q,
    const u16* __restrict__ P /*f16 [E,128]*/,
    const int* __restrict__ rowptr, const int2* __restrict__ ce,
    u16* __restrict__ Hsum, int N) {
  __shared__ float part[4][128];
  int wave = threadIdx.x >> 6, lane = threadIdx.x & 63;
  int node = blockIdx.x * 2 + (wave >> 1);
  int h = wave & 1;
  float pb0 = 0.f, pb1 = 0.f;
  int e = 0, e1 = 0;
  if (node < N) {
    int s = rfl(rowptr[node]);
    int t = rfl(rowptr[node + 1]);
    int mid = (s + t) >> 1;
    e  = h ? mid : s;
    e1 = h ? t : mid;
    u32 pbu = *((const u32*)(pb + (size_t)node * 128) + lane);
    pb0 = bflo(pbu); pb1 = bfhi(pbu);
  }
  float acc0 = 0, acc1 = 0;
  for (; e + 4 <= e1; e += 4) {
    int4 r01 = *(const int4*)(ce + e);
    int4 r23 = *(const int4*)(ce + e + 2);
    int s0 = rfl(r01.x), i0 = rfl(r01.y);
    int s1 = rfl(r01.z), i1 = rfl(r01.w);
    int s2 = rfl(r23.x), i2 = rfl(r23.y);
    int s3 = rfl(r23.z), i3 = rfl(r23.w);
    u32 q0 = *((const u32*)(q + (size_t)s0 * 128) + lane);
    u32 v0 = *((const u32*)(P + (size_t)i0 * 128) + lane);
    u32 q1 = *((const u32*)(q + (size_t)s1 * 128) + lane);
    u32 v1 = *((const u32*)(P + (size_t)i1 * 128) + lane);
    u32 q2 = *((const u32*)(q + (size_t)s2 * 128) + lane);
    u32 v2 = *((const u32*)(P + (size_t)i2 * 128) + lane);
    u32 q3 = *((const u32*)(q + (size_t)s3 * 128) + lane);
    u32 v3 = *((const u32*)(P + (size_t)i3 * 128) + lane);
    acc0 += fmaxf(pb0 + bflo(q0) + h2lo(v0), 0.f) + fmaxf(pb0 + bflo(q1) + h2lo(v1), 0.f)
          + fmaxf(pb0 + bflo(q2) + h2lo(v2), 0.f) + fmaxf(pb0 + bflo(q3) + h2lo(v3), 0.f);
    acc1 += fmaxf(pb1 + bfhi(q0) + h2hi(v0), 0.f) + fmaxf(pb1 + bfhi(q1) + h2hi(v1), 0.f)
          + fmaxf(pb1 + bfhi(q2) + h2hi(v2), 0.f) + fmaxf(pb1 + bfhi(q3) + h2hi(v3), 0.f);
  }
  for (; e < e1; ++e) {
    int2 r = ce[e];
    int s0 = rfl(r.x), i0 = rfl(r.y);
    u32 q0 = *((const u32*)(q + (size_t)s0 * 128) + lane);
    u32 v0 = *((const u32*)(P + (size_t)i0 * 128) + lane);
    acc0 += fmaxf(pb0 + bflo(q0) + h2lo(v0), 0.f);
    acc1 += fmaxf(pb1 + bfhi(q0) + h2hi(v0), 0.f);
  }
  part[wave][2 * lane]     = acc0;
  part[wave][2 * lane + 1] = acc1;
  __syncthreads();
  if (h == 0 && node < N) {
    float r0v = part[wave][2 * lane]     + part[wave + 1][2 * lane];
    float r1v = part[wave][2 * lane + 1] + part[wave + 1][2 * lane + 1];
    *((u32*)(Hsum + (size_t)node * 128) + lane) = packb2(r0v, r1v);
  }
}

extern "C" void kernel_launch(void* const* d_in, const int* in_sizes, int n_in,
                              void* d_out, int out_size, void* d_ws, size_t ws_size,
                              hipStream_t stream) {
  const float* x      = (const float*)d_in[0];
  const float* mask   = (const float*)d_in[1];
  const float* ea     = (const float*)d_in[2];
  const int*   eidx   = (const int*)d_in[3];
  const float* m_w1   = (const float*)d_in[4];
  const float* m_b1   = (const float*)d_in[5];
  const float* m_w2   = (const float*)d_in[6];
  const float* m_b2   = (const float*)d_in[7];
  const float* ea0_w1 = (const float*)d_in[8];
  const float* ea0_b1 = (const float*)d_in[9];
  const float* ea0_w2 = (const float*)d_in[10];
  const float* ea0_b2 = (const float*)d_in[11];
  const float* tag0_w = (const float*)d_in[12];
  const float* tag0_b = (const float*)d_in[13];
  const float* ea1_w1 = (const float*)d_in[14];
  const float* ea1_b1 = (const float*)d_in[15];
  const float* ea1_w2 = (const float*)d_in[16];
  const float* ea1_b2 = (const float*)d_in[17];
  const float* tag1_w = (const float*)d_in[18];
  const float* tag1_b = (const float*)d_in[19];
  const float* ea2_w1 = (const float*)d_in[20];
  const float* ea2_b1 = (const float*)d_in[21];
  const float* ea2_w2 = (const float*)d_in[22];
  const float* ea2_b2 = (const float*)d_in[23];

  const int N = in_sizes[0] / 16;   // 20000
  const int E = in_sizes[2] / 16;   // 160000
  const int E2 = 2 * E;
  const int NB = (N + 255) / 256;

  char* w = (char*)d_ws;
  auto alloc = [&](size_t bytes) { char* p = w; w += (bytes + 255) & ~(size_t)255; return p; };
  int*   degi   = (int*)alloc((size_t)N * 4);
  int*   cursor = (int*)alloc((size_t)N * 4);
  int*   rowptr = (int*)alloc((size_t)(N + 1) * 4);
  int*   bsum   = (int*)alloc((size_t)256 * 4);
  float* dis    = (float*)alloc((size_t)N * 4);
  int2*  cw     = (int2*)alloc((size_t)E2 * 8);
  int2*  ce     = (int2*)alloc((size_t)E2 * 8);
  u16*   X0     = (u16*)alloc((size_t)N * 128 * 2);
  u16*   X1     = (u16*)alloc((size_t)N * 128 * 2);
  u16*   X2     = (u16*)alloc((size_t)N * 128 * 2);
  u16*   G0     = (u16*)alloc((size_t)N * 128 * 2);
  u16*   G1     = (u16*)alloc((size_t)N * 128 * 2);
  u16*   G2     = (u16*)alloc((size_t)N * 128 * 2);
  u16*   G3     = (u16*)alloc((size_t)N * 128 * 2);
  u16*   Wt     = (u16*)alloc((size_t)14 * 16384 * 2);
  u16*   W3     = (u16*)alloc((size_t)3 * 2048 * 2);
  u16*   P0     = (u16*)alloc((size_t)E * 128 * 2);
  u16*   P1     = (u16*)alloc((size_t)E * 128 * 2);
  u16*   P2     = (u16*)alloc((size_t)E * 128 * 2);
  (void)ws_size; (void)n_in; (void)out_size;

  // ---- prep (also zeros degi) + edge tables + CSR (parallel scan) ----
  prep_wt<<<112, 256, 0, stream>>>(ea0_w2, tag0_w, ea1_w1, ea1_w2, tag1_w, ea2_w1, Wt, degi, N);
  prep_wt_ea<<<3, 256, 0, stream>>>(ea0_w1 + 32 * 128, ea1_w1 + 256 * 128,
                                    ea2_w1 + 256 * 128, W3);
  ea_proj_mfma<<<(E + 63) / 64, 256, 0, stream>>>(ea, W3, P0, P1, P2, E);
  count_deg<<<(E + 255) / 256, 256, 0, stream>>>(eidx, degi, E);
  scan1<<<NB, 256, 0, stream>>>(degi, bsum, N);
  scan2<<<1, 256, 0, stream>>>(bsum, rowptr, NB, N);
  scan3<<<NB, 256, 0, stream>>>(degi, bsum, rowptr, cursor, dis, N);
  fill_csr<<<(E2 + 255) / 256, 256, 0, stream>>>(eidx, cursor, dis, cw, ce, E);

  const int gb = (N + 7) / 8;
  const int gm = (N + 63) / 64;
  const int g2 = (N + 1) / 2;    // gather blocks: 4 waves = 2 nodes x 2 waves
  u16* WT_ea0w2  = Wt + 0 * 16384;
  u16* WT_tag0   = Wt + 1 * 16384;
  u16* WT_ea1d   = Wt + 5 * 16384;
  u16* WT_ea1s   = Wt + 6 * 16384;
  u16* WT_ea1w2  = Wt + 7 * 16384;
  u16* WT_tag1   = Wt + 8 * 16384;
  u16* WT_ea2d   = Wt + 12 * 16384;
  u16* WT_ea2s   = Wt + 13 * 16384;

  // ---- fused head: mask MLP -> h16 -> EA0 pb/q ----
  gemm_head<<<gb, 128, 0, stream>>>(mask, x, m_w1, m_b1, m_w2, m_b2,
                                    ea0_w1, ea0_b1, X0, X1, N);

  // ---- EA0 ----
  ea_gather6<<<g2, 256, 0, stream>>>(X0, X1, P0, rowptr, ce, X2, N);
  gemm_mfma<true><<<gm, 256, 0, stream>>>(X2, WT_ea0w2, X0, ea0_b2, degi, N, 1);   // h1 -> X0

  // ---- TAG0: g_k = h1@lin_k; h2 = relu(g0 + L(g1 + L(g2 + L g3)) + b) ----
  gemm_mfma_quad<<<gm, 256, 0, stream>>>(X0, WT_tag0, G0, G1, G2, G3, N);
  tag_gather6<false><<<g2, 256, 0, stream>>>(G3, G2, nullptr, dis, rowptr, cw, X1, N);
  tag_gather6<false><<<g2, 256, 0, stream>>>(X1, G1, nullptr, dis, rowptr, cw, X2, N);
  tag_gather6<true><<<g2, 256, 0, stream>>>(X2, G0, tag0_b, dis, rowptr, cw, X0, N);  // h2 -> X0

  // ---- EA1 ----
  gemm_mfma_dual<<<gm, 256, 0, stream>>>(X0, WT_ea1d, WT_ea1s, X1, X2, ea1_b1, N);
  ea_gather6<<<g2, 256, 0, stream>>>(X1, X2, P1, rowptr, ce, G0, N);
  gemm_mfma<true><<<gm, 256, 0, stream>>>(G0, WT_ea1w2, X0, ea1_b2, degi, N, 1);   // h3 -> X0

  // ---- TAG1 ----
  gemm_mfma_quad<<<gm, 256, 0, stream>>>(X0, WT_tag1, G0, G1, G2, G3, N);
  tag_gather6<false><<<g2, 256, 0, stream>>>(G3, G2, nullptr, dis, rowptr, cw, X1, N);
  tag_gather6<false><<<g2, 256, 0, stream>>>(X1, G1, nullptr, dis, rowptr, cw, X2, N);
  tag_gather6<true><<<g2, 256, 0, stream>>>(X2, G0, tag1_b, dis, rowptr, cw, X0, N);  // h4 -> X0

  // ---- EA2 (final, out 16, fp32) ----
  gemm_mfma_dual<<<gm, 256, 0, stream>>>(X0, WT_ea2d, WT_ea2s, X1, X2, ea2_b1, N);
  ea_gather6<<<g2, 256, 0, stream>>>(X1, X2, P2, rowptr, ce, G0, N);
  gemm_tail<<<gb, 128, 0, stream>>>(G0, ea2_w2, (float*)d_out, ea2_b2, degi, N);
}

// Round 11
// 432.068 us; speedup vs baseline: 1.1367x; 1.1367x over previous
//
#include <hip/hip_runtime.h>

typedef unsigned short u16;
typedef unsigned int u32;

using bfrag  = __attribute__((ext_vector_type(8))) short;   // 8 bf16 (4 VGPRs)
using f32x4  = __attribute__((ext_vector_type(4))) float;   // 4 fp32 acc
using f32x16 = __attribute__((ext_vector_type(16))) float;  // 16 fp32 acc (32x32 MFMA)

// ---------- bf16 / f16 helpers ----------
__device__ __forceinline__ float b2f(u16 u) {
  union { u32 i; float f; } c; c.i = ((u32)u) << 16; return c.f;
}
__device__ __forceinline__ float bflo(u32 u) { union { u32 i; float f; } c; c.i = u << 16; return c.f; }
__device__ __forceinline__ float bfhi(u32 u) { union { u32 i; float f; } c; c.i = u & 0xffff0000u; return c.f; }
__device__ __forceinline__ u16 f2b(float f) {  // round-to-nearest-even
  union { float f; u32 i; } c; c.f = f;
  u32 x = c.i;
  u32 r = x + 0x7fffu + ((x >> 16) & 1u);
  return (u16)(r >> 16);
}
__device__ __forceinline__ u32 packb2(float x, float y) {
  return ((u32)f2b(x)) | (((u32)f2b(y)) << 16);
}
__device__ __forceinline__ u16 f2h(float x) {
  union { _Float16 h; u16 u; } c; c.h = (_Float16)x; return c.u;
}
__device__ __forceinline__ float h2lo(u32 u) { union { u32 i; _Float16 h[2]; } c; c.i = u; return (float)c.h[0]; }
__device__ __forceinline__ float h2hi(u32 u) { union { u32 i; _Float16 h[2]; } c; c.i = u; return (float)c.h[1]; }
__device__ __forceinline__ int rfl(int v) { return __builtin_amdgcn_readfirstlane(v); }

// ---------- CSR build ----------
__global__ __launch_bounds__(256) void count_deg(const int* __restrict__ eidx,
                                                 int* __restrict__ degi, int E) {
  int e = blockIdx.x * 256 + threadIdx.x;
  if (e >= E) return;
  atomicAdd(&degi[eidx[E + e]], 1);
  atomicAdd(&degi[eidx[e]], 1);
}

__global__ __launch_bounds__(256) void scan1(const int* __restrict__ degi,
                                             int* __restrict__ bsum, int N) {
  __shared__ int sh[256];
  int t = threadIdx.x;
  int gid = blockIdx.x * 256 + t;
  sh[t] = (gid < N) ? degi[gid] : 0;
  __syncthreads();
  for (int off = 128; off > 0; off >>= 1) {
    if (t < off) sh[t] += sh[t + off];
    __syncthreads();
  }
  if (t == 0) bsum[blockIdx.x] = sh[0];
}

__global__ __launch_bounds__(256) void scan2(int* __restrict__ bsum,
                                             int* __restrict__ rowptr, int nb, int N) {
  __shared__ int sh[256];
  int t = threadIdx.x;
  int v = (t < nb) ? bsum[t] : 0;
  sh[t] = v;
  __syncthreads();
  for (int off = 1; off < 256; off <<= 1) {
    int x = sh[t];
    int add = (t >= off) ? sh[t - off] : 0;
    __syncthreads();
    sh[t] = x + add;
    __syncthreads();
  }
  if (t < nb) bsum[t] = sh[t] - v;
  if (t == nb - 1) rowptr[N] = sh[t];
}

__global__ __launch_bounds__(256) void scan3(const int* __restrict__ degi,
                                             const int* __restrict__ bsum,
                                             int* __restrict__ rowptr,
                                             int* __restrict__ cursor,
                                             float* __restrict__ dis, int N) {
  __shared__ int sh[256];
  int t = threadIdx.x;
  int gid = blockIdx.x * 256 + t;
  int d = (gid < N) ? degi[gid] : 0;
  sh[t] = d;
  __syncthreads();
  for (int off = 1; off < 256; off <<= 1) {
    int x = sh[t];
    int add = (t >= off) ? sh[t - off] : 0;
    __syncthreads();
    sh[t] = x + add;
    __syncthreads();
  }
  if (gid < N) {
    int run = bsum[blockIdx.x] + sh[t] - d;
    rowptr[gid] = run;
    cursor[gid] = run;
    dis[gid] = d > 0 ? rsqrtf((float)d) : 0.0f;
  }
}

__global__ __launch_bounds__(256) void fill_csr(const int* __restrict__ eidx,
                                                int* __restrict__ cursor,
                                                const float* __restrict__ dis,
                                                int2* __restrict__ cw,
                                                int2* __restrict__ ce, int E) {
  int i = blockIdx.x * 256 + threadIdx.x;
  int E2 = 2 * E;
  if (i >= E2) return;
  int e = (i < E) ? i : i - E;
  int s, d;
  if (i < E) { s = eidx[e]; d = eidx[E + e]; }
  else       { s = eidx[E + e]; d = eidx[e]; }
  int pos = atomicAdd(&cursor[d], 1);
  cw[pos] = make_int2(s, __float_as_int(dis[s]));
  ce[pos] = make_int2(s, e);
}

// ---------- weight prep: 14x [128][128] -> bf16 [n][k]; blocks 112-114: W3 transpose; zeros degi ----------
__global__ __launch_bounds__(256) void prep_wt(
    const float* __restrict__ ea0_w2, const float* __restrict__ tag0_w,
    const float* __restrict__ ea1_w1, const float* __restrict__ ea1_w2,
    const float* __restrict__ tag1_w, const float* __restrict__ ea2_w1,
    const float* __restrict__ ea0_w1,
    u16* __restrict__ Wt, u16* __restrict__ W3, int* __restrict__ degi, int N) {
  int gid = blockIdx.x * 256 + threadIdx.x;
  if (gid < N) degi[gid] = 0;
  int t = threadIdx.x;
  if (blockIdx.x >= 112) {   // W3: fp32 [16][128] -> bf16 [128n][16k]
    int tab = blockIdx.x - 112;
    const float* src = (tab == 0) ? (ea0_w1 + 32 * 128)
                     : (tab == 1) ? (ea1_w1 + 256 * 128)
                                  : (ea2_w1 + 256 * 128);
    u16* dst = W3 + tab * 2048;
    for (int i = 0; i < 8; ++i) {
      int idx = i * 256 + t;
      int n = idx >> 4, k = idx & 15;
      dst[idx] = f2b(src[k * 128 + n]);
    }
    return;
  }
  int mat = blockIdx.x >> 3, chunk = blockIdx.x & 7;
  const float* src;
  if      (mat == 0)  src = ea0_w2;
  else if (mat <= 4)  src = tag0_w + (mat - 1) * 16384;
  else if (mat == 5)  src = ea1_w1;
  else if (mat == 6)  src = ea1_w1 + 16384;
  else if (mat == 7)  src = ea1_w2;
  else if (mat <= 11) src = tag1_w + (mat - 8) * 16384;
  else if (mat == 12) src = ea2_w1;
  else                src = ea2_w1 + 16384;
  u16* dst = Wt + mat * 16384;
  for (int i = 0; i < 8; ++i) {
    int idx = chunk * 2048 + i * 256 + t;
    int k = idx >> 7, n = idx & 127;
    dst[n * 128 + k] = f2b(src[idx]);
  }
}

// ---------- edge projection via MFMA 32x32x16: P_l[e,:] = ea[e,:16] @ W_l  (f16) ----------
__global__ __launch_bounds__(256) void ea_proj_mfma(
    const float* __restrict__ ea, const u16* __restrict__ W3,
    u16* __restrict__ P0, u16* __restrict__ P1, u16* __restrict__ P2, int E) {
  __shared__ u16 Alds[64 * 16];
  __shared__ u16 Wlds[3 * 2048];
  int t = threadIdx.x;
  int base = blockIdx.x * 64;
  int rows = E - base; if (rows > 64) rows = 64;
#pragma unroll
  for (int i = 0; i < 3; ++i)
    *(uint4*)(Wlds + (i * 256 + t) * 8) = *(const uint4*)(W3 + (i * 256 + t) * 8);
#pragma unroll
  for (int i = 0; i < 4; ++i) {
    int idx = (i * 256 + t) * 4;
    float4 v = make_float4(0.f, 0.f, 0.f, 0.f);
    if ((idx >> 4) < rows) v = *(const float4*)(ea + (size_t)base * 16 + idx);
    ushort4 h;
    h.x = f2b(v.x); h.y = f2b(v.y); h.z = f2b(v.z); h.w = f2b(v.w);
    *(ushort4*)(Alds + idx) = h;
  }
  __syncthreads();
  int wave = t >> 6, lane = t & 63;
  int rowt = (wave >> 1) * 32;
  int colt = (wave & 1) * 64;
  int mm = lane & 31, kh = lane >> 5;
  bfrag a = *(const bfrag*)(Alds + (rowt + mm) * 16 + kh * 8);
#pragma unroll
  for (int tab = 0; tab < 3; ++tab) {
    const u16* wl = Wlds + tab * 2048;
    bfrag b0 = *(const bfrag*)(wl + (colt + mm) * 16 + kh * 8);
    bfrag b1 = *(const bfrag*)(wl + (colt + 32 + mm) * 16 + kh * 8);
    f32x16 acc0, acc1;
#pragma unroll
    for (int z = 0; z < 16; ++z) { acc0[z] = 0.f; acc1[z] = 0.f; }
    acc0 = __builtin_amdgcn_mfma_f32_32x32x16_bf16(a, b0, acc0, 0, 0, 0);
    acc1 = __builtin_amdgcn_mfma_f32_32x32x16_bf16(a, b1, acc1, 0, 0, 0);
    u16* P = (tab == 0) ? P0 : (tab == 1) ? P1 : P2;
#pragma unroll
    for (int reg = 0; reg < 16; ++reg) {
      int row = rowt + (reg & 3) + 8 * (reg >> 2) + 4 * kh;
      if (row < rows) {
        size_t off = (size_t)(base + row) * 128;
        P[off + colt + mm]      = f2h(acc0[reg]);
        P[off + colt + 32 + mm] = f2h(acc1[reg]);
      }
    }
  }
}

// ---------- fused head: h16 = relu(mask@w1+b1)@w2 + b2 + x;  pb = h16@Wd + b1', q = h16@Ws ----------
__global__ __launch_bounds__(128) void gemm_head(
    const float* __restrict__ mask, const float* __restrict__ x,
    const float* __restrict__ m_w1, const float* __restrict__ m_b1,
    const float* __restrict__ m_w2, const float* __restrict__ m_b2,
    const float* __restrict__ ea0_w1, const float* __restrict__ ea0_b1,
    u16* __restrict__ pb, u16* __restrict__ q, int M) {
  const int ROWS = 8;
  int t = threadIdx.x;
  int base = blockIdx.x * ROWS;
  __shared__ float Ml[ROWS * 16];
  __shared__ float T1[ROWS * 128];
  __shared__ float H[ROWS * 16];
  for (int i = t; i < ROWS * 16; i += 128) {
    int r = i >> 4, k = i & 15;
    int row = base + r;
    Ml[i] = (row < M) ? mask[(size_t)row * 16 + k] : 0.f;
  }
  __syncthreads();
  {
    float acc[ROWS];
#pragma unroll
    for (int r = 0; r < ROWS; ++r) acc[r] = m_b1[t];
    for (int k = 0; k < 16; ++k) {
      float w = m_w1[k * 128 + t];
#pragma unroll
      for (int r = 0; r < ROWS; ++r) acc[r] += Ml[r * 16 + k] * w;
    }
#pragma unroll
    for (int r = 0; r < ROWS; ++r) T1[r * 128 + t] = fmaxf(acc[r], 0.f);
  }
  __syncthreads();
  {
    int r = t >> 4, u = t & 15;
    float acc = m_b2[u];
    for (int k = 0; k < 128; ++k) acc += T1[r * 128 + k] * m_w2[k * 16 + u];
    int row = base + r;
    float xv = (row < M) ? x[(size_t)row * 16 + u] : 0.f;
    H[r * 16 + u] = acc + xv;
  }
  __syncthreads();
  {
    float aP[ROWS], aQ[ROWS];
    float b1v = ea0_b1[t];
#pragma unroll
    for (int r = 0; r < ROWS; ++r) { aP[r] = b1v; aQ[r] = 0.f; }
    for (int k = 0; k < 16; ++k) {
      float wd = ea0_w1[k * 128 + t];
      float ws = ea0_w1[(16 + k) * 128 + t];
#pragma unroll
      for (int r = 0; r < ROWS; ++r) {
        float h = H[r * 16 + k];
        aP[r] += h * wd;
        aQ[r] += h * ws;
      }
    }
#pragma unroll
    for (int r = 0; r < ROWS; ++r) {
      int row = base + r;
      if (row < M) {
        pb[(size_t)row * 128 + t] = f2b(aP[r]);
        q[(size_t)row * 128 + t]  = f2b(aQ[r]);
      }
    }
  }
}

// ---------- MFMA GEMM: C[M,128] = A[M,128]bf16 @ W (+bias/deg*bias +relu) ----------
template<bool OUTBF16>
__global__ __launch_bounds__(256) void gemm_mfma(
    const u16* __restrict__ A, const u16* __restrict__ Wt,
    void* __restrict__ Cout, const float* __restrict__ bias,
    const int* __restrict__ degi, int M, int relu) {
  __shared__ u16 Alds[64 * 136];
  __shared__ u16 Wlds[128 * 136];
  int t = threadIdx.x;
  int base = blockIdx.x * 64;
#pragma unroll
  for (int i = 0; i < 8; ++i) {
    int idx = (i * 256 + t) * 8;
    int n = idx >> 7, k = idx & 127;
    uint4 v = *(const uint4*)(Wt + idx);
    *(uint4*)(Wlds + n * 136 + k) = v;
  }
#pragma unroll
  for (int i = 0; i < 4; ++i) {
    int idx = (i * 256 + t) * 8;
    int r = idx >> 7, k = idx & 127;
    int row = base + r;
    uint4 v = make_uint4(0, 0, 0, 0);
    if (row < M) v = *(const uint4*)(A + (size_t)row * 128 + k);
    *(uint4*)(Alds + r * 136 + k) = v;
  }
  __syncthreads();
  int wave = t >> 6, lane = t & 63;
  int m = lane & 15, quad = lane >> 4;
  int arow = wave * 16 + m;
  bfrag a[4];
#pragma unroll
  for (int ks = 0; ks < 4; ++ks)
    a[ks] = *(const bfrag*)(Alds + arow * 136 + ks * 32 + quad * 8);
  f32x4 acc[8];
#pragma unroll
  for (int nt = 0; nt < 8; ++nt) acc[nt] = (f32x4){0.f, 0.f, 0.f, 0.f};
#pragma unroll
  for (int nt = 0; nt < 8; ++nt) {
    int n = nt * 16 + m;
#pragma unroll
    for (int ks = 0; ks < 4; ++ks) {
      bfrag b = *(const bfrag*)(Wlds + n * 136 + ks * 32 + quad * 8);
      acc[nt] = __builtin_amdgcn_mfma_f32_16x16x32_bf16(a[ks], b, acc[nt], 0, 0, 0);
    }
  }
#pragma unroll
  for (int nt = 0; nt < 8; ++nt) {
    int col = nt * 16 + m;
#pragma unroll
    for (int r = 0; r < 4; ++r) {
      int row = base + wave * 16 + quad * 4 + r;
      if (row < M) {
        float v = acc[nt][r];
        if (bias) { float b = bias[col]; v += degi ? b * (float)degi[row] : b; }
        if (relu) v = fmaxf(v, 0.f);
        if (OUTBF16) ((u16*)Cout)[(size_t)row * 128 + col] = f2b(v);
        else         ((float*)Cout)[(size_t)row * 128 + col] = v;
      }
    }
  }
}

// ---------- dual MFMA GEMM: C0 = A@W0 (+bias0), C1 = A@W1 (both bf16) ----------
__global__ __launch_bounds__(256) void gemm_mfma_dual(
    const u16* __restrict__ A, const u16* __restrict__ W0t, const u16* __restrict__ W1t,
    u16* __restrict__ C0, u16* __restrict__ C1, const float* __restrict__ bias0, int M) {
  __shared__ u16 Alds[64 * 136];
  __shared__ u16 Wlds[128 * 136];
  int t = threadIdx.x;
  int base = blockIdx.x * 64;
#pragma unroll
  for (int i = 0; i < 8; ++i) {
    int idx = (i * 256 + t) * 8;
    int n = idx >> 7, k = idx & 127;
    uint4 v = *(const uint4*)(W0t + idx);
    *(uint4*)(Wlds + n * 136 + k) = v;
  }
#pragma unroll
  for (int i = 0; i < 4; ++i) {
    int idx = (i * 256 + t) * 8;
    int r = idx >> 7, k = idx & 127;
    int row = base + r;
    uint4 v = make_uint4(0, 0, 0, 0);
    if (row < M) v = *(const uint4*)(A + (size_t)row * 128 + k);
    *(uint4*)(Alds + r * 136 + k) = v;
  }
  __syncthreads();
  int wave = t >> 6, lane = t & 63;
  int m = lane & 15, quad = lane >> 4;
  int arow = wave * 16 + m;
  bfrag a[4];
#pragma unroll
  for (int ks = 0; ks < 4; ++ks)
    a[ks] = *(const bfrag*)(Alds + arow * 136 + ks * 32 + quad * 8);
  f32x4 acc0[8], acc1[8];
#pragma unroll
  for (int nt = 0; nt < 8; ++nt) { acc0[nt] = (f32x4){0,0,0,0}; acc1[nt] = (f32x4){0,0,0,0}; }
#pragma unroll
  for (int nt = 0; nt < 8; ++nt) {
    int n = nt * 16 + m;
#pragma unroll
    for (int ks = 0; ks < 4; ++ks) {
      bfrag b = *(const bfrag*)(Wlds + n * 136 + ks * 32 + quad * 8);
      acc0[nt] = __builtin_amdgcn_mfma_f32_16x16x32_bf16(a[ks], b, acc0[nt], 0, 0, 0);
    }
  }
  __syncthreads();
#pragma unroll
  for (int i = 0; i < 8; ++i) {
    int idx = (i * 256 + t) * 8;
    int n = idx >> 7, k = idx & 127;
    uint4 v = *(const uint4*)(W1t + idx);
    *(uint4*)(Wlds + n * 136 + k) = v;
  }
  __syncthreads();
#pragma unroll
  for (int nt = 0; nt < 8; ++nt) {
    int n = nt * 16 + m;
#pragma unroll
    for (int ks = 0; ks < 4; ++ks) {
      bfrag b = *(const bfrag*)(Wlds + n * 136 + ks * 32 + quad * 8);
      acc1[nt] = __builtin_amdgcn_mfma_f32_16x16x32_bf16(a[ks], b, acc1[nt], 0, 0, 0);
    }
  }
#pragma unroll
  for (int nt = 0; nt < 8; ++nt) {
    int col = nt * 16 + m;
#pragma unroll
    for (int r = 0; r < 4; ++r) {
      int row = base + wave * 16 + quad * 4 + r;
      if (row < M) {
        float v0 = acc0[nt][r];
        if (bias0) v0 += bias0[col];
        C0[(size_t)row * 128 + col] = f2b(v0);
        C1[(size_t)row * 128 + col] = f2b(acc1[nt][r]);
      }
    }
  }
}

// ---------- quad MFMA GEMM (TAG): G_k = A @ W_k, k=0..3 ----------
__global__ __launch_bounds__(256) void gemm_mfma_quad(
    const u16* __restrict__ A, const u16* __restrict__ Wt4,
    u16* __restrict__ G0, u16* __restrict__ G1,
    u16* __restrict__ G2, u16* __restrict__ G3, int M) {
  __shared__ u16 Alds[64 * 136];
  __shared__ u16 Wlds[128 * 136];
  int t = threadIdx.x;
  int base = blockIdx.x * 64;
#pragma unroll
  for (int i = 0; i < 4; ++i) {
    int idx = (i * 256 + t) * 8;
    int r = idx >> 7, k = idx & 127;
    int row = base + r;
    uint4 v = make_uint4(0, 0, 0, 0);
    if (row < M) v = *(const uint4*)(A + (size_t)row * 128 + k);
    *(uint4*)(Alds + r * 136 + k) = v;
  }
  __syncthreads();
  int wave = t >> 6, lane = t & 63;
  int m = lane & 15, quad = lane >> 4;
  int arow = wave * 16 + m;
  bfrag a[4];
#pragma unroll
  for (int ks = 0; ks < 4; ++ks)
    a[ks] = *(const bfrag*)(Alds + arow * 136 + ks * 32 + quad * 8);
#pragma unroll
  for (int mat = 0; mat < 4; ++mat) {
    __syncthreads();
#pragma unroll
    for (int i = 0; i < 8; ++i) {
      int idx = (i * 256 + t) * 8;
      int n = idx >> 7, k = idx & 127;
      uint4 v = *(const uint4*)(Wt4 + mat * 16384 + idx);
      *(uint4*)(Wlds + n * 136 + k) = v;
    }
    __syncthreads();
    f32x4 acc[8];
#pragma unroll
    for (int nt = 0; nt < 8; ++nt) acc[nt] = (f32x4){0.f, 0.f, 0.f, 0.f};
#pragma unroll
    for (int nt = 0; nt < 8; ++nt) {
      int n = nt * 16 + m;
#pragma unroll
      for (int ks = 0; ks < 4; ++ks) {
        bfrag b = *(const bfrag*)(Wlds + n * 136 + ks * 32 + quad * 8);
        acc[nt] = __builtin_amdgcn_mfma_f32_16x16x32_bf16(a[ks], b, acc[nt], 0, 0, 0);
      }
    }
    u16* G = (mat == 0) ? G0 : (mat == 1) ? G1 : (mat == 2) ? G2 : G3;
#pragma unroll
    for (int nt = 0; nt < 8; ++nt) {
      int col = nt * 16 + m;
#pragma unroll
      for (int r = 0; r < 4; ++r) {
        int row = base + wave * 16 + quad * 4 + r;
        if (row < M) G[(size_t)row * 128 + col] = f2b(acc[nt][r]);
      }
    }
  }
}

// ---------- VALU GEMM (final 128->16) ----------
__global__ __launch_bounds__(128) void gemm_tail(
    const u16* __restrict__ A, const float* __restrict__ W, float* __restrict__ Cout,
    const float* __restrict__ bias, const int* __restrict__ degi, int M) {
  const int ROWS = 8;
  int t = threadIdx.x;
  int base = blockIdx.x * ROWS;
  __shared__ float Al[ROWS * 128];
  for (int i = t; i < ROWS * 128; i += 128) {
    int r = i >> 7, k = i & 127;
    int row = base + r;
    Al[i] = (row < M) ? b2f(A[(size_t)row * 128 + k]) : 0.f;
  }
  __syncthreads();
  int r = t >> 4, u = t & 15;
  int row = base + r;
  float acc = 0.f;
  for (int k = 0; k < 128; ++k) acc += Al[r * 128 + k] * W[k * 16 + u];
  if (row < M) {
    Cout[(size_t)row * 16 + u] = acc + bias[u] * (float)degi[row];
  }
}

// ---------- TAG gather v7: 1 node/wave, 8-edge unroll + 4/2/1 remainder ----------
template<bool FINAL>
__global__ __launch_bounds__(256) void tag_gather7(
    const u16* __restrict__ g, const u16* __restrict__ Cin,
    const float* __restrict__ bias, const float* __restrict__ dis,
    const int* __restrict__ rowptr, const int2* __restrict__ cw,
    u16* __restrict__ out, int N) {
  int wave = threadIdx.x >> 6, lane = threadIdx.x & 63;
  int node = blockIdx.x * 4 + wave;
  if (node >= N) return;
  int e0 = rfl(rowptr[node]);
  int e1 = rfl(rowptr[node + 1]);
  float a0 = 0, a1 = 0, b0 = 0, b1 = 0;
  int e = e0;
  for (; e + 8 <= e1; e += 8) {
    int4 ra = *(const int4*)(cw + e);
    int4 rb = *(const int4*)(cw + e + 2);
    int4 rc = *(const int4*)(cw + e + 4);
    int4 rd = *(const int4*)(cw + e + 6);
    int s0 = rfl(ra.x); float w0 = __uint_as_float(rfl(ra.y));
    int s1 = rfl(ra.z); float w1 = __uint_as_float(rfl(ra.w));
    int s2 = rfl(rb.x); float w2 = __uint_as_float(rfl(rb.y));
    int s3 = rfl(rb.z); float w3 = __uint_as_float(rfl(rb.w));
    int s4 = rfl(rc.x); float w4 = __uint_as_float(rfl(rc.y));
    int s5 = rfl(rc.z); float w5 = __uint_as_float(rfl(rc.w));
    int s6 = rfl(rd.x); float w6 = __uint_as_float(rfl(rd.y));
    int s7 = rfl(rd.z); float w7 = __uint_as_float(rfl(rd.w));
    u32 h0 = *((const u32*)(g + (size_t)s0 * 128) + lane);
    u32 h1 = *((const u32*)(g + (size_t)s1 * 128) + lane);
    u32 h2 = *((const u32*)(g + (size_t)s2 * 128) + lane);
    u32 h3 = *((const u32*)(g + (size_t)s3 * 128) + lane);
    u32 h4 = *((const u32*)(g + (size_t)s4 * 128) + lane);
    u32 h5 = *((const u32*)(g + (size_t)s5 * 128) + lane);
    u32 h6 = *((const u32*)(g + (size_t)s6 * 128) + lane);
    u32 h7 = *((const u32*)(g + (size_t)s7 * 128) + lane);
    a0 += w0 * bflo(h0) + w2 * bflo(h2) + w4 * bflo(h4) + w6 * bflo(h6);
    a1 += w0 * bfhi(h0) + w2 * bfhi(h2) + w4 * bfhi(h4) + w6 * bfhi(h6);
    b0 += w1 * bflo(h1) + w3 * bflo(h3) + w5 * bflo(h5) + w7 * bflo(h7);
    b1 += w1 * bfhi(h1) + w3 * bfhi(h3) + w5 * bfhi(h5) + w7 * bfhi(h7);
  }
  for (; e + 4 <= e1; e += 4) {
    int4 ra = *(const int4*)(cw + e);
    int4 rb = *(const int4*)(cw + e + 2);
    int s0 = rfl(ra.x); float w0 = __uint_as_float(rfl(ra.y));
    int s1 = rfl(ra.z); float w1 = __uint_as_float(rfl(ra.w));
    int s2 = rfl(rb.x); float w2 = __uint_as_float(rfl(rb.y));
    int s3 = rfl(rb.z); float w3 = __uint_as_float(rfl(rb.w));
    u32 h0 = *((const u32*)(g + (size_t)s0 * 128) + lane);
    u32 h1 = *((const u32*)(g + (size_t)s1 * 128) + lane);
    u32 h2 = *((const u32*)(g + (size_t)s2 * 128) + lane);
    u32 h3 = *((const u32*)(g + (size_t)s3 * 128) + lane);
    a0 += w0 * bflo(h0) + w2 * bflo(h2);
    a1 += w0 * bfhi(h0) + w2 * bfhi(h2);
    b0 += w1 * bflo(h1) + w3 * bflo(h3);
    b1 += w1 * bfhi(h1) + w3 * bfhi(h3);
  }
  if (e + 2 <= e1) {
    int4 ra = *(const int4*)(cw + e);
    int s0 = rfl(ra.x); float w0 = __uint_as_float(rfl(ra.y));
    int s1 = rfl(ra.z); float w1 = __uint_as_float(rfl(ra.w));
    u32 h0 = *((const u32*)(g + (size_t)s0 * 128) + lane);
    u32 h1 = *((const u32*)(g + (size_t)s1 * 128) + lane);
    a0 += w0 * bflo(h0); a1 += w0 * bfhi(h0);
    b0 += w1 * bflo(h1); b1 += w1 * bfhi(h1);
    e += 2;
  }
  if (e < e1) {
    int2 r = cw[e];
    int s0 = rfl(r.x); float w0 = __uint_as_float(rfl(r.y));
    u32 h0 = *((const u32*)(g + (size_t)s0 * 128) + lane);
    a0 += w0 * bflo(h0); a1 += w0 * bfhi(h0);
  }
  float dn = dis[node];
  float r0v = dn * (a0 + b0), r1v = dn * (a1 + b1);
  u32 cin = *((const u32*)(Cin + (size_t)node * 128) + lane);
  r0v += bflo(cin); r1v += bfhi(cin);
  if (FINAL) {
    float2 bv = *(const float2*)(bias + 2 * lane);
    r0v = fmaxf(r0v + bv.x, 0.f);
    r1v = fmaxf(r1v + bv.y, 0.f);
  }
  *((u32*)(out + (size_t)node * 128) + lane) = packb2(r0v, r1v);
}

// ---------- EA gather v7: 1 node/wave, 8-edge unroll (16 row loads in flight) ----------
__global__ __launch_bounds__(256) void ea_gather7(
    const u16* __restrict__ pb, const u16* __restrict__ q,
    const u16* __restrict__ P /*f16 [E,128]*/,
    const int* __restrict__ rowptr, const int2* __restrict__ ce,
    u16* __restrict__ Hsum, int N) {
  int wave = threadIdx.x >> 6, lane = threadIdx.x & 63;
  int node = blockIdx.x * 4 + wave;
  if (node >= N) return;
  int e0 = rfl(rowptr[node]);
  int e1 = rfl(rowptr[node + 1]);
  u32 pbu = *((const u32*)(pb + (size_t)node * 128) + lane);
  float pb0 = bflo(pbu), pb1 = bfhi(pbu);
  float acc0 = 0, acc1 = 0;
  int e = e0;
  for (; e + 8 <= e1; e += 8) {
    int4 ra = *(const int4*)(ce + e);
    int4 rb = *(const int4*)(ce + e + 2);
    int4 rc = *(const int4*)(ce + e + 4);
    int4 rd = *(const int4*)(ce + e + 6);
    int s0 = rfl(ra.x), i0 = rfl(ra.y);
    int s1 = rfl(ra.z), i1 = rfl(ra.w);
    int s2 = rfl(rb.x), i2 = rfl(rb.y);
    int s3 = rfl(rb.z), i3 = rfl(rb.w);
    int s4 = rfl(rc.x), i4 = rfl(rc.y);
    int s5 = rfl(rc.z), i5 = rfl(rc.w);
    int s6 = rfl(rd.x), i6 = rfl(rd.y);
    int s7 = rfl(rd.z), i7 = rfl(rd.w);
    u32 q0 = *((const u32*)(q + (size_t)s0 * 128) + lane);
    u32 v0 = *((const u32*)(P + (size_t)i0 * 128) + lane);
    u32 q1 = *((const u32*)(q + (size_t)s1 * 128) + lane);
    u32 v1 = *((const u32*)(P + (size_t)i1 * 128) + lane);
    u32 q2 = *((const u32*)(q + (size_t)s2 * 128) + lane);
    u32 v2 = *((const u32*)(P + (size_t)i2 * 128) + lane);
    u32 q3 = *((const u32*)(q + (size_t)s3 * 128) + lane);
    u32 v3 = *((const u32*)(P + (size_t)i3 * 128) + lane);
    u32 q4 = *((const u32*)(q + (size_t)s4 * 128) + lane);
    u32 v4 = *((const u32*)(P + (size_t)i4 * 128) + lane);
    u32 q5 = *((const u32*)(q + (size_t)s5 * 128) + lane);
    u32 v5 = *((const u32*)(P + (size_t)i5 * 128) + lane);
    u32 q6 = *((const u32*)(q + (size_t)s6 * 128) + lane);
    u32 v6 = *((const u32*)(P + (size_t)i6 * 128) + lane);
    u32 q7 = *((const u32*)(q + (size_t)s7 * 128) + lane);
    u32 v7 = *((const u32*)(P + (size_t)i7 * 128) + lane);
    acc0 += fmaxf(pb0 + bflo(q0) + h2lo(v0), 0.f) + fmaxf(pb0 + bflo(q1) + h2lo(v1), 0.f)
          + fmaxf(pb0 + bflo(q2) + h2lo(v2), 0.f) + fmaxf(pb0 + bflo(q3) + h2lo(v3), 0.f)
          + fmaxf(pb0 + bflo(q4) + h2lo(v4), 0.f) + fmaxf(pb0 + bflo(q5) + h2lo(v5), 0.f)
          + fmaxf(pb0 + bflo(q6) + h2lo(v6), 0.f) + fmaxf(pb0 + bflo(q7) + h2lo(v7), 0.f);
    acc1 += fmaxf(pb1 + bfhi(q0) + h2hi(v0), 0.f) + fmaxf(pb1 + bfhi(q1) + h2hi(v1), 0.f)
          + fmaxf(pb1 + bfhi(q2) + h2hi(v2), 0.f) + fmaxf(pb1 + bfhi(q3) + h2hi(v3), 0.f)
          + fmaxf(pb1 + bfhi(q4) + h2hi(v4), 0.f) + fmaxf(pb1 + bfhi(q5) + h2hi(v5), 0.f)
          + fmaxf(pb1 + bfhi(q6) + h2hi(v6), 0.f) + fmaxf(pb1 + bfhi(q7) + h2hi(v7), 0.f);
  }
  for (; e + 4 <= e1; e += 4) {
    int4 ra = *(const int4*)(ce + e);
    int4 rb = *(const int4*)(ce + e + 2);
    int s0 = rfl(ra.x), i0 = rfl(ra.y);
    int s1 = rfl(ra.z), i1 = rfl(ra.w);
    int s2 = rfl(rb.x), i2 = rfl(rb.y);
    int s3 = rfl(rb.z), i3 = rfl(rb.w);
    u32 q0 = *((const u32*)(q + (size_t)s0 * 128) + lane);
    u32 v0 = *((const u32*)(P + (size_t)i0 * 128) + lane);
    u32 q1 = *((const u32*)(q + (size_t)s1 * 128) + lane);
    u32 v1 = *((const u32*)(P + (size_t)i1 * 128) + lane);
    u32 q2 = *((const u32*)(q + (size_t)s2 * 128) + lane);
    u32 v2 = *((const u32*)(P + (size_t)i2 * 128) + lane);
    u32 q3 = *((const u32*)(q + (size_t)s3 * 128) + lane);
    u32 v3 = *((const u32*)(P + (size_t)i3 * 128) + lane);
    acc0 += fmaxf(pb0 + bflo(q0) + h2lo(v0), 0.f) + fmaxf(pb0 + bflo(q1) + h2lo(v1), 0.f)
          + fmaxf(pb0 + bflo(q2) + h2lo(v2), 0.f) + fmaxf(pb0 + bflo(q3) + h2lo(v3), 0.f);
    acc1 += fmaxf(pb1 + bfhi(q0) + h2hi(v0), 0.f) + fmaxf(pb1 + bfhi(q1) + h2hi(v1), 0.f)
          + fmaxf(pb1 + bfhi(q2) + h2hi(v2), 0.f) + fmaxf(pb1 + bfhi(q3) + h2hi(v3), 0.f);
  }
  if (e + 2 <= e1) {
    int4 ra = *(const int4*)(ce + e);
    int s0 = rfl(ra.x), i0 = rfl(ra.y);
    int s1 = rfl(ra.z), i1 = rfl(ra.w);
    u32 q0 = *((const u32*)(q + (size_t)s0 * 128) + lane);
    u32 v0 = *((const u32*)(P + (size_t)i0 * 128) + lane);
    u32 q1 = *((const u32*)(q + (size_t)s1 * 128) + lane);
    u32 v1 = *((const u32*)(P + (size_t)i1 * 128) + lane);
    acc0 += fmaxf(pb0 + bflo(q0) + h2lo(v0), 0.f) + fmaxf(pb0 + bflo(q1) + h2lo(v1), 0.f);
    acc1 += fmaxf(pb1 + bfhi(q0) + h2hi(v0), 0.f) + fmaxf(pb1 + bfhi(q1) + h2hi(v1), 0.f);
    e += 2;
  }
  if (e < e1) {
    int2 r = ce[e];
    int s0 = rfl(r.x), i0 = rfl(r.y);
    u32 q0 = *((const u32*)(q + (size_t)s0 * 128) + lane);
    u32 v0 = *((const u32*)(P + (size_t)i0 * 128) + lane);
    acc0 += fmaxf(pb0 + bflo(q0) + h2lo(v0), 0.f);
    acc1 += fmaxf(pb1 + bfhi(q0) + h2hi(v0), 0.f);
  }
  *((u32*)(Hsum + (size_t)node * 128) + lane) = packb2(acc0, acc1);
}

extern "C" void kernel_launch(void* const* d_in, const int* in_sizes, int n_in,
                              void* d_out, int out_size, void* d_ws, size_t ws_size,
                              hipStream_t stream) {
  const float* x      = (const float*)d_in[0];
  const float* mask   = (const float*)d_in[1];
  const float* ea     = (const float*)d_in[2];
  const int*   eidx   = (const int*)d_in[3];
  const float* m_w1   = (const float*)d_in[4];
  const float* m_b1   = (const float*)d_in[5];
  const float* m_w2   = (const float*)d_in[6];
  const float* m_b2   = (const float*)d_in[7];
  const float* ea0_w1 = (const float*)d_in[8];
  const float* ea0_b1 = (const float*)d_in[9];
  const float* ea0_w2 = (const float*)d_in[10];
  const float* ea0_b2 = (const float*)d_in[11];
  const float* tag0_w = (const float*)d_in[12];
  const float* tag0_b = (const float*)d_in[13];
  const float* ea1_w1 = (const float*)d_in[14];
  const float* ea1_b1 = (const float*)d_in[15];
  const float* ea1_w2 = (const float*)d_in[16];
  const float* ea1_b2 = (const float*)d_in[17];
  const float* tag1_w = (const float*)d_in[18];
  const float* tag1_b = (const float*)d_in[19];
  const float* ea2_w1 = (const float*)d_in[20];
  const float* ea2_b1 = (const float*)d_in[21];
  const float* ea2_w2 = (const float*)d_in[22];
  const float* ea2_b2 = (const float*)d_in[23];

  const int N = in_sizes[0] / 16;   // 20000
  const int E = in_sizes[2] / 16;   // 160000
  const int E2 = 2 * E;
  const int NB = (N + 255) / 256;

  char* w = (char*)d_ws;
  auto alloc = [&](size_t bytes) { char* p = w; w += (bytes + 255) & ~(size_t)255; return p; };
  int*   degi   = (int*)alloc((size_t)N * 4);
  int*   cursor = (int*)alloc((size_t)N * 4);
  int*   rowptr = (int*)alloc((size_t)(N + 1) * 4);
  int*   bsum   = (int*)alloc((size_t)256 * 4);
  float* dis    = (float*)alloc((size_t)N * 4);
  int2*  cw     = (int2*)alloc((size_t)E2 * 8);
  int2*  ce     = (int2*)alloc((size_t)E2 * 8);
  u16*   X0     = (u16*)alloc((size_t)N * 128 * 2);
  u16*   X1     = (u16*)alloc((size_t)N * 128 * 2);
  u16*   X2     = (u16*)alloc((size_t)N * 128 * 2);
  u16*   G0     = (u16*)alloc((size_t)N * 128 * 2);
  u16*   G1     = (u16*)alloc((size_t)N * 128 * 2);
  u16*   G2     = (u16*)alloc((size_t)N * 128 * 2);
  u16*   G3     = (u16*)alloc((size_t)N * 128 * 2);
  u16*   Wt     = (u16*)alloc((size_t)14 * 16384 * 2);
  u16*   W3     = (u16*)alloc((size_t)3 * 2048 * 2);
  u16*   P0     = (u16*)alloc((size_t)E * 128 * 2);
  u16*   P1     = (u16*)alloc((size_t)E * 128 * 2);
  u16*   P2     = (u16*)alloc((size_t)E * 128 * 2);
  (void)ws_size; (void)n_in; (void)out_size;

  // ---- prep (weights + W3 + zero degi) + edge tables + CSR (parallel scan) ----
  prep_wt<<<115, 256, 0, stream>>>(ea0_w2, tag0_w, ea1_w1, ea1_w2, tag1_w, ea2_w1,
                                   ea0_w1, Wt, W3, degi, N);
  ea_proj_mfma<<<(E + 63) / 64, 256, 0, stream>>>(ea, W3, P0, P1, P2, E);
  count_deg<<<(E + 255) / 256, 256, 0, stream>>>(eidx, degi, E);
  scan1<<<NB, 256, 0, stream>>>(degi, bsum, N);
  scan2<<<1, 256, 0, stream>>>(bsum, rowptr, NB, N);
  scan3<<<NB, 256, 0, stream>>>(degi, bsum, rowptr, cursor, dis, N);
  fill_csr<<<(E2 + 255) / 256, 256, 0, stream>>>(eidx, cursor, dis, cw, ce, E);

  const int gb = (N + 7) / 8;
  const int gm = (N + 63) / 64;
  const int g4 = (N + 3) / 4;    // gather blocks: 4 waves x 1 node
  u16* WT_ea0w2  = Wt + 0 * 16384;
  u16* WT_tag0   = Wt + 1 * 16384;
  u16* WT_ea1d   = Wt + 5 * 16384;
  u16* WT_ea1s   = Wt + 6 * 16384;
  u16* WT_ea1w2  = Wt + 7 * 16384;
  u16* WT_tag1   = Wt + 8 * 16384;
  u16* WT_ea2d   = Wt + 12 * 16384;
  u16* WT_ea2s   = Wt + 13 * 16384;

  // ---- fused head: mask MLP -> h16 -> EA0 pb/q ----
  gemm_head<<<gb, 128, 0, stream>>>(mask, x, m_w1, m_b1, m_w2, m_b2,
                                    ea0_w1, ea0_b1, X0, X1, N);

  // ---- EA0 ----
  ea_gather7<<<g4, 256, 0, stream>>>(X0, X1, P0, rowptr, ce, X2, N);
  gemm_mfma<true><<<gm, 256, 0, stream>>>(X2, WT_ea0w2, X0, ea0_b2, degi, N, 1);   // h1 -> X0

  // ---- TAG0: g_k = h1@lin_k; h2 = relu(g0 + L(g1 + L(g2 + L g3)) + b) ----
  gemm_mfma_quad<<<gm, 256, 0, stream>>>(X0, WT_tag0, G0, G1, G2, G3, N);
  tag_gather7<false><<<g4, 256, 0, stream>>>(G3, G2, nullptr, dis, rowptr, cw, X1, N);
  tag_gather7<false><<<g4, 256, 0, stream>>>(X1, G1, nullptr, dis, rowptr, cw, X2, N);
  tag_gather7<true><<<g4, 256, 0, stream>>>(X2, G0, tag0_b, dis, rowptr, cw, X0, N);  // h2 -> X0

  // ---- EA1 ----
  gemm_mfma_dual<<<gm, 256, 0, stream>>>(X0, WT_ea1d, WT_ea1s, X1, X2, ea1_b1, N);
  ea_gather7<<<g4, 256, 0, stream>>>(X1, X2, P1, rowptr, ce, G0, N);
  gemm_mfma<true><<<gm, 256, 0, stream>>>(G0, WT_ea1w2, X0, ea1_b2, degi, N, 1);   // h3 -> X0

  // ---- TAG1 ----
  gemm_mfma_quad<<<gm, 256, 0, stream>>>(X0, WT_tag1, G0, G1, G2, G3, N);
  tag_gather7<false><<<g4, 256, 0, stream>>>(G3, G2, nullptr, dis, rowptr, cw, X1, N);
  tag_gather7<false><<<g4, 256, 0, stream>>>(X1, G1, nullptr, dis, rowptr, cw, X2, N);
  tag_gather7<true><<<g4, 256, 0, stream>>>(X2, G0, tag1_b, dis, rowptr, cw, X0, N);  // h4 -> X0

  // ---- EA2 (final, out 16, fp32) ----
  gemm_mfma_dual<<<gm, 256, 0, stream>>>(X0, WT_ea2d, WT_ea2s, X1, X2, ea2_b1, N);
  ea_gather7<<<g4, 256, 0, stream>>>(X1, X2, P2, rowptr, ce, G0, N);
  gemm_tail<<<gb, 128, 0, stream>>>(G0, ea2_w2, (float*)d_out, ea2_b2, degi, N);
}

// Round 12
// 429.450 us; speedup vs baseline: 1.1437x; 1.0061x over previous
//
#include <hip/hip_runtime.h>

typedef unsigned short u16;
typedef unsigned int u32;

using bfrag  = __attribute__((ext_vector_type(8))) short;   // 8 bf16 (4 VGPRs)
using f32x4  = __attribute__((ext_vector_type(4))) float;   // 4 fp32 acc
using f32x16 = __attribute__((ext_vector_type(16))) float;  // 16 fp32 acc (32x32 MFMA)

// ---------- bf16 / f16 helpers ----------
__device__ __forceinline__ float b2f(u16 u) {
  union { u32 i; float f; } c; c.i = ((u32)u) << 16; return c.f;
}
__device__ __forceinline__ float bflo(u32 u) { union { u32 i; float f; } c; c.i = u << 16; return c.f; }
__device__ __forceinline__ float bfhi(u32 u) { union { u32 i; float f; } c; c.i = u & 0xffff0000u; return c.f; }
__device__ __forceinline__ u16 f2b(float f) {  // round-to-nearest-even
  union { float f; u32 i; } c; c.f = f;
  u32 x = c.i;
  u32 r = x + 0x7fffu + ((x >> 16) & 1u);
  return (u16)(r >> 16);
}
__device__ __forceinline__ u32 packb2(float x, float y) {
  return ((u32)f2b(x)) | (((u32)f2b(y)) << 16);
}
__device__ __forceinline__ u16 f2h(float x) {
  union { _Float16 h; u16 u; } c; c.h = (_Float16)x; return c.u;
}
__device__ __forceinline__ float h2lo(u32 u) { union { u32 i; _Float16 h[2]; } c; c.i = u; return (float)c.h[0]; }
__device__ __forceinline__ float h2hi(u32 u) { union { u32 i; _Float16 h[2]; } c; c.i = u; return (float)c.h[1]; }
__device__ __forceinline__ int rfl(int v) { return __builtin_amdgcn_readfirstlane(v); }

// ---------- CSR build ----------
__global__ __launch_bounds__(256) void count_deg(const int* __restrict__ eidx,
                                                 int* __restrict__ degi, int E) {
  int e = blockIdx.x * 256 + threadIdx.x;
  if (e >= E) return;
  atomicAdd(&degi[eidx[E + e]], 1);
  atomicAdd(&degi[eidx[e]], 1);
}

__global__ __launch_bounds__(256) void scan1(const int* __restrict__ degi,
                                             int* __restrict__ bsum, int N) {
  __shared__ int sh[256];
  int t = threadIdx.x;
  int gid = blockIdx.x * 256 + t;
  sh[t] = (gid < N) ? degi[gid] : 0;
  __syncthreads();
  for (int off = 128; off > 0; off >>= 1) {
    if (t < off) sh[t] += sh[t + off];
    __syncthreads();
  }
  if (t == 0) bsum[blockIdx.x] = sh[0];
}

__global__ __launch_bounds__(256) void scan2(int* __restrict__ bsum,
                                             int* __restrict__ rowptr, int nb, int N) {
  __shared__ int sh[256];
  int t = threadIdx.x;
  int v = (t < nb) ? bsum[t] : 0;
  sh[t] = v;
  __syncthreads();
  for (int off = 1; off < 256; off <<= 1) {
    int x = sh[t];
    int add = (t >= off) ? sh[t - off] : 0;
    __syncthreads();
    sh[t] = x + add;
    __syncthreads();
  }
  if (t < nb) bsum[t] = sh[t] - v;
  if (t == nb - 1) rowptr[N] = sh[t];
}

__global__ __launch_bounds__(256) void scan3(const int* __restrict__ degi,
                                             const int* __restrict__ bsum,
                                             int* __restrict__ rowptr,
                                             int* __restrict__ cursor,
                                             float* __restrict__ dis, int N) {
  __shared__ int sh[256];
  int t = threadIdx.x;
  int gid = blockIdx.x * 256 + t;
  int d = (gid < N) ? degi[gid] : 0;
  sh[t] = d;
  __syncthreads();
  for (int off = 1; off < 256; off <<= 1) {
    int x = sh[t];
    int add = (t >= off) ? sh[t - off] : 0;
    __syncthreads();
    sh[t] = x + add;
    __syncthreads();
  }
  if (gid < N) {
    int run = bsum[blockIdx.x] + sh[t] - d;
    rowptr[gid] = run;
    cursor[gid] = run;
    dis[gid] = d > 0 ? rsqrtf((float)d) : 0.0f;
  }
}

__global__ __launch_bounds__(256) void fill_csr(const int* __restrict__ eidx,
                                                int* __restrict__ cursor,
                                                const float* __restrict__ dis,
                                                int2* __restrict__ cw,
                                                int2* __restrict__ ce, int E) {
  int i = blockIdx.x * 256 + threadIdx.x;
  int E2 = 2 * E;
  if (i >= E2) return;
  int e = (i < E) ? i : i - E;
  int s, d;
  if (i < E) { s = eidx[e]; d = eidx[E + e]; }
  else       { s = eidx[E + e]; d = eidx[e]; }
  int pos = atomicAdd(&cursor[d], 1);
  cw[pos] = make_int2(s, __float_as_int(dis[s]));
  ce[pos] = make_int2(s, e);
}

// ---------- weight prep: 14x [128][128] -> bf16 [n][k]; blocks 112-114: W3 transpose; zeros degi ----------
__global__ __launch_bounds__(256) void prep_wt(
    const float* __restrict__ ea0_w2, const float* __restrict__ tag0_w,
    const float* __restrict__ ea1_w1, const float* __restrict__ ea1_w2,
    const float* __restrict__ tag1_w, const float* __restrict__ ea2_w1,
    const float* __restrict__ ea0_w1,
    u16* __restrict__ Wt, u16* __restrict__ W3, int* __restrict__ degi, int N) {
  int gid = blockIdx.x * 256 + threadIdx.x;
  if (gid < N) degi[gid] = 0;
  int t = threadIdx.x;
  if (blockIdx.x >= 112) {   // W3: fp32 [16][128] -> bf16 [128n][16k]
    int tab = blockIdx.x - 112;
    const float* src = (tab == 0) ? (ea0_w1 + 32 * 128)
                     : (tab == 1) ? (ea1_w1 + 256 * 128)
                                  : (ea2_w1 + 256 * 128);
    u16* dst = W3 + tab * 2048;
    for (int i = 0; i < 8; ++i) {
      int idx = i * 256 + t;
      int n = idx >> 4, k = idx & 15;
      dst[idx] = f2b(src[k * 128 + n]);
    }
    return;
  }
  int mat = blockIdx.x >> 3, chunk = blockIdx.x & 7;
  const float* src;
  if      (mat == 0)  src = ea0_w2;
  else if (mat <= 4)  src = tag0_w + (mat - 1) * 16384;
  else if (mat == 5)  src = ea1_w1;
  else if (mat == 6)  src = ea1_w1 + 16384;
  else if (mat == 7)  src = ea1_w2;
  else if (mat <= 11) src = tag1_w + (mat - 8) * 16384;
  else if (mat == 12) src = ea2_w1;
  else                src = ea2_w1 + 16384;
  u16* dst = Wt + mat * 16384;
  for (int i = 0; i < 8; ++i) {
    int idx = chunk * 2048 + i * 256 + t;
    int k = idx >> 7, n = idx & 127;
    dst[n * 128 + k] = f2b(src[idx]);
  }
}

// ---------- edge projection via MFMA 32x32x16: P_l[e,:] = ea[e,:16] @ W_l  (f16) ----------
__global__ __launch_bounds__(256) void ea_proj_mfma(
    const float* __restrict__ ea, const u16* __restrict__ W3,
    u16* __restrict__ P0, u16* __restrict__ P1, u16* __restrict__ P2, int E) {
  __shared__ u16 Alds[64 * 16];
  __shared__ u16 Wlds[3 * 2048];
  int t = threadIdx.x;
  int base = blockIdx.x * 64;
  int rows = E - base; if (rows > 64) rows = 64;
#pragma unroll
  for (int i = 0; i < 3; ++i)
    *(uint4*)(Wlds + (i * 256 + t) * 8) = *(const uint4*)(W3 + (i * 256 + t) * 8);
#pragma unroll
  for (int i = 0; i < 4; ++i) {
    int idx = (i * 256 + t) * 4;
    float4 v = make_float4(0.f, 0.f, 0.f, 0.f);
    if ((idx >> 4) < rows) v = *(const float4*)(ea + (size_t)base * 16 + idx);
    ushort4 h;
    h.x = f2b(v.x); h.y = f2b(v.y); h.z = f2b(v.z); h.w = f2b(v.w);
    *(ushort4*)(Alds + idx) = h;
  }
  __syncthreads();
  int wave = t >> 6, lane = t & 63;
  int rowt = (wave >> 1) * 32;
  int colt = (wave & 1) * 64;
  int mm = lane & 31, kh = lane >> 5;
  bfrag a = *(const bfrag*)(Alds + (rowt + mm) * 16 + kh * 8);
#pragma unroll
  for (int tab = 0; tab < 3; ++tab) {
    const u16* wl = Wlds + tab * 2048;
    bfrag b0 = *(const bfrag*)(wl + (colt + mm) * 16 + kh * 8);
    bfrag b1 = *(const bfrag*)(wl + (colt + 32 + mm) * 16 + kh * 8);
    f32x16 acc0, acc1;
#pragma unroll
    for (int z = 0; z < 16; ++z) { acc0[z] = 0.f; acc1[z] = 0.f; }
    acc0 = __builtin_amdgcn_mfma_f32_32x32x16_bf16(a, b0, acc0, 0, 0, 0);
    acc1 = __builtin_amdgcn_mfma_f32_32x32x16_bf16(a, b1, acc1, 0, 0, 0);
    u16* P = (tab == 0) ? P0 : (tab == 1) ? P1 : P2;
#pragma unroll
    for (int reg = 0; reg < 16; ++reg) {
      int row = rowt + (reg & 3) + 8 * (reg >> 2) + 4 * kh;
      if (row < rows) {
        size_t off = (size_t)(base + row) * 128;
        P[off + colt + mm]      = f2h(acc0[reg]);
        P[off + colt + 32 + mm] = f2h(acc1[reg]);
      }
    }
  }
}

// ---------- fused head: h16 = relu(mask@w1+b1)@w2 + b2 + x;  pb = h16@Wd + b1', q = h16@Ws ----------
__global__ __launch_bounds__(128) void gemm_head(
    const float* __restrict__ mask, const float* __restrict__ x,
    const float* __restrict__ m_w1, const float* __restrict__ m_b1,
    const float* __restrict__ m_w2, const float* __restrict__ m_b2,
    const float* __restrict__ ea0_w1, const float* __restrict__ ea0_b1,
    u16* __restrict__ pb, u16* __restrict__ q, int M) {
  const int ROWS = 8;
  int t = threadIdx.x;
  int base = blockIdx.x * ROWS;
  __shared__ float Ml[ROWS * 16];
  __shared__ float T1[ROWS * 128];
  __shared__ float H[ROWS * 16];
  for (int i = t; i < ROWS * 16; i += 128) {
    int r = i >> 4, k = i & 15;
    int row = base + r;
    Ml[i] = (row < M) ? mask[(size_t)row * 16 + k] : 0.f;
  }
  __syncthreads();
  {
    float acc[ROWS];
#pragma unroll
    for (int r = 0; r < ROWS; ++r) acc[r] = m_b1[t];
    for (int k = 0; k < 16; ++k) {
      float w = m_w1[k * 128 + t];
#pragma unroll
      for (int r = 0; r < ROWS; ++r) acc[r] += Ml[r * 16 + k] * w;
    }
#pragma unroll
    for (int r = 0; r < ROWS; ++r) T1[r * 128 + t] = fmaxf(acc[r], 0.f);
  }
  __syncthreads();
  {
    int r = t >> 4, u = t & 15;
    float acc = m_b2[u];
    for (int k = 0; k < 128; ++k) acc += T1[r * 128 + k] * m_w2[k * 16 + u];
    int row = base + r;
    float xv = (row < M) ? x[(size_t)row * 16 + u] : 0.f;
    H[r * 16 + u] = acc + xv;
  }
  __syncthreads();
  {
    float aP[ROWS], aQ[ROWS];
    float b1v = ea0_b1[t];
#pragma unroll
    for (int r = 0; r < ROWS; ++r) { aP[r] = b1v; aQ[r] = 0.f; }
    for (int k = 0; k < 16; ++k) {
      float wd = ea0_w1[k * 128 + t];
      float ws = ea0_w1[(16 + k) * 128 + t];
#pragma unroll
      for (int r = 0; r < ROWS; ++r) {
        float h = H[r * 16 + k];
        aP[r] += h * wd;
        aQ[r] += h * ws;
      }
    }
#pragma unroll
    for (int r = 0; r < ROWS; ++r) {
      int row = base + r;
      if (row < M) {
        pb[(size_t)row * 128 + t] = f2b(aP[r]);
        q[(size_t)row * 128 + t]  = f2b(aQ[r]);
      }
    }
  }
}

// ---------- MFMA GEMM: C[M,128] = A[M,128]bf16 @ W (+bias/deg*bias +relu) ----------
template<bool OUTBF16>
__global__ __launch_bounds__(256) void gemm_mfma(
    const u16* __restrict__ A, const u16* __restrict__ Wt,
    void* __restrict__ Cout, const float* __restrict__ bias,
    const int* __restrict__ degi, int M, int relu) {
  __shared__ u16 Alds[64 * 136];
  __shared__ u16 Wlds[128 * 136];
  int t = threadIdx.x;
  int base = blockIdx.x * 64;
#pragma unroll
  for (int i = 0; i < 8; ++i) {
    int idx = (i * 256 + t) * 8;
    int n = idx >> 7, k = idx & 127;
    uint4 v = *(const uint4*)(Wt + idx);
    *(uint4*)(Wlds + n * 136 + k) = v;
  }
#pragma unroll
  for (int i = 0; i < 4; ++i) {
    int idx = (i * 256 + t) * 8;
    int r = idx >> 7, k = idx & 127;
    int row = base + r;
    uint4 v = make_uint4(0, 0, 0, 0);
    if (row < M) v = *(const uint4*)(A + (size_t)row * 128 + k);
    *(uint4*)(Alds + r * 136 + k) = v;
  }
  __syncthreads();
  int wave = t >> 6, lane = t & 63;
  int m = lane & 15, quad = lane >> 4;
  int arow = wave * 16 + m;
  bfrag a[4];
#pragma unroll
  for (int ks = 0; ks < 4; ++ks)
    a[ks] = *(const bfrag*)(Alds + arow * 136 + ks * 32 + quad * 8);
  f32x4 acc[8];
#pragma unroll
  for (int nt = 0; nt < 8; ++nt) acc[nt] = (f32x4){0.f, 0.f, 0.f, 0.f};
#pragma unroll
  for (int nt = 0; nt < 8; ++nt) {
    int n = nt * 16 + m;
#pragma unroll
    for (int ks = 0; ks < 4; ++ks) {
      bfrag b = *(const bfrag*)(Wlds + n * 136 + ks * 32 + quad * 8);
      acc[nt] = __builtin_amdgcn_mfma_f32_16x16x32_bf16(a[ks], b, acc[nt], 0, 0, 0);
    }
  }
#pragma unroll
  for (int nt = 0; nt < 8; ++nt) {
    int col = nt * 16 + m;
#pragma unroll
    for (int r = 0; r < 4; ++r) {
      int row = base + wave * 16 + quad * 4 + r;
      if (row < M) {
        float v = acc[nt][r];
        if (bias) { float b = bias[col]; v += degi ? b * (float)degi[row] : b; }
        if (relu) v = fmaxf(v, 0.f);
        if (OUTBF16) ((u16*)Cout)[(size_t)row * 128 + col] = f2b(v);
        else         ((float*)Cout)[(size_t)row * 128 + col] = v;
      }
    }
  }
}

// ---------- dual MFMA GEMM: C0 = A@W0 (+bias0), C1 = A@W1 (both bf16) ----------
__global__ __launch_bounds__(256) void gemm_mfma_dual(
    const u16* __restrict__ A, const u16* __restrict__ W0t, const u16* __restrict__ W1t,
    u16* __restrict__ C0, u16* __restrict__ C1, const float* __restrict__ bias0, int M) {
  __shared__ u16 Alds[64 * 136];
  __shared__ u16 Wlds[128 * 136];
  int t = threadIdx.x;
  int base = blockIdx.x * 64;
#pragma unroll
  for (int i = 0; i < 8; ++i) {
    int idx = (i * 256 + t) * 8;
    int n = idx >> 7, k = idx & 127;
    uint4 v = *(const uint4*)(W0t + idx);
    *(uint4*)(Wlds + n * 136 + k) = v;
  }
#pragma unroll
  for (int i = 0; i < 4; ++i) {
    int idx = (i * 256 + t) * 8;
    int r = idx >> 7, k = idx & 127;
    int row = base + r;
    uint4 v = make_uint4(0, 0, 0, 0);
    if (row < M) v = *(const uint4*)(A + (size_t)row * 128 + k);
    *(uint4*)(Alds + r * 136 + k) = v;
  }
  __syncthreads();
  int wave = t >> 6, lane = t & 63;
  int m = lane & 15, quad = lane >> 4;
  int arow = wave * 16 + m;
  bfrag a[4];
#pragma unroll
  for (int ks = 0; ks < 4; ++ks)
    a[ks] = *(const bfrag*)(Alds + arow * 136 + ks * 32 + quad * 8);
  f32x4 acc0[8], acc1[8];
#pragma unroll
  for (int nt = 0; nt < 8; ++nt) { acc0[nt] = (f32x4){0,0,0,0}; acc1[nt] = (f32x4){0,0,0,0}; }
#pragma unroll
  for (int nt = 0; nt < 8; ++nt) {
    int n = nt * 16 + m;
#pragma unroll
    for (int ks = 0; ks < 4; ++ks) {
      bfrag b = *(const bfrag*)(Wlds + n * 136 + ks * 32 + quad * 8);
      acc0[nt] = __builtin_amdgcn_mfma_f32_16x16x32_bf16(a[ks], b, acc0[nt], 0, 0, 0);
    }
  }
  __syncthreads();
#pragma unroll
  for (int i = 0; i < 8; ++i) {
    int idx = (i * 256 + t) * 8;
    int n = idx >> 7, k = idx & 127;
    uint4 v = *(const uint4*)(W1t + idx);
    *(uint4*)(Wlds + n * 136 + k) = v;
  }
  __syncthreads();
#pragma unroll
  for (int nt = 0; nt < 8; ++nt) {
    int n = nt * 16 + m;
#pragma unroll
    for (int ks = 0; ks < 4; ++ks) {
      bfrag b = *(const bfrag*)(Wlds + n * 136 + ks * 32 + quad * 8);
      acc1[nt] = __builtin_amdgcn_mfma_f32_16x16x32_bf16(a[ks], b, acc1[nt], 0, 0, 0);
    }
  }
#pragma unroll
  for (int nt = 0; nt < 8; ++nt) {
    int col = nt * 16 + m;
#pragma unroll
    for (int r = 0; r < 4; ++r) {
      int row = base + wave * 16 + quad * 4 + r;
      if (row < M) {
        float v0 = acc0[nt][r];
        if (bias0) v0 += bias0[col];
        C0[(size_t)row * 128 + col] = f2b(v0);
        C1[(size_t)row * 128 + col] = f2b(acc1[nt][r]);
      }
    }
  }
}

// ---------- quad MFMA GEMM (TAG): G_k = A @ W_k, k=0..3 ----------
__global__ __launch_bounds__(256) void gemm_mfma_quad(
    const u16* __restrict__ A, const u16* __restrict__ Wt4,
    u16* __restrict__ G0, u16* __restrict__ G1,
    u16* __restrict__ G2, u16* __restrict__ G3, int M) {
  __shared__ u16 Alds[64 * 136];
  __shared__ u16 Wlds[128 * 136];
  int t = threadIdx.x;
  int base = blockIdx.x * 64;
#pragma unroll
  for (int i = 0; i < 4; ++i) {
    int idx = (i * 256 + t) * 8;
    int r = idx >> 7, k = idx & 127;
    int row = base + r;
    uint4 v = make_uint4(0, 0, 0, 0);
    if (row < M) v = *(const uint4*)(A + (size_t)row * 128 + k);
    *(uint4*)(Alds + r * 136 + k) = v;
  }
  __syncthreads();
  int wave = t >> 6, lane = t & 63;
  int m = lane & 15, quad = lane >> 4;
  int arow = wave * 16 + m;
  bfrag a[4];
#pragma unroll
  for (int ks = 0; ks < 4; ++ks)
    a[ks] = *(const bfrag*)(Alds + arow * 136 + ks * 32 + quad * 8);
#pragma unroll
  for (int mat = 0; mat < 4; ++mat) {
    __syncthreads();
#pragma unroll
    for (int i = 0; i < 8; ++i) {
      int idx = (i * 256 + t) * 8;
      int n = idx >> 7, k = idx & 127;
      uint4 v = *(const uint4*)(Wt4 + mat * 16384 + idx);
      *(uint4*)(Wlds + n * 136 + k) = v;
    }
    __syncthreads();
    f32x4 acc[8];
#pragma unroll
    for (int nt = 0; nt < 8; ++nt) acc[nt] = (f32x4){0.f, 0.f, 0.f, 0.f};
#pragma unroll
    for (int nt = 0; nt < 8; ++nt) {
      int n = nt * 16 + m;
#pragma unroll
      for (int ks = 0; ks < 4; ++ks) {
        bfrag b = *(const bfrag*)(Wlds + n * 136 + ks * 32 + quad * 8);
        acc[nt] = __builtin_amdgcn_mfma_f32_16x16x32_bf16(a[ks], b, acc[nt], 0, 0, 0);
      }
    }
    u16* G = (mat == 0) ? G0 : (mat == 1) ? G1 : (mat == 2) ? G2 : G3;
#pragma unroll
    for (int nt = 0; nt < 8; ++nt) {
      int col = nt * 16 + m;
#pragma unroll
      for (int r = 0; r < 4; ++r) {
        int row = base + wave * 16 + quad * 4 + r;
        if (row < M) G[(size_t)row * 128 + col] = f2b(acc[nt][r]);
      }
    }
  }
}

// ---------- VALU GEMM (final 128->16) ----------
__global__ __launch_bounds__(128) void gemm_tail(
    const u16* __restrict__ A, const float* __restrict__ W, float* __restrict__ Cout,
    const float* __restrict__ bias, const int* __restrict__ degi, int M) {
  const int ROWS = 8;
  int t = threadIdx.x;
  int base = blockIdx.x * ROWS;
  __shared__ float Al[ROWS * 128];
  for (int i = t; i < ROWS * 128; i += 128) {
    int r = i >> 7, k = i & 127;
    int row = base + r;
    Al[i] = (row < M) ? b2f(A[(size_t)row * 128 + k]) : 0.f;
  }
  __syncthreads();
  int r = t >> 4, u = t & 15;
  int row = base + r;
  float acc = 0.f;
  for (int k = 0; k < 128; ++k) acc += Al[r * 128 + k] * W[k * 16 + u];
  if (row < M) {
    Cout[(size_t)row * 16 + u] = acc + bias[u] * (float)degi[row];
  }
}

// ---------- per-edge bodies (records read from LDS at loop-counter addresses) ----------
__device__ __forceinline__ void tag_edge(const int2* __restrict__ rr, int j,
    const u16* __restrict__ g, int lane, float& x0, float& x1) {
  int2 r = rr[j];
  int s = rfl(r.x); float w = __uint_as_float(rfl(r.y));
  u32 h = *((const u32*)(g + (size_t)s * 128) + lane);
  x0 += w * bflo(h); x1 += w * bfhi(h);
}
__device__ __forceinline__ void ea_edge(const int2* __restrict__ rr, int j,
    const u16* __restrict__ q, const u16* __restrict__ P, int lane,
    float pb0, float pb1, float& x0, float& x1) {
  int2 r = rr[j];
  int s = rfl(r.x), i = rfl(r.y);
  u32 qv = *((const u32*)(q + (size_t)s * 128) + lane);
  u32 pv = *((const u32*)(P + (size_t)i * 128) + lane);
  x0 += fmaxf(pb0 + bflo(qv) + h2lo(pv), 0.f);
  x1 += fmaxf(pb1 + bfhi(qv) + h2hi(pv), 0.f);
}

// ---------- TAG gather v8: 1 node/wave, LDS-staged 64-record batches, 8-edge unroll ----------
template<bool FINAL>
__global__ __launch_bounds__(256) void tag_gather8(
    const u16* __restrict__ g, const u16* __restrict__ Cin,
    const float* __restrict__ bias, const float* __restrict__ dis,
    const int* __restrict__ rowptr, const int2* __restrict__ cw,
    u16* __restrict__ out, int N) {
  __shared__ int2 recs[4][64];
  int wave = threadIdx.x >> 6, lane = threadIdx.x & 63;
  int node = blockIdx.x * 4 + wave;
  if (node >= N) return;     // per-wave LDS only; no cross-wave sync needed
  int e0 = rfl(rowptr[node]);
  int e1 = rfl(rowptr[node + 1]);
  int2* rr = recs[wave];
  float a0 = 0, a1 = 0, b0 = 0, b1 = 0;
  for (int base = e0; base < e1; base += 64) {
    if (base + lane < e1) rr[lane] = cw[base + lane];   // one coalesced 8B/lane load
    int cnt = min(64, e1 - base);
    int j = 0;
    for (; j + 8 <= cnt; j += 8) {
      tag_edge(rr, j + 0, g, lane, a0, a1);
      tag_edge(rr, j + 1, g, lane, b0, b1);
      tag_edge(rr, j + 2, g, lane, a0, a1);
      tag_edge(rr, j + 3, g, lane, b0, b1);
      tag_edge(rr, j + 4, g, lane, a0, a1);
      tag_edge(rr, j + 5, g, lane, b0, b1);
      tag_edge(rr, j + 6, g, lane, a0, a1);
      tag_edge(rr, j + 7, g, lane, b0, b1);
    }
    for (; j + 2 <= cnt; j += 2) {
      tag_edge(rr, j + 0, g, lane, a0, a1);
      tag_edge(rr, j + 1, g, lane, b0, b1);
    }
    if (j < cnt) tag_edge(rr, j, g, lane, a0, a1);
  }
  float dn = dis[node];
  float r0v = dn * (a0 + b0), r1v = dn * (a1 + b1);
  u32 cin = *((const u32*)(Cin + (size_t)node * 128) + lane);
  r0v += bflo(cin); r1v += bfhi(cin);
  if (FINAL) {
    float2 bv = *(const float2*)(bias + 2 * lane);
    r0v = fmaxf(r0v + bv.x, 0.f);
    r1v = fmaxf(r1v + bv.y, 0.f);
  }
  *((u32*)(out + (size_t)node * 128) + lane) = packb2(r0v, r1v);
}

// ---------- EA gather v8: 1 node/wave, LDS-staged records, 8-edge unroll ----------
__global__ __launch_bounds__(256) void ea_gather8(
    const u16* __restrict__ pb, const u16* __restrict__ q,
    const u16* __restrict__ P /*f16 [E,128]*/,
    const int* __restrict__ rowptr, const int2* __restrict__ ce,
    u16* __restrict__ Hsum, int N) {
  __shared__ int2 recs[4][64];
  int wave = threadIdx.x >> 6, lane = threadIdx.x & 63;
  int node = blockIdx.x * 4 + wave;
  if (node >= N) return;
  int e0 = rfl(rowptr[node]);
  int e1 = rfl(rowptr[node + 1]);
  int2* rr = recs[wave];
  u32 pbu = *((const u32*)(pb + (size_t)node * 128) + lane);
  float pb0 = bflo(pbu), pb1 = bfhi(pbu);
  float a0 = 0, a1 = 0, b0 = 0, b1 = 0;
  for (int base = e0; base < e1; base += 64) {
    if (base + lane < e1) rr[lane] = ce[base + lane];
    int cnt = min(64, e1 - base);
    int j = 0;
    for (; j + 8 <= cnt; j += 8) {
      ea_edge(rr, j + 0, q, P, lane, pb0, pb1, a0, a1);
      ea_edge(rr, j + 1, q, P, lane, pb0, pb1, b0, b1);
      ea_edge(rr, j + 2, q, P, lane, pb0, pb1, a0, a1);
      ea_edge(rr, j + 3, q, P, lane, pb0, pb1, b0, b1);
      ea_edge(rr, j + 4, q, P, lane, pb0, pb1, a0, a1);
      ea_edge(rr, j + 5, q, P, lane, pb0, pb1, b0, b1);
      ea_edge(rr, j + 6, q, P, lane, pb0, pb1, a0, a1);
      ea_edge(rr, j + 7, q, P, lane, pb0, pb1, b0, b1);
    }
    for (; j + 2 <= cnt; j += 2) {
      ea_edge(rr, j + 0, q, P, lane, pb0, pb1, a0, a1);
      ea_edge(rr, j + 1, q, P, lane, pb0, pb1, b0, b1);
    }
    if (j < cnt) ea_edge(rr, j, q, P, lane, pb0, pb1, a0, a1);
  }
  *((u32*)(Hsum + (size_t)node * 128) + lane) = packb2(a0 + b0, a1 + b1);
}

extern "C" void kernel_launch(void* const* d_in, const int* in_sizes, int n_in,
                              void* d_out, int out_size, void* d_ws, size_t ws_size,
                              hipStream_t stream) {
  const float* x      = (const float*)d_in[0];
  const float* mask   = (const float*)d_in[1];
  const float* ea     = (const float*)d_in[2];
  const int*   eidx   = (const int*)d_in[3];
  const float* m_w1   = (const float*)d_in[4];
  const float* m_b1   = (const float*)d_in[5];
  const float* m_w2   = (const float*)d_in[6];
  const float* m_b2   = (const float*)d_in[7];
  const float* ea0_w1 = (const float*)d_in[8];
  const float* ea0_b1 = (const float*)d_in[9];
  const float* ea0_w2 = (const float*)d_in[10];
  const float* ea0_b2 = (const float*)d_in[11];
  const float* tag0_w = (const float*)d_in[12];
  const float* tag0_b = (const float*)d_in[13];
  const float* ea1_w1 = (const float*)d_in[14];
  const float* ea1_b1 = (const float*)d_in[15];
  const float* ea1_w2 = (const float*)d_in[16];
  const float* ea1_b2 = (const float*)d_in[17];
  const float* tag1_w = (const float*)d_in[18];
  const float* tag1_b = (const float*)d_in[19];
  const float* ea2_w1 = (const float*)d_in[20];
  const float* ea2_b1 = (const float*)d_in[21];
  const float* ea2_w2 = (const float*)d_in[22];
  const float* ea2_b2 = (const float*)d_in[23];

  const int N = in_sizes[0] / 16;   // 20000
  const int E = in_sizes[2] / 16;   // 160000
  const int E2 = 2 * E;
  const int NB = (N + 255) / 256;

  char* w = (char*)d_ws;
  auto alloc = [&](size_t bytes) { char* p = w; w += (bytes + 255) & ~(size_t)255; return p; };
  int*   degi   = (int*)alloc((size_t)N * 4);
  int*   cursor = (int*)alloc((size_t)N * 4);
  int*   rowptr = (int*)alloc((size_t)(N + 1) * 4);
  int*   bsum   = (int*)alloc((size_t)256 * 4);
  float* dis    = (float*)alloc((size_t)N * 4);
  int2*  cw     = (int2*)alloc((size_t)E2 * 8);
  int2*  ce     = (int2*)alloc((size_t)E2 * 8);
  u16*   X0     = (u16*)alloc((size_t)N * 128 * 2);
  u16*   X1     = (u16*)alloc((size_t)N * 128 * 2);
  u16*   X2     = (u16*)alloc((size_t)N * 128 * 2);
  u16*   G0     = (u16*)alloc((size_t)N * 128 * 2);
  u16*   G1     = (u16*)alloc((size_t)N * 128 * 2);
  u16*   G2     = (u16*)alloc((size_t)N * 128 * 2);
  u16*   G3     = (u16*)alloc((size_t)N * 128 * 2);
  u16*   Wt     = (u16*)alloc((size_t)14 * 16384 * 2);
  u16*   W3     = (u16*)alloc((size_t)3 * 2048 * 2);
  u16*   P0     = (u16*)alloc((size_t)E * 128 * 2);
  u16*   P1     = (u16*)alloc((size_t)E * 128 * 2);
  u16*   P2     = (u16*)alloc((size_t)E * 128 * 2);
  (void)ws_size; (void)n_in; (void)out_size;

  // ---- prep (weights + W3 + zero degi) + edge tables + CSR (parallel scan) ----
  prep_wt<<<115, 256, 0, stream>>>(ea0_w2, tag0_w, ea1_w1, ea1_w2, tag1_w, ea2_w1,
                                   ea0_w1, Wt, W3, degi, N);
  ea_proj_mfma<<<(E + 63) / 64, 256, 0, stream>>>(ea, W3, P0, P1, P2, E);
  count_deg<<<(E + 255) / 256, 256, 0, stream>>>(eidx, degi, E);
  scan1<<<NB, 256, 0, stream>>>(degi, bsum, N);
  scan2<<<1, 256, 0, stream>>>(bsum, rowptr, NB, N);
  scan3<<<NB, 256, 0, stream>>>(degi, bsum, rowptr, cursor, dis, N);
  fill_csr<<<(E2 + 255) / 256, 256, 0, stream>>>(eidx, cursor, dis, cw, ce, E);

  const int gb = (N + 7) / 8;
  const int gm = (N + 63) / 64;
  const int g4 = (N + 3) / 4;    // gather blocks: 4 waves x 1 node
  u16* WT_ea0w2  = Wt + 0 * 16384;
  u16* WT_tag0   = Wt + 1 * 16384;
  u16* WT_ea1d   = Wt + 5 * 16384;
  u16* WT_ea1s   = Wt + 6 * 16384;
  u16* WT_ea1w2  = Wt + 7 * 16384;
  u16* WT_tag1   = Wt + 8 * 16384;
  u16* WT_ea2d   = Wt + 12 * 16384;
  u16* WT_ea2s   = Wt + 13 * 16384;

  // ---- fused head: mask MLP -> h16 -> EA0 pb/q ----
  gemm_head<<<gb, 128, 0, stream>>>(mask, x, m_w1, m_b1, m_w2, m_b2,
                                    ea0_w1, ea0_b1, X0, X1, N);

  // ---- EA0 ----
  ea_gather8<<<g4, 256, 0, stream>>>(X0, X1, P0, rowptr, ce, X2, N);
  gemm_mfma<true><<<gm, 256, 0, stream>>>(X2, WT_ea0w2, X0, ea0_b2, degi, N, 1);   // h1 -> X0

  // ---- TAG0: g_k = h1@lin_k; h2 = relu(g0 + L(g1 + L(g2 + L g3)) + b) ----
  gemm_mfma_quad<<<gm, 256, 0, stream>>>(X0, WT_tag0, G0, G1, G2, G3, N);
  tag_gather8<false><<<g4, 256, 0, stream>>>(G3, G2, nullptr, dis, rowptr, cw, X1, N);
  tag_gather8<false><<<g4, 256, 0, stream>>>(X1, G1, nullptr, dis, rowptr, cw, X2, N);
  tag_gather8<true><<<g4, 256, 0, stream>>>(X2, G0, tag0_b, dis, rowptr, cw, X0, N);  // h2 -> X0

  // ---- EA1 ----
  gemm_mfma_dual<<<gm, 256, 0, stream>>>(X0, WT_ea1d, WT_ea1s, X1, X2, ea1_b1, N);
  ea_gather8<<<g4, 256, 0, stream>>>(X1, X2, P1, rowptr, ce, G0, N);
  gemm_mfma<true><<<gm, 256, 0, stream>>>(G0, WT_ea1w2, X0, ea1_b2, degi, N, 1);   // h3 -> X0

  // ---- TAG1 ----
  gemm_mfma_quad<<<gm, 256, 0, stream>>>(X0, WT_tag1, G0, G1, G2, G3, N);
  tag_gather8<false><<<g4, 256, 0, stream>>>(G3, G2, nullptr, dis, rowptr, cw, X1, N);
  tag_gather8<false><<<g4, 256, 0, stream>>>(X1, G1, nullptr, dis, rowptr, cw, X2, N);
  tag_gather8<true><<<g4, 256, 0, stream>>>(X2, G0, tag1_b, dis, rowptr, cw, X0, N);  // h4 -> X0

  // ---- EA2 (final, out 16, fp32) ----
  gemm_mfma_dual<<<gm, 256, 0, stream>>>(X0, WT_ea2d, WT_ea2s, X1, X2, ea2_b1, N);
  ea_gather8<<<g4, 256, 0, stream>>>(X1, X2, P2, rowptr, ce, G0, N);
  gemm_tail<<<gb, 128, 0, stream>>>(G0, ea2_w2, (float*)d_out, ea2_b2, degi, N);
}

// Round 13
// 424.537 us; speedup vs baseline: 1.1569x; 1.0116x over previous
//
#include <hip/hip_runtime.h>

typedef unsigned short u16;
typedef unsigned int u32;

using bfrag  = __attribute__((ext_vector_type(8))) short;   // 8 bf16 (4 VGPRs)
using f32x4  = __attribute__((ext_vector_type(4))) float;   // 4 fp32 acc
using f32x16 = __attribute__((ext_vector_type(16))) float;  // 16 fp32 acc (32x32 MFMA)

// ---------- bf16 / f16 helpers ----------
__device__ __forceinline__ float b2f(u16 u) {
  union { u32 i; float f; } c; c.i = ((u32)u) << 16; return c.f;
}
__device__ __forceinline__ float bflo(u32 u) { union { u32 i; float f; } c; c.i = u << 16; return c.f; }
__device__ __forceinline__ float bfhi(u32 u) { union { u32 i; float f; } c; c.i = u & 0xffff0000u; return c.f; }
__device__ __forceinline__ u16 f2b(float f) {  // round-to-nearest-even
  union { float f; u32 i; } c; c.f = f;
  u32 x = c.i;
  u32 r = x + 0x7fffu + ((x >> 16) & 1u);
  return (u16)(r >> 16);
}
__device__ __forceinline__ u32 packb2(float x, float y) {
  return ((u32)f2b(x)) | (((u32)f2b(y)) << 16);
}
__device__ __forceinline__ u16 f2h(float x) {
  union { _Float16 h; u16 u; } c; c.h = (_Float16)x; return c.u;
}
__device__ __forceinline__ float h2lo(u32 u) { union { u32 i; _Float16 h[2]; } c; c.i = u; return (float)c.h[0]; }
__device__ __forceinline__ float h2hi(u32 u) { union { u32 i; _Float16 h[2]; } c; c.i = u; return (float)c.h[1]; }
__device__ __forceinline__ int rfl(int v) { return __builtin_amdgcn_readfirstlane(v); }

// ---------- prologue: blocks [0,PB) edge-proj MFMA; [PB,PB+CB) count_deg; rest prep_wt ----------
__global__ __launch_bounds__(256) void prologue(
    const float* __restrict__ ea, const int* __restrict__ eidx,
    const float* __restrict__ ea0_w1, const float* __restrict__ ea0_w2,
    const float* __restrict__ tag0_w, const float* __restrict__ ea1_w1,
    const float* __restrict__ ea1_w2, const float* __restrict__ tag1_w,
    const float* __restrict__ ea2_w1,
    u16* __restrict__ P0, u16* __restrict__ P1, u16* __restrict__ P2,
    int* __restrict__ degi, u16* __restrict__ Wt, int E, int N,
    int PB, int CB) {
  int t = threadIdx.x;
  if (blockIdx.x < (unsigned)PB) {
    // ---- edge projection via MFMA 32x32x16: P_l[e,:] = ea[e,:16] @ W_l (f16 out) ----
    __shared__ u16 Alds[64 * 16];
    __shared__ u16 Wlds[3 * 2048];
    int base = blockIdx.x * 64;
    int rows = E - base; if (rows > 64) rows = 64;
    const float* wsrc[3] = { ea0_w1 + 32 * 128, ea1_w1 + 256 * 128, ea2_w1 + 256 * 128 };
#pragma unroll
    for (int i = 0; i < 8; ++i) {
      int idx = i * 256 + t;             // 0..2047
      int n = idx >> 4, k = idx & 15;
      Wlds[0 * 2048 + idx] = f2b(wsrc[0][k * 128 + n]);
      Wlds[1 * 2048 + idx] = f2b(wsrc[1][k * 128 + n]);
      Wlds[2 * 2048 + idx] = f2b(wsrc[2][k * 128 + n]);
    }
#pragma unroll
    for (int i = 0; i < 4; ++i) {
      int idx = (i * 256 + t) * 4;
      float4 v = make_float4(0.f, 0.f, 0.f, 0.f);
      if ((idx >> 4) < rows) v = *(const float4*)(ea + (size_t)base * 16 + idx);
      ushort4 h;
      h.x = f2b(v.x); h.y = f2b(v.y); h.z = f2b(v.z); h.w = f2b(v.w);
      *(ushort4*)(Alds + idx) = h;
    }
    __syncthreads();
    int wave = t >> 6, lane = t & 63;
    int rowt = (wave >> 1) * 32;
    int colt = (wave & 1) * 64;
    int mm = lane & 31, kh = lane >> 5;
    bfrag a = *(const bfrag*)(Alds + (rowt + mm) * 16 + kh * 8);
#pragma unroll
    for (int tab = 0; tab < 3; ++tab) {
      const u16* wl = Wlds + tab * 2048;
      bfrag b0 = *(const bfrag*)(wl + (colt + mm) * 16 + kh * 8);
      bfrag b1 = *(const bfrag*)(wl + (colt + 32 + mm) * 16 + kh * 8);
      f32x16 acc0, acc1;
#pragma unroll
      for (int z = 0; z < 16; ++z) { acc0[z] = 0.f; acc1[z] = 0.f; }
      acc0 = __builtin_amdgcn_mfma_f32_32x32x16_bf16(a, b0, acc0, 0, 0, 0);
      acc1 = __builtin_amdgcn_mfma_f32_32x32x16_bf16(a, b1, acc1, 0, 0, 0);
      u16* P = (tab == 0) ? P0 : (tab == 1) ? P1 : P2;
#pragma unroll
      for (int reg = 0; reg < 16; ++reg) {
        int row = rowt + (reg & 3) + 8 * (reg >> 2) + 4 * kh;
        if (row < rows) {
          size_t off = (size_t)(base + row) * 128;
          P[off + colt + mm]      = f2h(acc0[reg]);
          P[off + colt + 32 + mm] = f2h(acc1[reg]);
        }
      }
    }
    return;
  }
  if (blockIdx.x < (unsigned)(PB + CB)) {
    // ---- count_deg (degi pre-zeroed by memset) ----
    int e = (blockIdx.x - PB) * 256 + t;
    if (e < E) {
      atomicAdd(&degi[eidx[E + e]], 1);
      atomicAdd(&degi[eidx[e]], 1);
    }
    return;
  }
  // ---- prep_wt: 14x fp32 [128][128] -> bf16 [n][k] ----
  int wb = blockIdx.x - PB - CB;          // 0..111
  int mat = wb >> 3, chunk = wb & 7;
  const float* src;
  if      (mat == 0)  src = ea0_w2;
  else if (mat <= 4)  src = tag0_w + (mat - 1) * 16384;
  else if (mat == 5)  src = ea1_w1;
  else if (mat == 6)  src = ea1_w1 + 16384;
  else if (mat == 7)  src = ea1_w2;
  else if (mat <= 11) src = tag1_w + (mat - 8) * 16384;
  else if (mat == 12) src = ea2_w1;
  else                src = ea2_w1 + 16384;
  u16* dst = Wt + mat * 16384;
  for (int i = 0; i < 8; ++i) {
    int idx = chunk * 2048 + i * 256 + t;
    int k = idx >> 7, n = idx & 127;
    dst[n * 128 + k] = f2b(src[idx]);
  }
}

// ---------- parallel scan ----------
__global__ __launch_bounds__(256) void scan1(const int* __restrict__ degi,
                                             int* __restrict__ bsum, int N) {
  __shared__ int sh[256];
  int t = threadIdx.x;
  int gid = blockIdx.x * 256 + t;
  sh[t] = (gid < N) ? degi[gid] : 0;
  __syncthreads();
  for (int off = 128; off > 0; off >>= 1) {
    if (t < off) sh[t] += sh[t + off];
    __syncthreads();
  }
  if (t == 0) bsum[blockIdx.x] = sh[0];
}

__global__ __launch_bounds__(256) void scan2(int* __restrict__ bsum,
                                             int* __restrict__ rowptr, int nb, int N) {
  __shared__ int sh[256];
  int t = threadIdx.x;
  int v = (t < nb) ? bsum[t] : 0;
  sh[t] = v;
  __syncthreads();
  for (int off = 1; off < 256; off <<= 1) {
    int x = sh[t];
    int add = (t >= off) ? sh[t - off] : 0;
    __syncthreads();
    sh[t] = x + add;
    __syncthreads();
  }
  if (t < nb) bsum[t] = sh[t] - v;
  if (t == nb - 1) rowptr[N] = sh[t];
}

__global__ __launch_bounds__(256) void scan3(const int* __restrict__ degi,
                                             const int* __restrict__ bsum,
                                             int* __restrict__ rowptr,
                                             int* __restrict__ cursor,
                                             float* __restrict__ dis, int N) {
  __shared__ int sh[256];
  int t = threadIdx.x;
  int gid = blockIdx.x * 256 + t;
  int d = (gid < N) ? degi[gid] : 0;
  sh[t] = d;
  __syncthreads();
  for (int off = 1; off < 256; off <<= 1) {
    int x = sh[t];
    int add = (t >= off) ? sh[t - off] : 0;
    __syncthreads();
    sh[t] = x + add;
    __syncthreads();
  }
  if (gid < N) {
    int run = bsum[blockIdx.x] + sh[t] - d;
    rowptr[gid] = run;
    cursor[gid] = run;
    dis[gid] = d > 0 ? rsqrtf((float)d) : 0.0f;
  }
}

// ---------- fill_head: blocks [0,FB) fill_csr; [FB,FB+HB) head MLP (16 rows/block) ----------
__global__ __launch_bounds__(256) void fill_head(
    const int* __restrict__ eidx, int* __restrict__ cursor,
    const float* __restrict__ dis, int2* __restrict__ cw, int2* __restrict__ ce, int E,
    const float* __restrict__ mask, const float* __restrict__ x,
    const float* __restrict__ m_w1, const float* __restrict__ m_b1,
    const float* __restrict__ m_w2, const float* __restrict__ m_b2,
    const float* __restrict__ ea0_w1, const float* __restrict__ ea0_b1,
    u16* __restrict__ pb, u16* __restrict__ q, int M, int FB) {
  int t = threadIdx.x;
  if (blockIdx.x < (unsigned)FB) {
    int i = blockIdx.x * 256 + t;
    int E2 = 2 * E;
    if (i >= E2) return;
    int e = (i < E) ? i : i - E;
    int s, d;
    if (i < E) { s = eidx[e]; d = eidx[E + e]; }
    else       { s = eidx[E + e]; d = eidx[e]; }
    int pos = atomicAdd(&cursor[d], 1);
    cw[pos] = make_int2(s, __float_as_int(dis[s]));
    ce[pos] = make_int2(s, e);
    return;
  }
  // ---- head: h16 = relu(mask@w1+b1)@w2 + b2 + x; pb = h16@Wd + b1', q = h16@Ws ----
  __shared__ float Ml[16 * 16];
  __shared__ float T1[16 * 128];
  __shared__ float H[16 * 16];
  int base = (blockIdx.x - FB) * 16;
  {
    int r = t >> 4, k = t & 15;
    int row = base + r;
    Ml[t] = (row < M) ? mask[(size_t)row * 16 + k] : 0.f;
  }
  __syncthreads();
  {
    int col = t & 127, h2 = t >> 7;
    float acc[8];
    float b1v = m_b1[col];
#pragma unroll
    for (int r = 0; r < 8; ++r) acc[r] = b1v;
    for (int k = 0; k < 16; ++k) {
      float w = m_w1[k * 128 + col];
#pragma unroll
      for (int r = 0; r < 8; ++r) acc[r] += Ml[(h2 * 8 + r) * 16 + k] * w;
    }
#pragma unroll
    for (int r = 0; r < 8; ++r) T1[(h2 * 8 + r) * 128 + col] = fmaxf(acc[r], 0.f);
  }
  __syncthreads();
  {
    int r = t >> 4, u = t & 15;
    float acc = m_b2[u];
    for (int k = 0; k < 128; ++k) acc += T1[r * 128 + k] * m_w2[k * 16 + u];
    int row = base + r;
    float xv = (row < M) ? x[(size_t)row * 16 + u] : 0.f;
    H[t] = acc + xv;
  }
  __syncthreads();
  {
    int col = t & 127, h2 = t >> 7;
    float aP[8], aQ[8];
    float b1v = ea0_b1[col];
#pragma unroll
    for (int r = 0; r < 8; ++r) { aP[r] = b1v; aQ[r] = 0.f; }
    for (int k = 0; k < 16; ++k) {
      float wd = ea0_w1[k * 128 + col];
      float ws = ea0_w1[(16 + k) * 128 + col];
#pragma unroll
      for (int r = 0; r < 8; ++r) {
        float h = H[(h2 * 8 + r) * 16 + k];
        aP[r] += h * wd;
        aQ[r] += h * ws;
      }
    }
#pragma unroll
    for (int r = 0; r < 8; ++r) {
      int row = base + h2 * 8 + r;
      if (row < M) {
        pb[(size_t)row * 128 + col] = f2b(aP[r]);
        q[(size_t)row * 128 + col]  = f2b(aQ[r]);
      }
    }
  }
}

// ---------- MFMA GEMM: C[M,128] = A[M,128]bf16 @ W (+bias/deg*bias +relu) ----------
template<bool OUTBF16>
__global__ __launch_bounds__(256) void gemm_mfma(
    const u16* __restrict__ A, const u16* __restrict__ Wt,
    void* __restrict__ Cout, const float* __restrict__ bias,
    const int* __restrict__ degi, int M, int relu) {
  __shared__ u16 Alds[64 * 136];
  __shared__ u16 Wlds[128 * 136];
  int t = threadIdx.x;
  int base = blockIdx.x * 64;
#pragma unroll
  for (int i = 0; i < 8; ++i) {
    int idx = (i * 256 + t) * 8;
    int n = idx >> 7, k = idx & 127;
    uint4 v = *(const uint4*)(Wt + idx);
    *(uint4*)(Wlds + n * 136 + k) = v;
  }
#pragma unroll
  for (int i = 0; i < 4; ++i) {
    int idx = (i * 256 + t) * 8;
    int r = idx >> 7, k = idx & 127;
    int row = base + r;
    uint4 v = make_uint4(0, 0, 0, 0);
    if (row < M) v = *(const uint4*)(A + (size_t)row * 128 + k);
    *(uint4*)(Alds + r * 136 + k) = v;
  }
  __syncthreads();
  int wave = t >> 6, lane = t & 63;
  int m = lane & 15, quad = lane >> 4;
  int arow = wave * 16 + m;
  bfrag a[4];
#pragma unroll
  for (int ks = 0; ks < 4; ++ks)
    a[ks] = *(const bfrag*)(Alds + arow * 136 + ks * 32 + quad * 8);
  f32x4 acc[8];
#pragma unroll
  for (int nt = 0; nt < 8; ++nt) acc[nt] = (f32x4){0.f, 0.f, 0.f, 0.f};
#pragma unroll
  for (int nt = 0; nt < 8; ++nt) {
    int n = nt * 16 + m;
#pragma unroll
    for (int ks = 0; ks < 4; ++ks) {
      bfrag b = *(const bfrag*)(Wlds + n * 136 + ks * 32 + quad * 8);
      acc[nt] = __builtin_amdgcn_mfma_f32_16x16x32_bf16(a[ks], b, acc[nt], 0, 0, 0);
    }
  }
#pragma unroll
  for (int nt = 0; nt < 8; ++nt) {
    int col = nt * 16 + m;
#pragma unroll
    for (int r = 0; r < 4; ++r) {
      int row = base + wave * 16 + quad * 4 + r;
      if (row < M) {
        float v = acc[nt][r];
        if (bias) { float b = bias[col]; v += degi ? b * (float)degi[row] : b; }
        if (relu) v = fmaxf(v, 0.f);
        if (OUTBF16) ((u16*)Cout)[(size_t)row * 128 + col] = f2b(v);
        else         ((float*)Cout)[(size_t)row * 128 + col] = v;
      }
    }
  }
}

// ---------- dual MFMA GEMM: C0 = A@W0 (+bias0), C1 = A@W1 (both bf16) ----------
__global__ __launch_bounds__(256) void gemm_mfma_dual(
    const u16* __restrict__ A, const u16* __restrict__ W0t, const u16* __restrict__ W1t,
    u16* __restrict__ C0, u16* __restrict__ C1, const float* __restrict__ bias0, int M) {
  __shared__ u16 Alds[64 * 136];
  __shared__ u16 Wlds[128 * 136];
  int t = threadIdx.x;
  int base = blockIdx.x * 64;
#pragma unroll
  for (int i = 0; i < 8; ++i) {
    int idx = (i * 256 + t) * 8;
    int n = idx >> 7, k = idx & 127;
    uint4 v = *(const uint4*)(W0t + idx);
    *(uint4*)(Wlds + n * 136 + k) = v;
  }
#pragma unroll
  for (int i = 0; i < 4; ++i) {
    int idx = (i * 256 + t) * 8;
    int r = idx >> 7, k = idx & 127;
    int row = base + r;
    uint4 v = make_uint4(0, 0, 0, 0);
    if (row < M) v = *(const uint4*)(A + (size_t)row * 128 + k);
    *(uint4*)(Alds + r * 136 + k) = v;
  }
  __syncthreads();
  int wave = t >> 6, lane = t & 63;
  int m = lane & 15, quad = lane >> 4;
  int arow = wave * 16 + m;
  bfrag a[4];
#pragma unroll
  for (int ks = 0; ks < 4; ++ks)
    a[ks] = *(const bfrag*)(Alds + arow * 136 + ks * 32 + quad * 8);
  f32x4 acc0[8], acc1[8];
#pragma unroll
  for (int nt = 0; nt < 8; ++nt) { acc0[nt] = (f32x4){0,0,0,0}; acc1[nt] = (f32x4){0,0,0,0}; }
#pragma unroll
  for (int nt = 0; nt < 8; ++nt) {
    int n = nt * 16 + m;
#pragma unroll
    for (int ks = 0; ks < 4; ++ks) {
      bfrag b = *(const bfrag*)(Wlds + n * 136 + ks * 32 + quad * 8);
      acc0[nt] = __builtin_amdgcn_mfma_f32_16x16x32_bf16(a[ks], b, acc0[nt], 0, 0, 0);
    }
  }
  __syncthreads();
#pragma unroll
  for (int i = 0; i < 8; ++i) {
    int idx = (i * 256 + t) * 8;
    int n = idx >> 7, k = idx & 127;
    uint4 v = *(const uint4*)(W1t + idx);
    *(uint4*)(Wlds + n * 136 + k) = v;
  }
  __syncthreads();
#pragma unroll
  for (int nt = 0; nt < 8; ++nt) {
    int n = nt * 16 + m;
#pragma unroll
    for (int ks = 0; ks < 4; ++ks) {
      bfrag b = *(const bfrag*)(Wlds + n * 136 + ks * 32 + quad * 8);
      acc1[nt] = __builtin_amdgcn_mfma_f32_16x16x32_bf16(a[ks], b, acc1[nt], 0, 0, 0);
    }
  }
#pragma unroll
  for (int nt = 0; nt < 8; ++nt) {
    int col = nt * 16 + m;
#pragma unroll
    for (int r = 0; r < 4; ++r) {
      int row = base + wave * 16 + quad * 4 + r;
      if (row < M) {
        float v0 = acc0[nt][r];
        if (bias0) v0 += bias0[col];
        C0[(size_t)row * 128 + col] = f2b(v0);
        C1[(size_t)row * 128 + col] = f2b(acc1[nt][r]);
      }
    }
  }
}

// ---------- penta MFMA GEMM: h = relu(A@W2 + deg*bias); G_k = h @ W_k (k=0..3) ----------
// h lives only in LDS (each wave's own 16-row slab) — never touches global.
__global__ __launch_bounds__(256) void gemm_mfma_penta(
    const u16* __restrict__ A, const u16* __restrict__ W2t, const u16* __restrict__ Wt4,
    const float* __restrict__ bias, const int* __restrict__ degi,
    u16* __restrict__ G0, u16* __restrict__ G1,
    u16* __restrict__ G2, u16* __restrict__ G3, int M) {
  __shared__ u16 Alds[64 * 136];
  __shared__ u16 Wlds[128 * 136];
  int t = threadIdx.x;
  int base = blockIdx.x * 64;
#pragma unroll
  for (int i = 0; i < 8; ++i) {
    int idx = (i * 256 + t) * 8;
    int n = idx >> 7, k = idx & 127;
    uint4 v = *(const uint4*)(W2t + idx);
    *(uint4*)(Wlds + n * 136 + k) = v;
  }
#pragma unroll
  for (int i = 0; i < 4; ++i) {
    int idx = (i * 256 + t) * 8;
    int r = idx >> 7, k = idx & 127;
    int row = base + r;
    uint4 v = make_uint4(0, 0, 0, 0);
    if (row < M) v = *(const uint4*)(A + (size_t)row * 128 + k);
    *(uint4*)(Alds + r * 136 + k) = v;
  }
  __syncthreads();
  int wave = t >> 6, lane = t & 63;
  int m = lane & 15, quad = lane >> 4;
  int arow = wave * 16 + m;
  bfrag a[4];
#pragma unroll
  for (int ks = 0; ks < 4; ++ks)
    a[ks] = *(const bfrag*)(Alds + arow * 136 + ks * 32 + quad * 8);
  // ---- stage 1: h = relu(A@W2 + deg*bias) -> own LDS slab ----
  {
    f32x4 acc[8];
#pragma unroll
    for (int nt = 0; nt < 8; ++nt) acc[nt] = (f32x4){0.f, 0.f, 0.f, 0.f};
#pragma unroll
    for (int nt = 0; nt < 8; ++nt) {
      int n = nt * 16 + m;
#pragma unroll
      for (int ks = 0; ks < 4; ++ks) {
        bfrag b = *(const bfrag*)(Wlds + n * 136 + ks * 32 + quad * 8);
        acc[nt] = __builtin_amdgcn_mfma_f32_16x16x32_bf16(a[ks], b, acc[nt], 0, 0, 0);
      }
    }
#pragma unroll
    for (int nt = 0; nt < 8; ++nt) {
      int col = nt * 16 + m;
#pragma unroll
      for (int r = 0; r < 4; ++r) {
        int lrow = wave * 16 + quad * 4 + r;
        int row = base + lrow;
        float v = 0.f;
        if (row < M) v = fmaxf(acc[nt][r] + bias[col] * (float)degi[row], 0.f);
        Alds[lrow * 136 + col] = f2b(v);   // own wave's slab; in-wave DS ordering
      }
    }
  }
  // reload a-frags (h) from own slab
#pragma unroll
  for (int ks = 0; ks < 4; ++ks)
    a[ks] = *(const bfrag*)(Alds + arow * 136 + ks * 32 + quad * 8);
  // ---- stage 2: G_k = h @ W_k ----
#pragma unroll
  for (int mat = 0; mat < 4; ++mat) {
    __syncthreads();    // all waves done reading Wlds from previous matmul
#pragma unroll
    for (int i = 0; i < 8; ++i) {
      int idx = (i * 256 + t) * 8;
      int n = idx >> 7, k = idx & 127;
      uint4 v = *(const uint4*)(Wt4 + mat * 16384 + idx);
      *(uint4*)(Wlds + n * 136 + k) = v;
    }
    __syncthreads();
    f32x4 acc[8];
#pragma unroll
    for (int nt = 0; nt < 8; ++nt) acc[nt] = (f32x4){0.f, 0.f, 0.f, 0.f};
#pragma unroll
    for (int nt = 0; nt < 8; ++nt) {
      int n = nt * 16 + m;
#pragma unroll
      for (int ks = 0; ks < 4; ++ks) {
        bfrag b = *(const bfrag*)(Wlds + n * 136 + ks * 32 + quad * 8);
        acc[nt] = __builtin_amdgcn_mfma_f32_16x16x32_bf16(a[ks], b, acc[nt], 0, 0, 0);
      }
    }
    u16* G = (mat == 0) ? G0 : (mat == 1) ? G1 : (mat == 2) ? G2 : G3;
#pragma unroll
    for (int nt = 0; nt < 8; ++nt) {
      int col = nt * 16 + m;
#pragma unroll
      for (int r = 0; r < 4; ++r) {
        int row = base + wave * 16 + quad * 4 + r;
        if (row < M) G[(size_t)row * 128 + col] = f2b(acc[nt][r]);
      }
    }
  }
}

// ---------- VALU GEMM (final 128->16) ----------
__global__ __launch_bounds__(128) void gemm_tail(
    const u16* __restrict__ A, const float* __restrict__ W, float* __restrict__ Cout,
    const float* __restrict__ bias, const int* __restrict__ degi, int M) {
  const int ROWS = 8;
  int t = threadIdx.x;
  int base = blockIdx.x * ROWS;
  __shared__ float Al[ROWS * 128];
  for (int i = t; i < ROWS * 128; i += 128) {
    int r = i >> 7, k = i & 127;
    int row = base + r;
    Al[i] = (row < M) ? b2f(A[(size_t)row * 128 + k]) : 0.f;
  }
  __syncthreads();
  int r = t >> 4, u = t & 15;
  int row = base + r;
  float acc = 0.f;
  for (int k = 0; k < 128; ++k) acc += Al[r * 128 + k] * W[k * 16 + u];
  if (row < M) {
    Cout[(size_t)row * 16 + u] = acc + bias[u] * (float)degi[row];
  }
}

// ---------- per-edge bodies (records read from LDS at loop-counter addresses) ----------
__device__ __forceinline__ void tag_edge(const int2* __restrict__ rr, int j,
    const u16* __restrict__ g, int lane, float& x0, float& x1) {
  int2 r = rr[j];
  int s = rfl(r.x); float w = __uint_as_float(rfl(r.y));
  u32 h = *((const u32*)(g + (size_t)s * 128) + lane);
  x0 += w * bflo(h); x1 += w * bfhi(h);
}
__device__ __forceinline__ void ea_edge(const int2* __restrict__ rr, int j,
    const u16* __restrict__ q, const u16* __restrict__ P, int lane,
    float pb0, float pb1, float& x0, float& x1) {
  int2 r = rr[j];
  int s = rfl(r.x), i = rfl(r.y);
  u32 qv = *((const u32*)(q + (size_t)s * 128) + lane);
  u32 pv = *((const u32*)(P + (size_t)i * 128) + lane);
  x0 += fmaxf(pb0 + bflo(qv) + h2lo(pv), 0.f);
  x1 += fmaxf(pb1 + bfhi(qv) + h2hi(pv), 0.f);
}

// ---------- TAG gather v8: 1 node/wave, LDS-staged 64-record batches, 8-edge unroll ----------
template<bool FINAL>
__global__ __launch_bounds__(256) void tag_gather8(
    const u16* __restrict__ g, const u16* __restrict__ Cin,
    const float* __restrict__ bias, const float* __restrict__ dis,
    const int* __restrict__ rowptr, const int2* __restrict__ cw,
    u16* __restrict__ out, int N) {
  __shared__ int2 recs[4][64];
  int wave = threadIdx.x >> 6, lane = threadIdx.x & 63;
  int node = blockIdx.x * 4 + wave;
  if (node >= N) return;
  int e0 = rfl(rowptr[node]);
  int e1 = rfl(rowptr[node + 1]);
  int2* rr = recs[wave];
  float a0 = 0, a1 = 0, b0 = 0, b1 = 0;
  for (int base = e0; base < e1; base += 64) {
    if (base + lane < e1) rr[lane] = cw[base + lane];
    int cnt = min(64, e1 - base);
    int j = 0;
    for (; j + 8 <= cnt; j += 8) {
      tag_edge(rr, j + 0, g, lane, a0, a1);
      tag_edge(rr, j + 1, g, lane, b0, b1);
      tag_edge(rr, j + 2, g, lane, a0, a1);
      tag_edge(rr, j + 3, g, lane, b0, b1);
      tag_edge(rr, j + 4, g, lane, a0, a1);
      tag_edge(rr, j + 5, g, lane, b0, b1);
      tag_edge(rr, j + 6, g, lane, a0, a1);
      tag_edge(rr, j + 7, g, lane, b0, b1);
    }
    for (; j + 2 <= cnt; j += 2) {
      tag_edge(rr, j + 0, g, lane, a0, a1);
      tag_edge(rr, j + 1, g, lane, b0, b1);
    }
    if (j < cnt) tag_edge(rr, j, g, lane, a0, a1);
  }
  float dn = dis[node];
  float r0v = dn * (a0 + b0), r1v = dn * (a1 + b1);
  u32 cin = *((const u32*)(Cin + (size_t)node * 128) + lane);
  r0v += bflo(cin); r1v += bfhi(cin);
  if (FINAL) {
    float2 bv = *(const float2*)(bias + 2 * lane);
    r0v = fmaxf(r0v + bv.x, 0.f);
    r1v = fmaxf(r1v + bv.y, 0.f);
  }
  *((u32*)(out + (size_t)node * 128) + lane) = packb2(r0v, r1v);
}

// ---------- EA gather v8: 1 node/wave, LDS-staged records, 8-edge unroll ----------
__global__ __launch_bounds__(256) void ea_gather8(
    const u16* __restrict__ pb, const u16* __restrict__ q,
    const u16* __restrict__ P /*f16 [E,128]*/,
    const int* __restrict__ rowptr, const int2* __restrict__ ce,
    u16* __restrict__ Hsum, int N) {
  __shared__ int2 recs[4][64];
  int wave = threadIdx.x >> 6, lane = threadIdx.x & 63;
  int node = blockIdx.x * 4 + wave;
  if (node >= N) return;
  int e0 = rfl(rowptr[node]);
  int e1 = rfl(rowptr[node + 1]);
  int2* rr = recs[wave];
  u32 pbu = *((const u32*)(pb + (size_t)node * 128) + lane);
  float pb0 = bflo(pbu), pb1 = bfhi(pbu);
  float a0 = 0, a1 = 0, b0 = 0, b1 = 0;
  for (int base = e0; base < e1; base += 64) {
    if (base + lane < e1) rr[lane] = ce[base + lane];
    int cnt = min(64, e1 - base);
    int j = 0;
    for (; j + 8 <= cnt; j += 8) {
      ea_edge(rr, j + 0, q, P, lane, pb0, pb1, a0, a1);
      ea_edge(rr, j + 1, q, P, lane, pb0, pb1, b0, b1);
      ea_edge(rr, j + 2, q, P, lane, pb0, pb1, a0, a1);
      ea_edge(rr, j + 3, q, P, lane, pb0, pb1, b0, b1);
      ea_edge(rr, j + 4, q, P, lane, pb0, pb1, a0, a1);
      ea_edge(rr, j + 5, q, P, lane, pb0, pb1, b0, b1);
      ea_edge(rr, j + 6, q, P, lane, pb0, pb1, a0, a1);
      ea_edge(rr, j + 7, q, P, lane, pb0, pb1, b0, b1);
    }
    for (; j + 2 <= cnt; j += 2) {
      ea_edge(rr, j + 0, q, P, lane, pb0, pb1, a0, a1);
      ea_edge(rr, j + 1, q, P, lane, pb0, pb1, b0, b1);
    }
    if (j < cnt) ea_edge(rr, j, q, P, lane, pb0, pb1, a0, a1);
  }
  *((u32*)(Hsum + (size_t)node * 128) + lane) = packb2(a0 + b0, a1 + b1);
}

extern "C" void kernel_launch(void* const* d_in, const int* in_sizes, int n_in,
                              void* d_out, int out_size, void* d_ws, size_t ws_size,
                              hipStream_t stream) {
  const float* x      = (const float*)d_in[0];
  const float* mask   = (const float*)d_in[1];
  const float* ea     = (const float*)d_in[2];
  const int*   eidx   = (const int*)d_in[3];
  const float* m_w1   = (const float*)d_in[4];
  const float* m_b1   = (const float*)d_in[5];
  const float* m_w2   = (const float*)d_in[6];
  const float* m_b2   = (const float*)d_in[7];
  const float* ea0_w1 = (const float*)d_in[8];
  const float* ea0_b1 = (const float*)d_in[9];
  const float* ea0_w2 = (const float*)d_in[10];
  const float* ea0_b2 = (const float*)d_in[11];
  const float* tag0_w = (const float*)d_in[12];
  const float* tag0_b = (const float*)d_in[13];
  const float* ea1_w1 = (const float*)d_in[14];
  const float* ea1_b1 = (const float*)d_in[15];
  const float* ea1_w2 = (const float*)d_in[16];
  const float* ea1_b2 = (const float*)d_in[17];
  const float* tag1_w = (const float*)d_in[18];
  const float* tag1_b = (const float*)d_in[19];
  const float* ea2_w1 = (const float*)d_in[20];
  const float* ea2_b1 = (const float*)d_in[21];
  const float* ea2_w2 = (const float*)d_in[22];
  const float* ea2_b2 = (const float*)d_in[23];

  const int N = in_sizes[0] / 16;   // 20000
  const int E = in_sizes[2] / 16;   // 160000
  const int E2 = 2 * E;
  const int NB = (N + 255) / 256;

  char* w = (char*)d_ws;
  auto alloc = [&](size_t bytes) { char* p = w; w += (bytes + 255) & ~(size_t)255; return p; };
  int*   degi   = (int*)alloc((size_t)N * 4);
  int*   cursor = (int*)alloc((size_t)N * 4);
  int*   rowptr = (int*)alloc((size_t)(N + 1) * 4);
  int*   bsum   = (int*)alloc((size_t)256 * 4);
  float* dis    = (float*)alloc((size_t)N * 4);
  int2*  cw     = (int2*)alloc((size_t)E2 * 8);
  int2*  ce     = (int2*)alloc((size_t)E2 * 8);
  u16*   X0     = (u16*)alloc((size_t)N * 128 * 2);
  u16*   X1     = (u16*)alloc((size_t)N * 128 * 2);
  u16*   X2     = (u16*)alloc((size_t)N * 128 * 2);
  u16*   G0     = (u16*)alloc((size_t)N * 128 * 2);
  u16*   G1     = (u16*)alloc((size_t)N * 128 * 2);
  u16*   G2     = (u16*)alloc((size_t)N * 128 * 2);
  u16*   G3     = (u16*)alloc((size_t)N * 128 * 2);
  u16*   Wt     = (u16*)alloc((size_t)14 * 16384 * 2);
  u16*   P0     = (u16*)alloc((size_t)E * 128 * 2);
  u16*   P1     = (u16*)alloc((size_t)E * 128 * 2);
  u16*   P2     = (u16*)alloc((size_t)E * 128 * 2);
  (void)ws_size; (void)n_in; (void)out_size;

  const int PB = (E + 63) / 64;        // 2500 proj blocks
  const int CB = (E + 255) / 256;      // 625 count blocks
  const int FB = (E2 + 255) / 256;     // 1250 fill blocks
  const int HB = (N + 15) / 16;        // 1250 head blocks
  const int gm = (N + 63) / 64;
  const int g4 = (N + 3) / 4;
  const int gb = (N + 7) / 8;

  u16* WT_ea0w2  = Wt + 0 * 16384;
  u16* WT_tag0   = Wt + 1 * 16384;
  u16* WT_ea1d   = Wt + 5 * 16384;
  u16* WT_ea1s   = Wt + 6 * 16384;
  u16* WT_ea1w2  = Wt + 7 * 16384;
  u16* WT_tag1   = Wt + 8 * 16384;
  u16* WT_ea2d   = Wt + 12 * 16384;
  u16* WT_ea2s   = Wt + 13 * 16384;

  // ---- prologue: proj + count + weight prep (degi zeroed by memset) ----
  hipMemsetAsync(degi, 0, (size_t)N * 4, stream);
  prologue<<<PB + CB + 112, 256, 0, stream>>>(ea, eidx, ea0_w1, ea0_w2, tag0_w,
                                              ea1_w1, ea1_w2, tag1_w, ea2_w1,
                                              P0, P1, P2, degi, Wt, E, N, PB, CB);
  scan1<<<NB, 256, 0, stream>>>(degi, bsum, N);
  scan2<<<1, 256, 0, stream>>>(bsum, rowptr, NB, N);
  scan3<<<NB, 256, 0, stream>>>(degi, bsum, rowptr, cursor, dis, N);
  fill_head<<<FB + HB, 256, 0, stream>>>(eidx, cursor, dis, cw, ce, E,
                                         mask, x, m_w1, m_b1, m_w2, m_b2,
                                         ea0_w1, ea0_b1, X0, X1, N, FB);

  // ---- EA0 + TAG0 GEMMs fused ----
  ea_gather8<<<g4, 256, 0, stream>>>(X0, X1, P0, rowptr, ce, X2, N);
  gemm_mfma_penta<<<gm, 256, 0, stream>>>(X2, WT_ea0w2, WT_tag0, ea0_b2, degi,
                                          G0, G1, G2, G3, N);
  tag_gather8<false><<<g4, 256, 0, stream>>>(G3, G2, nullptr, dis, rowptr, cw, X1, N);
  tag_gather8<false><<<g4, 256, 0, stream>>>(X1, G1, nullptr, dis, rowptr, cw, X2, N);
  tag_gather8<true><<<g4, 256, 0, stream>>>(X2, G0, tag0_b, dis, rowptr, cw, X0, N);  // h2 -> X0

  // ---- EA1 + TAG1 ----
  gemm_mfma_dual<<<gm, 256, 0, stream>>>(X0, WT_ea1d, WT_ea1s, X1, X2, ea1_b1, N);
  ea_gather8<<<g4, 256, 0, stream>>>(X1, X2, P1, rowptr, ce, G0, N);
  gemm_mfma_penta<<<gm, 256, 0, stream>>>(G0, WT_ea1w2, WT_tag1, ea1_b2, degi,
                                          G0, G1, G2, G3, N);   // in-place A=G0 safe (block-local rows)
  tag_gather8<false><<<g4, 256, 0, stream>>>(G3, G2, nullptr, dis, rowptr, cw, X1, N);
  tag_gather8<false><<<g4, 256, 0, stream>>>(X1, G1, nullptr, dis, rowptr, cw, X2, N);
  tag_gather8<true><<<g4, 256, 0, stream>>>(X2, G0, tag1_b, dis, rowptr, cw, X0, N);  // h4 -> X0

  // ---- EA2 (final, out 16, fp32) ----
  gemm_mfma_dual<<<gm, 256, 0, stream>>>(X0, WT_ea2d, WT_ea2s, X1, X2, ea2_b1, N);
  ea_gather8<<<g4, 256, 0, stream>>>(X1, X2, P2, rowptr, ce, G0, N);
  gemm_tail<<<gb, 128, 0, stream>>>(G0, ea2_w2, (float*)d_out, ea2_b2, degi, N);
}

// Round 14
// 421.795 us; speedup vs baseline: 1.1644x; 1.0065x over previous
//
#include <hip/hip_runtime.h>

typedef unsigned short u16;
typedef unsigned int u32;

using bfrag  = __attribute__((ext_vector_type(8))) short;   // 8 bf16 (4 VGPRs)
using f32x4  = __attribute__((ext_vector_type(4))) float;   // 4 fp32 acc
using f32x16 = __attribute__((ext_vector_type(16))) float;  // 16 fp32 acc (32x32 MFMA)

// ---------- bf16 / f16 helpers ----------
__device__ __forceinline__ float b2f(u16 u) {
  union { u32 i; float f; } c; c.i = ((u32)u) << 16; return c.f;
}
__device__ __forceinline__ float bflo(u32 u) { union { u32 i; float f; } c; c.i = u << 16; return c.f; }
__device__ __forceinline__ float bfhi(u32 u) { union { u32 i; float f; } c; c.i = u & 0xffff0000u; return c.f; }
__device__ __forceinline__ u16 f2b(float f) {  // round-to-nearest-even
  union { float f; u32 i; } c; c.f = f;
  u32 x = c.i;
  u32 r = x + 0x7fffu + ((x >> 16) & 1u);
  return (u16)(r >> 16);
}
__device__ __forceinline__ u32 packb2(float x, float y) {
  return ((u32)f2b(x)) | (((u32)f2b(y)) << 16);
}
__device__ __forceinline__ u16 f2h(float x) {
  union { _Float16 h; u16 u; } c; c.h = (_Float16)x; return c.u;
}
__device__ __forceinline__ float h2lo(u32 u) { union { u32 i; _Float16 h[2]; } c; c.i = u; return (float)c.h[0]; }
__device__ __forceinline__ float h2hi(u32 u) { union { u32 i; _Float16 h[2]; } c; c.i = u; return (float)c.h[1]; }
__device__ __forceinline__ int rfl(int v) { return __builtin_amdgcn_readfirstlane(v); }

// ---------- prologue: blocks [0,PB) edge-proj MFMA; [PB,PB+CB) count_deg; rest prep_wt ----------
__global__ __launch_bounds__(256) void prologue(
    const float* __restrict__ ea, const int* __restrict__ eidx,
    const float* __restrict__ ea0_w1, const float* __restrict__ ea0_w2,
    const float* __restrict__ tag0_w, const float* __restrict__ ea1_w1,
    const float* __restrict__ ea1_w2, const float* __restrict__ tag1_w,
    const float* __restrict__ ea2_w1,
    u16* __restrict__ P0, u16* __restrict__ P1, u16* __restrict__ P2,
    int* __restrict__ degi, u16* __restrict__ Wt, int E, int N,
    int PB, int CB) {
  int t = threadIdx.x;
  if (blockIdx.x < (unsigned)PB) {
    // ---- edge projection via MFMA 32x32x16: P_l[e,:] = ea[e,:16] @ W_l (f16 out) ----
    __shared__ u16 Alds[64 * 16];
    __shared__ u16 Wlds[3 * 2048];
    int base = blockIdx.x * 64;
    int rows = E - base; if (rows > 64) rows = 64;
    const float* wsrc[3] = { ea0_w1 + 32 * 128, ea1_w1 + 256 * 128, ea2_w1 + 256 * 128 };
#pragma unroll
    for (int i = 0; i < 8; ++i) {
      int idx = i * 256 + t;             // 0..2047
      int n = idx >> 4, k = idx & 15;
      Wlds[0 * 2048 + idx] = f2b(wsrc[0][k * 128 + n]);
      Wlds[1 * 2048 + idx] = f2b(wsrc[1][k * 128 + n]);
      Wlds[2 * 2048 + idx] = f2b(wsrc[2][k * 128 + n]);
    }
#pragma unroll
    for (int i = 0; i < 4; ++i) {
      int idx = (i * 256 + t) * 4;
      float4 v = make_float4(0.f, 0.f, 0.f, 0.f);
      if ((idx >> 4) < rows) v = *(const float4*)(ea + (size_t)base * 16 + idx);
      ushort4 h;
      h.x = f2b(v.x); h.y = f2b(v.y); h.z = f2b(v.z); h.w = f2b(v.w);
      *(ushort4*)(Alds + idx) = h;
    }
    __syncthreads();
    int wave = t >> 6, lane = t & 63;
    int rowt = (wave >> 1) * 32;
    int colt = (wave & 1) * 64;
    int mm = lane & 31, kh = lane >> 5;
    bfrag a = *(const bfrag*)(Alds + (rowt + mm) * 16 + kh * 8);
#pragma unroll
    for (int tab = 0; tab < 3; ++tab) {
      const u16* wl = Wlds + tab * 2048;
      // adjacent-column pair in one lane: b0 = col (colt+2mm), b1 = col (colt+2mm+1)
      bfrag b0 = *(const bfrag*)(wl + (colt + 2 * mm) * 16 + kh * 8);
      bfrag b1 = *(const bfrag*)(wl + (colt + 2 * mm + 1) * 16 + kh * 8);
      f32x16 acc0, acc1;
#pragma unroll
      for (int z = 0; z < 16; ++z) { acc0[z] = 0.f; acc1[z] = 0.f; }
      acc0 = __builtin_amdgcn_mfma_f32_32x32x16_bf16(a, b0, acc0, 0, 0, 0);
      acc1 = __builtin_amdgcn_mfma_f32_32x32x16_bf16(a, b1, acc1, 0, 0, 0);
      u16* P = (tab == 0) ? P0 : (tab == 1) ? P1 : P2;
#pragma unroll
      for (int reg = 0; reg < 16; ++reg) {
        int row = rowt + (reg & 3) + 8 * (reg >> 2) + 4 * kh;
        if (row < rows) {
          // packed u32 store: cols (colt+2mm, colt+2mm+1) of this row — full-line combining
          u32 pr = ((u32)f2h(acc0[reg])) | (((u32)f2h(acc1[reg])) << 16);
          *(u32*)(P + (size_t)(base + row) * 128 + colt + 2 * mm) = pr;
        }
      }
    }
    return;
  }
  if (blockIdx.x < (unsigned)(PB + CB)) {
    // ---- count_deg (degi pre-zeroed by memset) ----
    int e = (blockIdx.x - PB) * 256 + t;
    if (e < E) {
      atomicAdd(&degi[eidx[E + e]], 1);
      atomicAdd(&degi[eidx[e]], 1);
    }
    return;
  }
  // ---- prep_wt: 14x fp32 [128][128] -> bf16 [n][k] ----
  int wb = blockIdx.x - PB - CB;          // 0..111
  int mat = wb >> 3, chunk = wb & 7;
  const float* src;
  if      (mat == 0)  src = ea0_w2;
  else if (mat <= 4)  src = tag0_w + (mat - 1) * 16384;
  else if (mat == 5)  src = ea1_w1;
  else if (mat == 6)  src = ea1_w1 + 16384;
  else if (mat == 7)  src = ea1_w2;
  else if (mat <= 11) src = tag1_w + (mat - 8) * 16384;
  else if (mat == 12) src = ea2_w1;
  else                src = ea2_w1 + 16384;
  u16* dst = Wt + mat * 16384;
  for (int i = 0; i < 8; ++i) {
    int idx = chunk * 2048 + i * 256 + t;
    int k = idx >> 7, n = idx & 127;
    dst[n * 128 + k] = f2b(src[idx]);
  }
}

// ---------- parallel scan ----------
__global__ __launch_bounds__(256) void scan1(const int* __restrict__ degi,
                                             int* __restrict__ bsum, int N) {
  __shared__ int sh[256];
  int t = threadIdx.x;
  int gid = blockIdx.x * 256 + t;
  sh[t] = (gid < N) ? degi[gid] : 0;
  __syncthreads();
  for (int off = 128; off > 0; off >>= 1) {
    if (t < off) sh[t] += sh[t + off];
    __syncthreads();
  }
  if (t == 0) bsum[blockIdx.x] = sh[0];
}

__global__ __launch_bounds__(256) void scan2(int* __restrict__ bsum,
                                             int* __restrict__ rowptr, int nb, int N) {
  __shared__ int sh[256];
  int t = threadIdx.x;
  int v = (t < nb) ? bsum[t] : 0;
  sh[t] = v;
  __syncthreads();
  for (int off = 1; off < 256; off <<= 1) {
    int x = sh[t];
    int add = (t >= off) ? sh[t - off] : 0;
    __syncthreads();
    sh[t] = x + add;
    __syncthreads();
  }
  if (t < nb) bsum[t] = sh[t] - v;
  if (t == nb - 1) rowptr[N] = sh[t];
}

__global__ __launch_bounds__(256) void scan3(const int* __restrict__ degi,
                                             const int* __restrict__ bsum,
                                             int* __restrict__ rowptr,
                                             int* __restrict__ cursor,
                                             float* __restrict__ dis, int N) {
  __shared__ int sh[256];
  int t = threadIdx.x;
  int gid = blockIdx.x * 256 + t;
  int d = (gid < N) ? degi[gid] : 0;
  sh[t] = d;
  __syncthreads();
  for (int off = 1; off < 256; off <<= 1) {
    int x = sh[t];
    int add = (t >= off) ? sh[t - off] : 0;
    __syncthreads();
    sh[t] = x + add;
    __syncthreads();
  }
  if (gid < N) {
    int run = bsum[blockIdx.x] + sh[t] - d;
    rowptr[gid] = run;
    cursor[gid] = run;
    dis[gid] = d > 0 ? rsqrtf((float)d) : 0.0f;
  }
}

// ---------- fill_head: blocks [0,FB) fill_csr; [FB,FB+HB) head MLP (16 rows/block) ----------
__global__ __launch_bounds__(256) void fill_head(
    const int* __restrict__ eidx, int* __restrict__ cursor,
    const float* __restrict__ dis, int2* __restrict__ cw, int2* __restrict__ ce, int E,
    const float* __restrict__ mask, const float* __restrict__ x,
    const float* __restrict__ m_w1, const float* __restrict__ m_b1,
    const float* __restrict__ m_w2, const float* __restrict__ m_b2,
    const float* __restrict__ ea0_w1, const float* __restrict__ ea0_b1,
    u16* __restrict__ pb, u16* __restrict__ q, int M, int FB) {
  int t = threadIdx.x;
  if (blockIdx.x < (unsigned)FB) {
    int i = blockIdx.x * 256 + t;
    int E2 = 2 * E;
    if (i >= E2) return;
    int e = (i < E) ? i : i - E;
    int s, d;
    if (i < E) { s = eidx[e]; d = eidx[E + e]; }
    else       { s = eidx[E + e]; d = eidx[e]; }
    int pos = atomicAdd(&cursor[d], 1);
    cw[pos] = make_int2(s, __float_as_int(dis[s]));
    ce[pos] = make_int2(s, e);
    return;
  }
  // ---- head: h16 = relu(mask@w1+b1)@w2 + b2 + x; pb = h16@Wd + b1', q = h16@Ws ----
  __shared__ float Ml[16 * 16];
  __shared__ float T1[16 * 128];
  __shared__ float H[16 * 16];
  int base = (blockIdx.x - FB) * 16;
  {
    int r = t >> 4, k = t & 15;
    int row = base + r;
    Ml[t] = (row < M) ? mask[(size_t)row * 16 + k] : 0.f;
  }
  __syncthreads();
  {
    int col = t & 127, h2 = t >> 7;
    float acc[8];
    float b1v = m_b1[col];
#pragma unroll
    for (int r = 0; r < 8; ++r) acc[r] = b1v;
    for (int k = 0; k < 16; ++k) {
      float w = m_w1[k * 128 + col];
#pragma unroll
      for (int r = 0; r < 8; ++r) acc[r] += Ml[(h2 * 8 + r) * 16 + k] * w;
    }
#pragma unroll
    for (int r = 0; r < 8; ++r) T1[(h2 * 8 + r) * 128 + col] = fmaxf(acc[r], 0.f);
  }
  __syncthreads();
  {
    int r = t >> 4, u = t & 15;
    float acc = m_b2[u];
    for (int k = 0; k < 128; ++k) acc += T1[r * 128 + k] * m_w2[k * 16 + u];
    int row = base + r;
    float xv = (row < M) ? x[(size_t)row * 16 + u] : 0.f;
    H[t] = acc + xv;
  }
  __syncthreads();
  {
    int col = t & 127, h2 = t >> 7;
    float aP[8], aQ[8];
    float b1v = ea0_b1[col];
#pragma unroll
    for (int r = 0; r < 8; ++r) { aP[r] = b1v; aQ[r] = 0.f; }
    for (int k = 0; k < 16; ++k) {
      float wd = ea0_w1[k * 128 + col];
      float ws = ea0_w1[(16 + k) * 128 + col];
#pragma unroll
      for (int r = 0; r < 8; ++r) {
        float h = H[(h2 * 8 + r) * 16 + k];
        aP[r] += h * wd;
        aQ[r] += h * ws;
      }
    }
#pragma unroll
    for (int r = 0; r < 8; ++r) {
      int row = base + h2 * 8 + r;
      if (row < M) {
        pb[(size_t)row * 128 + col] = f2b(aP[r]);
        q[(size_t)row * 128 + col]  = f2b(aQ[r]);
      }
    }
  }
}

// ---------- dual MFMA GEMM: C0 = A@W0 (+bias0), C1 = A@W1 (both bf16) ----------
__global__ __launch_bounds__(256) void gemm_mfma_dual(
    const u16* __restrict__ A, const u16* __restrict__ W0t, const u16* __restrict__ W1t,
    u16* __restrict__ C0, u16* __restrict__ C1, const float* __restrict__ bias0, int M) {
  __shared__ u16 Alds[64 * 136];
  __shared__ u16 Wlds[128 * 136];
  int t = threadIdx.x;
  int base = blockIdx.x * 64;
#pragma unroll
  for (int i = 0; i < 8; ++i) {
    int idx = (i * 256 + t) * 8;
    int n = idx >> 7, k = idx & 127;
    uint4 v = *(const uint4*)(W0t + idx);
    *(uint4*)(Wlds + n * 136 + k) = v;
  }
#pragma unroll
  for (int i = 0; i < 4; ++i) {
    int idx = (i * 256 + t) * 8;
    int r = idx >> 7, k = idx & 127;
    int row = base + r;
    uint4 v = make_uint4(0, 0, 0, 0);
    if (row < M) v = *(const uint4*)(A + (size_t)row * 128 + k);
    *(uint4*)(Alds + r * 136 + k) = v;
  }
  __syncthreads();
  int wave = t >> 6, lane = t & 63;
  int m = lane & 15, quad = lane >> 4;
  int arow = wave * 16 + m;
  bfrag a[4];
#pragma unroll
  for (int ks = 0; ks < 4; ++ks)
    a[ks] = *(const bfrag*)(Alds + arow * 136 + ks * 32 + quad * 8);
  f32x4 acc0[8], acc1[8];
#pragma unroll
  for (int nt = 0; nt < 8; ++nt) { acc0[nt] = (f32x4){0,0,0,0}; acc1[nt] = (f32x4){0,0,0,0}; }
#pragma unroll
  for (int nt = 0; nt < 8; ++nt) {
    int n = nt * 16 + m;
#pragma unroll
    for (int ks = 0; ks < 4; ++ks) {
      bfrag b = *(const bfrag*)(Wlds + n * 136 + ks * 32 + quad * 8);
      acc0[nt] = __builtin_amdgcn_mfma_f32_16x16x32_bf16(a[ks], b, acc0[nt], 0, 0, 0);
    }
  }
  __syncthreads();
#pragma unroll
  for (int i = 0; i < 8; ++i) {
    int idx = (i * 256 + t) * 8;
    int n = idx >> 7, k = idx & 127;
    uint4 v = *(const uint4*)(W1t + idx);
    *(uint4*)(Wlds + n * 136 + k) = v;
  }
  __syncthreads();
#pragma unroll
  for (int nt = 0; nt < 8; ++nt) {
    int n = nt * 16 + m;
#pragma unroll
    for (int ks = 0; ks < 4; ++ks) {
      bfrag b = *(const bfrag*)(Wlds + n * 136 + ks * 32 + quad * 8);
      acc1[nt] = __builtin_amdgcn_mfma_f32_16x16x32_bf16(a[ks], b, acc1[nt], 0, 0, 0);
    }
  }
#pragma unroll
  for (int nt = 0; nt < 8; ++nt) {
    int col = nt * 16 + m;
#pragma unroll
    for (int r = 0; r < 4; ++r) {
      int row = base + wave * 16 + quad * 4 + r;
      if (row < M) {
        float v0 = acc0[nt][r];
        if (bias0) v0 += bias0[col];
        C0[(size_t)row * 128 + col] = f2b(v0);
        C1[(size_t)row * 128 + col] = f2b(acc1[nt][r]);
      }
    }
  }
}

// ---------- penta MFMA GEMM: h = relu(A@W2 + deg*bias); G_k = h @ W_k (k=0..3) ----------
__global__ __launch_bounds__(256) void gemm_mfma_penta(
    const u16* __restrict__ A, const u16* __restrict__ W2t, const u16* __restrict__ Wt4,
    const float* __restrict__ bias, const int* __restrict__ degi,
    u16* __restrict__ G0, u16* __restrict__ G1,
    u16* __restrict__ G2, u16* __restrict__ G3, int M) {
  __shared__ u16 Alds[64 * 136];
  __shared__ u16 Wlds[128 * 136];
  int t = threadIdx.x;
  int base = blockIdx.x * 64;
#pragma unroll
  for (int i = 0; i < 8; ++i) {
    int idx = (i * 256 + t) * 8;
    int n = idx >> 7, k = idx & 127;
    uint4 v = *(const uint4*)(W2t + idx);
    *(uint4*)(Wlds + n * 136 + k) = v;
  }
#pragma unroll
  for (int i = 0; i < 4; ++i) {
    int idx = (i * 256 + t) * 8;
    int r = idx >> 7, k = idx & 127;
    int row = base + r;
    uint4 v = make_uint4(0, 0, 0, 0);
    if (row < M) v = *(const uint4*)(A + (size_t)row * 128 + k);
    *(uint4*)(Alds + r * 136 + k) = v;
  }
  __syncthreads();
  int wave = t >> 6, lane = t & 63;
  int m = lane & 15, quad = lane >> 4;
  int arow = wave * 16 + m;
  bfrag a[4];
#pragma unroll
  for (int ks = 0; ks < 4; ++ks)
    a[ks] = *(const bfrag*)(Alds + arow * 136 + ks * 32 + quad * 8);
  {
    f32x4 acc[8];
#pragma unroll
    for (int nt = 0; nt < 8; ++nt) acc[nt] = (f32x4){0.f, 0.f, 0.f, 0.f};
#pragma unroll
    for (int nt = 0; nt < 8; ++nt) {
      int n = nt * 16 + m;
#pragma unroll
      for (int ks = 0; ks < 4; ++ks) {
        bfrag b = *(const bfrag*)(Wlds + n * 136 + ks * 32 + quad * 8);
        acc[nt] = __builtin_amdgcn_mfma_f32_16x16x32_bf16(a[ks], b, acc[nt], 0, 0, 0);
      }
    }
#pragma unroll
    for (int nt = 0; nt < 8; ++nt) {
      int col = nt * 16 + m;
#pragma unroll
      for (int r = 0; r < 4; ++r) {
        int lrow = wave * 16 + quad * 4 + r;
        int row = base + lrow;
        float v = 0.f;
        if (row < M) v = fmaxf(acc[nt][r] + bias[col] * (float)degi[row], 0.f);
        Alds[lrow * 136 + col] = f2b(v);   // own wave's slab; in-wave DS ordering
      }
    }
  }
#pragma unroll
  for (int ks = 0; ks < 4; ++ks)
    a[ks] = *(const bfrag*)(Alds + arow * 136 + ks * 32 + quad * 8);
#pragma unroll
  for (int mat = 0; mat < 4; ++mat) {
    __syncthreads();
#pragma unroll
    for (int i = 0; i < 8; ++i) {
      int idx = (i * 256 + t) * 8;
      int n = idx >> 7, k = idx & 127;
      uint4 v = *(const uint4*)(Wt4 + mat * 16384 + idx);
      *(uint4*)(Wlds + n * 136 + k) = v;
    }
    __syncthreads();
    f32x4 acc[8];
#pragma unroll
    for (int nt = 0; nt < 8; ++nt) acc[nt] = (f32x4){0.f, 0.f, 0.f, 0.f};
#pragma unroll
    for (int nt = 0; nt < 8; ++nt) {
      int n = nt * 16 + m;
#pragma unroll
      for (int ks = 0; ks < 4; ++ks) {
        bfrag b = *(const bfrag*)(Wlds + n * 136 + ks * 32 + quad * 8);
        acc[nt] = __builtin_amdgcn_mfma_f32_16x16x32_bf16(a[ks], b, acc[nt], 0, 0, 0);
      }
    }
    u16* G = (mat == 0) ? G0 : (mat == 1) ? G1 : (mat == 2) ? G2 : G3;
#pragma unroll
    for (int nt = 0; nt < 8; ++nt) {
      int col = nt * 16 + m;
#pragma unroll
      for (int r = 0; r < 4; ++r) {
        int row = base + wave * 16 + quad * 4 + r;
        if (row < M) G[(size_t)row * 128 + col] = f2b(acc[nt][r]);
      }
    }
  }
}

// ---------- VALU GEMM (final 128->16) ----------
__global__ __launch_bounds__(128) void gemm_tail(
    const u16* __restrict__ A, const float* __restrict__ W, float* __restrict__ Cout,
    const float* __restrict__ bias, const int* __restrict__ degi, int M) {
  const int ROWS = 8;
  int t = threadIdx.x;
  int base = blockIdx.x * ROWS;
  __shared__ float Al[ROWS * 128];
  for (int i = t; i < ROWS * 128; i += 128) {
    int r = i >> 7, k = i & 127;
    int row = base + r;
    Al[i] = (row < M) ? b2f(A[(size_t)row * 128 + k]) : 0.f;
  }
  __syncthreads();
  int r = t >> 4, u = t & 15;
  int row = base + r;
  float acc = 0.f;
  for (int k = 0; k < 128; ++k) acc += Al[r * 128 + k] * W[k * 16 + u];
  if (row < M) {
    Cout[(size_t)row * 16 + u] = acc + bias[u] * (float)degi[row];
  }
}

// ---------- per-edge bodies (records read from LDS at loop-counter addresses) ----------
__device__ __forceinline__ void tag_edge(const int2* __restrict__ rr, int j,
    const u16* __restrict__ g, int lane, float& x0, float& x1) {
  int2 r = rr[j];
  int s = rfl(r.x); float w = __uint_as_float(rfl(r.y));
  u32 h = *((const u32*)(g + (size_t)s * 128) + lane);
  x0 += w * bflo(h); x1 += w * bfhi(h);
}
__device__ __forceinline__ void ea_edge(const int2* __restrict__ rr, int j,
    const u16* __restrict__ q, const u16* __restrict__ P, int lane,
    float pb0, float pb1, float& x0, float& x1) {
  int2 r = rr[j];
  int s = rfl(r.x), i = rfl(r.y);
  u32 qv = *((const u32*)(q + (size_t)s * 128) + lane);
  u32 pv = *((const u32*)(P + (size_t)i * 128) + lane);
  x0 += fmaxf(pb0 + bflo(qv) + h2lo(pv), 0.f);
  x1 += fmaxf(pb1 + bfhi(qv) + h2hi(pv), 0.f);
}

// ---------- TAG gather v8: 1 node/wave, LDS-staged 64-record batches, 8-edge unroll ----------
template<bool FINAL>
__global__ __launch_bounds__(256) void tag_gather8(
    const u16* __restrict__ g, const u16* __restrict__ Cin,
    const float* __restrict__ bias, const float* __restrict__ dis,
    const int* __restrict__ rowptr, const int2* __restrict__ cw,
    u16* __restrict__ out, int N) {
  __shared__ int2 recs[4][64];
  int wave = threadIdx.x >> 6, lane = threadIdx.x & 63;
  int node = blockIdx.x * 4 + wave;
  if (node >= N) return;
  int e0 = rfl(rowptr[node]);
  int e1 = rfl(rowptr[node + 1]);
  int2* rr = recs[wave];
  float a0 = 0, a1 = 0, b0 = 0, b1 = 0;
  for (int base = e0; base < e1; base += 64) {
    if (base + lane < e1) rr[lane] = cw[base + lane];
    int cnt = min(64, e1 - base);
    int j = 0;
    for (; j + 8 <= cnt; j += 8) {
      tag_edge(rr, j + 0, g, lane, a0, a1);
      tag_edge(rr, j + 1, g, lane, b0, b1);
      tag_edge(rr, j + 2, g, lane, a0, a1);
      tag_edge(rr, j + 3, g, lane, b0, b1);
      tag_edge(rr, j + 4, g, lane, a0, a1);
      tag_edge(rr, j + 5, g, lane, b0, b1);
      tag_edge(rr, j + 6, g, lane, a0, a1);
      tag_edge(rr, j + 7, g, lane, b0, b1);
    }
    for (; j + 2 <= cnt; j += 2) {
      tag_edge(rr, j + 0, g, lane, a0, a1);
      tag_edge(rr, j + 1, g, lane, b0, b1);
    }
    if (j < cnt) tag_edge(rr, j, g, lane, a0, a1);
  }
  float dn = dis[node];
  float r0v = dn * (a0 + b0), r1v = dn * (a1 + b1);
  u32 cin = *((const u32*)(Cin + (size_t)node * 128) + lane);
  r0v += bflo(cin); r1v += bfhi(cin);
  if (FINAL) {
    float2 bv = *(const float2*)(bias + 2 * lane);
    r0v = fmaxf(r0v + bv.x, 0.f);
    r1v = fmaxf(r1v + bv.y, 0.f);
  }
  *((u32*)(out + (size_t)node * 128) + lane) = packb2(r0v, r1v);
}

// ---------- EA gather v8: 1 node/wave, LDS-staged records, 8-edge unroll ----------
__global__ __launch_bounds__(256) void ea_gather8(
    const u16* __restrict__ pb, const u16* __restrict__ q,
    const u16* __restrict__ P /*f16 [E,128]*/,
    const int* __restrict__ rowptr, const int2* __restrict__ ce,
    u16* __restrict__ Hsum, int N) {
  __shared__ int2 recs[4][64];
  int wave = threadIdx.x >> 6, lane = threadIdx.x & 63;
  int node = blockIdx.x * 4 + wave;
  if (node >= N) return;
  int e0 = rfl(rowptr[node]);
  int e1 = rfl(rowptr[node + 1]);
  int2* rr = recs[wave];
  u32 pbu = *((const u32*)(pb + (size_t)node * 128) + lane);
  float pb0 = bflo(pbu), pb1 = bfhi(pbu);
  float a0 = 0, a1 = 0, b0 = 0, b1 = 0;
  for (int base = e0; base < e1; base += 64) {
    if (base + lane < e1) rr[lane] = ce[base + lane];
    int cnt = min(64, e1 - base);
    int j = 0;
    for (; j + 8 <= cnt; j += 8) {
      ea_edge(rr, j + 0, q, P, lane, pb0, pb1, a0, a1);
      ea_edge(rr, j + 1, q, P, lane, pb0, pb1, b0, b1);
      ea_edge(rr, j + 2, q, P, lane, pb0, pb1, a0, a1);
      ea_edge(rr, j + 3, q, P, lane, pb0, pb1, b0, b1);
      ea_edge(rr, j + 4, q, P, lane, pb0, pb1, a0, a1);
      ea_edge(rr, j + 5, q, P, lane, pb0, pb1, b0, b1);
      ea_edge(rr, j + 6, q, P, lane, pb0, pb1, a0, a1);
      ea_edge(rr, j + 7, q, P, lane, pb0, pb1, b0, b1);
    }
    for (; j + 2 <= cnt; j += 2) {
      ea_edge(rr, j + 0, q, P, lane, pb0, pb1, a0, a1);
      ea_edge(rr, j + 1, q, P, lane, pb0, pb1, b0, b1);
    }
    if (j < cnt) ea_edge(rr, j, q, P, lane, pb0, pb1, a0, a1);
  }
  *((u32*)(Hsum + (size_t)node * 128) + lane) = packb2(a0 + b0, a1 + b1);
}

extern "C" void kernel_launch(void* const* d_in, const int* in_sizes, int n_in,
                              void* d_out, int out_size, void* d_ws, size_t ws_size,
                              hipStream_t stream) {
  const float* x      = (const float*)d_in[0];
  const float* mask   = (const float*)d_in[1];
  const float* ea     = (const float*)d_in[2];
  const int*   eidx   = (const int*)d_in[3];
  const float* m_w1   = (const float*)d_in[4];
  const float* m_b1   = (const float*)d_in[5];
  const float* m_w2   = (const float*)d_in[6];
  const float* m_b2   = (const float*)d_in[7];
  const float* ea0_w1 = (const float*)d_in[8];
  const float* ea0_b1 = (const float*)d_in[9];
  const float* ea0_w2 = (const float*)d_in[10];
  const float* ea0_b2 = (const float*)d_in[11];
  const float* tag0_w = (const float*)d_in[12];
  const float* tag0_b = (const float*)d_in[13];
  const float* ea1_w1 = (const float*)d_in[14];
  const float* ea1_b1 = (const float*)d_in[15];
  const float* ea1_w2 = (const float*)d_in[16];
  const float* ea1_b2 = (const float*)d_in[17];
  const float* tag1_w = (const float*)d_in[18];
  const float* tag1_b = (const float*)d_in[19];
  const float* ea2_w1 = (const float*)d_in[20];
  const float* ea2_b1 = (const float*)d_in[21];
  const float* ea2_w2 = (const float*)d_in[22];
  const float* ea2_b2 = (const float*)d_in[23];

  const int N = in_sizes[0] / 16;   // 20000
  const int E = in_sizes[2] / 16;   // 160000
  const int E2 = 2 * E;
  const int NB = (N + 255) / 256;

  char* w = (char*)d_ws;
  auto alloc = [&](size_t bytes) { char* p = w; w += (bytes + 255) & ~(size_t)255; return p; };
  int*   degi   = (int*)alloc((size_t)N * 4);
  int*   cursor = (int*)alloc((size_t)N * 4);
  int*   rowptr = (int*)alloc((size_t)(N + 1) * 4);
  int*   bsum   = (int*)alloc((size_t)256 * 4);
  float* dis    = (float*)alloc((size_t)N * 4);
  int2*  cw     = (int2*)alloc((size_t)E2 * 8);
  int2*  ce     = (int2*)alloc((size_t)E2 * 8);
  u16*   X0     = (u16*)alloc((size_t)N * 128 * 2);
  u16*   X1     = (u16*)alloc((size_t)N * 128 * 2);
  u16*   X2     = (u16*)alloc((size_t)N * 128 * 2);
  u16*   G0     = (u16*)alloc((size_t)N * 128 * 2);
  u16*   G1     = (u16*)alloc((size_t)N * 128 * 2);
  u16*   G2     = (u16*)alloc((size_t)N * 128 * 2);
  u16*   G3     = (u16*)alloc((size_t)N * 128 * 2);
  u16*   Wt     = (u16*)alloc((size_t)14 * 16384 * 2);
  u16*   P0     = (u16*)alloc((size_t)E * 128 * 2);
  u16*   P1     = (u16*)alloc((size_t)E * 128 * 2);
  u16*   P2     = (u16*)alloc((size_t)E * 128 * 2);
  (void)ws_size; (void)n_in; (void)out_size;

  const int PB = (E + 63) / 64;        // 2500 proj blocks
  const int CB = (E + 255) / 256;      // 625 count blocks
  const int FB = (E2 + 255) / 256;     // 1250 fill blocks
  const int HB = (N + 15) / 16;        // 1250 head blocks
  const int gm = (N + 63) / 64;
  const int g4 = (N + 3) / 4;
  const int gb = (N + 7) / 8;

  u16* WT_ea0w2  = Wt + 0 * 16384;
  u16* WT_tag0   = Wt + 1 * 16384;
  u16* WT_ea1d   = Wt + 5 * 16384;
  u16* WT_ea1s   = Wt + 6 * 16384;
  u16* WT_ea1w2  = Wt + 7 * 16384;
  u16* WT_tag1   = Wt + 8 * 16384;
  u16* WT_ea2d   = Wt + 12 * 16384;
  u16* WT_ea2s   = Wt + 13 * 16384;

  // ---- prologue: proj + count + weight prep (degi zeroed by memset) ----
  hipMemsetAsync(degi, 0, (size_t)N * 4, stream);
  prologue<<<PB + CB + 112, 256, 0, stream>>>(ea, eidx, ea0_w1, ea0_w2, tag0_w,
                                              ea1_w1, ea1_w2, tag1_w, ea2_w1,
                                              P0, P1, P2, degi, Wt, E, N, PB, CB);
  scan1<<<NB, 256, 0, stream>>>(degi, bsum, N);
  scan2<<<1, 256, 0, stream>>>(bsum, rowptr, NB, N);
  scan3<<<NB, 256, 0, stream>>>(degi, bsum, rowptr, cursor, dis, N);
  fill_head<<<FB + HB, 256, 0, stream>>>(eidx, cursor, dis, cw, ce, E,
                                         mask, x, m_w1, m_b1, m_w2, m_b2,
                                         ea0_w1, ea0_b1, X0, X1, N, FB);

  // ---- EA0 + TAG0 GEMMs fused ----
  ea_gather8<<<g4, 256, 0, stream>>>(X0, X1, P0, rowptr, ce, X2, N);
  gemm_mfma_penta<<<gm, 256, 0, stream>>>(X2, WT_ea0w2, WT_tag0, ea0_b2, degi,
                                          G0, G1, G2, G3, N);
  tag_gather8<false><<<g4, 256, 0, stream>>>(G3, G2, nullptr, dis, rowptr, cw, X1, N);
  tag_gather8<false><<<g4, 256, 0, stream>>>(X1, G1, nullptr, dis, rowptr, cw, X2, N);
  tag_gather8<true><<<g4, 256, 0, stream>>>(X2, G0, tag0_b, dis, rowptr, cw, X0, N);  // h2 -> X0

  // ---- EA1 + TAG1 ----
  gemm_mfma_dual<<<gm, 256, 0, stream>>>(X0, WT_ea1d, WT_ea1s, X1, X2, ea1_b1, N);
  ea_gather8<<<g4, 256, 0, stream>>>(X1, X2, P1, rowptr, ce, G0, N);
  gemm_mfma_penta<<<gm, 256, 0, stream>>>(G0, WT_ea1w2, WT_tag1, ea1_b2, degi,
                                          G0, G1, G2, G3, N);   // in-place A=G0 safe (block-local rows)
  tag_gather8<false><<<g4, 256, 0, stream>>>(G3, G2, nullptr, dis, rowptr, cw, X1, N);
  tag_gather8<false><<<g4, 256, 0, stream>>>(X1, G1, nullptr, dis, rowptr, cw, X2, N);
  tag_gather8<true><<<g4, 256, 0, stream>>>(X2, G0, tag1_b, dis, rowptr, cw, X0, N);  // h4 -> X0

  // ---- EA2 (final, out 16, fp32) ----
  gemm_mfma_dual<<<gm, 256, 0, stream>>>(X0, WT_ea2d, WT_ea2s, X1, X2, ea2_b1, N);
  ea_gather8<<<g4, 256, 0, stream>>>(X1, X2, P2, rowptr, ce, G0, N);
  gemm_tail<<<gb, 128, 0, stream>>>(G0, ea2_w2, (float*)d_out, ea2_b2, degi, N);
}

// Round 15
// 413.200 us; speedup vs baseline: 1.1886x; 1.0208x over previous
//
#include <hip/hip_runtime.h>

typedef unsigned short u16;
typedef unsigned int u32;

using bfrag  = __attribute__((ext_vector_type(8))) short;   // 8 bf16 (4 VGPRs)
using f32x4  = __attribute__((ext_vector_type(4))) float;   // 4 fp32 acc
using f32x16 = __attribute__((ext_vector_type(16))) float;  // 16 fp32 acc (32x32 MFMA)

// ---------- bf16 / f16 helpers ----------
__device__ __forceinline__ float b2f(u16 u) {
  union { u32 i; float f; } c; c.i = ((u32)u) << 16; return c.f;
}
__device__ __forceinline__ float bflo(u32 u) { union { u32 i; float f; } c; c.i = u << 16; return c.f; }
__device__ __forceinline__ float bfhi(u32 u) { union { u32 i; float f; } c; c.i = u & 0xffff0000u; return c.f; }
__device__ __forceinline__ u16 f2b(float f) {  // round-to-nearest-even
  union { float f; u32 i; } c; c.f = f;
  u32 x = c.i;
  u32 r = x + 0x7fffu + ((x >> 16) & 1u);
  return (u16)(r >> 16);
}
__device__ __forceinline__ u32 packb2(float x, float y) {
  return ((u32)f2b(x)) | (((u32)f2b(y)) << 16);
}
__device__ __forceinline__ u16 f2h(float x) {
  union { _Float16 h; u16 u; } c; c.h = (_Float16)x; return c.u;
}
__device__ __forceinline__ float h2lo(u32 u) { union { u32 i; _Float16 h[2]; } c; c.i = u; return (float)c.h[0]; }
__device__ __forceinline__ float h2hi(u32 u) { union { u32 i; _Float16 h[2]; } c; c.i = u; return (float)c.h[1]; }
__device__ __forceinline__ int rfl(int v) { return __builtin_amdgcn_readfirstlane(v); }

// ---------- prologue: blocks [0,PB) proj (table x 256-edge chunk); [PB,PB+CB) count_deg; rest prep_wt ----------
__global__ __launch_bounds__(256) void prologue(
    const float* __restrict__ ea, const int* __restrict__ eidx,
    const float* __restrict__ ea0_w1, const float* __restrict__ ea0_w2,
    const float* __restrict__ tag0_w, const float* __restrict__ ea1_w1,
    const float* __restrict__ ea1_w2, const float* __restrict__ tag1_w,
    const float* __restrict__ ea2_w1,
    u16* __restrict__ P0, u16* __restrict__ P1, u16* __restrict__ P2,
    int* __restrict__ degi, u16* __restrict__ Wt, int E, int N,
    int PB, int CB, int EB) {
  int t = threadIdx.x;
  if (blockIdx.x < (unsigned)PB) {
    // ---- edge projection via MFMA 32x32x16: P[e,:] = ea[e,:16] @ W_tab (f16 out) ----
    __shared__ u16 Alds[256 * 16];   // 8 KB: 256 edges x 16 feats
    __shared__ u16 Wlds[2048];       // 4 KB: one table [128n][16k]
    int tab = blockIdx.x / EB;
    int chunk = blockIdx.x - tab * EB;
    int base = chunk * 256;
    int rows = E - base; if (rows > 256) rows = 256;
    const float* wsrc = (tab == 0) ? (ea0_w1 + 32 * 128)
                      : (tab == 1) ? (ea1_w1 + 256 * 128)
                                   : (ea2_w1 + 256 * 128);
    u16* P = (tab == 0) ? P0 : (tab == 1) ? P1 : P2;
#pragma unroll
    for (int i = 0; i < 8; ++i) {
      int idx = i * 256 + t;           // 0..2047
      int n = idx >> 4, k = idx & 15;
      Wlds[idx] = f2b(wsrc[k * 128 + n]);
    }
#pragma unroll
    for (int i = 0; i < 4; ++i) {
      int idx = (i * 256 + t) * 4;     // float index 0..4095
      float4 v = make_float4(0.f, 0.f, 0.f, 0.f);
      if ((idx >> 4) < rows) v = *(const float4*)(ea + (size_t)base * 16 + idx);
      ushort4 h;
      h.x = f2b(v.x); h.y = f2b(v.y); h.z = f2b(v.z); h.w = f2b(v.w);
      *(ushort4*)(Alds + idx) = h;
    }
    __syncthreads();
    int wave = t >> 6, lane = t & 63;
    int mm = lane & 31, kh = lane >> 5;
    // hoist B fragments (adjacent-column pairs), reused across row-tiles
    bfrag b00 = *(const bfrag*)(Wlds + (2 * mm) * 16 + kh * 8);
    bfrag b01 = *(const bfrag*)(Wlds + (2 * mm + 1) * 16 + kh * 8);
    bfrag b10 = *(const bfrag*)(Wlds + (64 + 2 * mm) * 16 + kh * 8);
    bfrag b11 = *(const bfrag*)(Wlds + (64 + 2 * mm + 1) * 16 + kh * 8);
#pragma unroll
    for (int it = 0; it < 4; ++it) {
      int task = wave + it * 4;        // 0..15
      int rowt = (task >> 1) * 32;
      int ch = task & 1;
      int colt = ch * 64;
      bfrag a = *(const bfrag*)(Alds + (rowt + mm) * 16 + kh * 8);
      f32x16 acc0, acc1;
#pragma unroll
      for (int z = 0; z < 16; ++z) { acc0[z] = 0.f; acc1[z] = 0.f; }
      acc0 = __builtin_amdgcn_mfma_f32_32x32x16_bf16(a, ch ? b10 : b00, acc0, 0, 0, 0);
      acc1 = __builtin_amdgcn_mfma_f32_32x32x16_bf16(a, ch ? b11 : b01, acc1, 0, 0, 0);
#pragma unroll
      for (int reg = 0; reg < 16; ++reg) {
        int row = rowt + (reg & 3) + 8 * (reg >> 2) + 4 * kh;
        if (row < rows) {
          u32 pr = ((u32)f2h(acc0[reg])) | (((u32)f2h(acc1[reg])) << 16);
          *(u32*)(P + (size_t)(base + row) * 128 + colt + 2 * mm) = pr;
        }
      }
    }
    return;
  }
  if (blockIdx.x < (unsigned)(PB + CB)) {
    // ---- count_deg (degi pre-zeroed by memset) ----
    int e = (blockIdx.x - PB) * 256 + t;
    if (e < E) {
      atomicAdd(&degi[eidx[E + e]], 1);
      atomicAdd(&degi[eidx[e]], 1);
    }
    return;
  }
  // ---- prep_wt: 14x fp32 [128][128] -> bf16 [n][k] ----
  int wb = blockIdx.x - PB - CB;          // 0..111
  int mat = wb >> 3, chunk = wb & 7;
  const float* src;
  if      (mat == 0)  src = ea0_w2;
  else if (mat <= 4)  src = tag0_w + (mat - 1) * 16384;
  else if (mat == 5)  src = ea1_w1;
  else if (mat == 6)  src = ea1_w1 + 16384;
  else if (mat == 7)  src = ea1_w2;
  else if (mat <= 11) src = tag1_w + (mat - 8) * 16384;
  else if (mat == 12) src = ea2_w1;
  else                src = ea2_w1 + 16384;
  u16* dst = Wt + mat * 16384;
  for (int i = 0; i < 8; ++i) {
    int idx = chunk * 2048 + i * 256 + t;
    int k = idx >> 7, n = idx & 127;
    dst[n * 128 + k] = f2b(src[idx]);
  }
}

// ---------- parallel scan ----------
__global__ __launch_bounds__(256) void scan1(const int* __restrict__ degi,
                                             int* __restrict__ bsum, int N) {
  __shared__ int sh[256];
  int t = threadIdx.x;
  int gid = blockIdx.x * 256 + t;
  sh[t] = (gid < N) ? degi[gid] : 0;
  __syncthreads();
  for (int off = 128; off > 0; off >>= 1) {
    if (t < off) sh[t] += sh[t + off];
    __syncthreads();
  }
  if (t == 0) bsum[blockIdx.x] = sh[0];
}

// scan2+scan3 merged: each block redundantly scans bsum (nb<=256) then its elements
__global__ __launch_bounds__(256) void scan23(const int* __restrict__ degi,
                                              const int* __restrict__ bsum,
                                              int* __restrict__ rowptr,
                                              int* __restrict__ cursor,
                                              float* __restrict__ dis, int nb, int N) {
  __shared__ int sh[256];
  int t = threadIdx.x;
  int v = (t < nb) ? bsum[t] : 0;
  sh[t] = v;
  __syncthreads();
  for (int off = 1; off < 256; off <<= 1) {
    int x = sh[t];
    int add = (t >= off) ? sh[t - off] : 0;
    __syncthreads();
    sh[t] = x + add;
    __syncthreads();
  }
  int blockoff = (blockIdx.x == 0) ? 0 : sh[blockIdx.x - 1];
  int total = sh[nb - 1];
  __syncthreads();
  int gid = blockIdx.x * 256 + t;
  int d = (gid < N) ? degi[gid] : 0;
  sh[t] = d;
  __syncthreads();
  for (int off = 1; off < 256; off <<= 1) {
    int x = sh[t];
    int add = (t >= off) ? sh[t - off] : 0;
    __syncthreads();
    sh[t] = x + add;
    __syncthreads();
  }
  if (gid < N) {
    int run = blockoff + sh[t] - d;
    rowptr[gid] = run;
    cursor[gid] = run;
    dis[gid] = d > 0 ? rsqrtf((float)d) : 0.0f;
  }
  if (blockIdx.x == 0 && t == 0) rowptr[N] = total;
}

// ---------- fill_head: blocks [0,FB) fill_csr (unified 16B records); [FB,FB+HB) head MLP ----------
__global__ __launch_bounds__(256) void fill_head(
    const int* __restrict__ eidx, int* __restrict__ cursor,
    const float* __restrict__ dis, int4* __restrict__ cr, int E,
    const float* __restrict__ mask, const float* __restrict__ x,
    const float* __restrict__ m_w1, const float* __restrict__ m_b1,
    const float* __restrict__ m_w2, const float* __restrict__ m_b2,
    const float* __restrict__ ea0_w1, const float* __restrict__ ea0_b1,
    u16* __restrict__ pb, u16* __restrict__ q, int M, int FB) {
  int t = threadIdx.x;
  if (blockIdx.x < (unsigned)FB) {
    int i = blockIdx.x * 256 + t;
    int E2 = 2 * E;
    if (i >= E2) return;
    int e = (i < E) ? i : i - E;
    int s, d;
    if (i < E) { s = eidx[e]; d = eidx[E + e]; }
    else       { s = eidx[E + e]; d = eidx[e]; }
    int pos = atomicAdd(&cursor[d], 1);
    cr[pos] = make_int4(s, e, __float_as_int(dis[s]), 0);
    return;
  }
  // ---- head: h16 = relu(mask@w1+b1)@w2 + b2 + x; pb = h16@Wd + b1', q = h16@Ws ----
  __shared__ float Ml[16 * 16];
  __shared__ float T1[16 * 128];
  __shared__ float H[16 * 16];
  int base = (blockIdx.x - FB) * 16;
  {
    int r = t >> 4, k = t & 15;
    int row = base + r;
    Ml[t] = (row < M) ? mask[(size_t)row * 16 + k] : 0.f;
  }
  __syncthreads();
  {
    int col = t & 127, h2 = t >> 7;
    float acc[8];
    float b1v = m_b1[col];
#pragma unroll
    for (int r = 0; r < 8; ++r) acc[r] = b1v;
    for (int k = 0; k < 16; ++k) {
      float w = m_w1[k * 128 + col];
#pragma unroll
      for (int r = 0; r < 8; ++r) acc[r] += Ml[(h2 * 8 + r) * 16 + k] * w;
    }
#pragma unroll
    for (int r = 0; r < 8; ++r) T1[(h2 * 8 + r) * 128 + col] = fmaxf(acc[r], 0.f);
  }
  __syncthreads();
  {
    int r = t >> 4, u = t & 15;
    float acc = m_b2[u];
    for (int k = 0; k < 128; ++k) acc += T1[r * 128 + k] * m_w2[k * 16 + u];
    int row = base + r;
    float xv = (row < M) ? x[(size_t)row * 16 + u] : 0.f;
    H[t] = acc + xv;
  }
  __syncthreads();
  {
    int col = t & 127, h2 = t >> 7;
    float aP[8], aQ[8];
    float b1v = ea0_b1[col];
#pragma unroll
    for (int r = 0; r < 8; ++r) { aP[r] = b1v; aQ[r] = 0.f; }
    for (int k = 0; k < 16; ++k) {
      float wd = ea0_w1[k * 128 + col];
      float ws = ea0_w1[(16 + k) * 128 + col];
#pragma unroll
      for (int r = 0; r < 8; ++r) {
        float h = H[(h2 * 8 + r) * 16 + k];
        aP[r] += h * wd;
        aQ[r] += h * ws;
      }
    }
#pragma unroll
    for (int r = 0; r < 8; ++r) {
      int row = base + h2 * 8 + r;
      if (row < M) {
        pb[(size_t)row * 128 + col] = f2b(aP[r]);
        q[(size_t)row * 128 + col]  = f2b(aQ[r]);
      }
    }
  }
}

// ---------- dual MFMA GEMM: C0 = A@W0 (+bias0), C1 = A@W1 (both bf16) ----------
__global__ __launch_bounds__(256) void gemm_mfma_dual(
    const u16* __restrict__ A, const u16* __restrict__ W0t, const u16* __restrict__ W1t,
    u16* __restrict__ C0, u16* __restrict__ C1, const float* __restrict__ bias0, int M) {
  __shared__ u16 Alds[64 * 136];
  __shared__ u16 Wlds[128 * 136];
  int t = threadIdx.x;
  int base = blockIdx.x * 64;
#pragma unroll
  for (int i = 0; i < 8; ++i) {
    int idx = (i * 256 + t) * 8;
    int n = idx >> 7, k = idx & 127;
    uint4 v = *(const uint4*)(W0t + idx);
    *(uint4*)(Wlds + n * 136 + k) = v;
  }
#pragma unroll
  for (int i = 0; i < 4; ++i) {
    int idx = (i * 256 + t) * 8;
    int r = idx >> 7, k = idx & 127;
    int row = base + r;
    uint4 v = make_uint4(0, 0, 0, 0);
    if (row < M) v = *(const uint4*)(A + (size_t)row * 128 + k);
    *(uint4*)(Alds + r * 136 + k) = v;
  }
  __syncthreads();
  int wave = t >> 6, lane = t & 63;
  int m = lane & 15, quad = lane >> 4;
  int arow = wave * 16 + m;
  bfrag a[4];
#pragma unroll
  for (int ks = 0; ks < 4; ++ks)
    a[ks] = *(const bfrag*)(Alds + arow * 136 + ks * 32 + quad * 8);
  f32x4 acc0[8], acc1[8];
#pragma unroll
  for (int nt = 0; nt < 8; ++nt) { acc0[nt] = (f32x4){0,0,0,0}; acc1[nt] = (f32x4){0,0,0,0}; }
#pragma unroll
  for (int nt = 0; nt < 8; ++nt) {
    int n = nt * 16 + m;
#pragma unroll
    for (int ks = 0; ks < 4; ++ks) {
      bfrag b = *(const bfrag*)(Wlds + n * 136 + ks * 32 + quad * 8);
      acc0[nt] = __builtin_amdgcn_mfma_f32_16x16x32_bf16(a[ks], b, acc0[nt], 0, 0, 0);
    }
  }
  __syncthreads();
#pragma unroll
  for (int i = 0; i < 8; ++i) {
    int idx = (i * 256 + t) * 8;
    int n = idx >> 7, k = idx & 127;
    uint4 v = *(const uint4*)(W1t + idx);
    *(uint4*)(Wlds + n * 136 + k) = v;
  }
  __syncthreads();
#pragma unroll
  for (int nt = 0; nt < 8; ++nt) {
    int n = nt * 16 + m;
#pragma unroll
    for (int ks = 0; ks < 4; ++ks) {
      bfrag b = *(const bfrag*)(Wlds + n * 136 + ks * 32 + quad * 8);
      acc1[nt] = __builtin_amdgcn_mfma_f32_16x16x32_bf16(a[ks], b, acc1[nt], 0, 0, 0);
    }
  }
#pragma unroll
  for (int nt = 0; nt < 8; ++nt) {
    int col = nt * 16 + m;
#pragma unroll
    for (int r = 0; r < 4; ++r) {
      int row = base + wave * 16 + quad * 4 + r;
      if (row < M) {
        float v0 = acc0[nt][r];
        if (bias0) v0 += bias0[col];
        C0[(size_t)row * 128 + col] = f2b(v0);
        C1[(size_t)row * 128 + col] = f2b(acc1[nt][r]);
      }
    }
  }
}

// ---------- penta MFMA GEMM: h = relu(A@W2 + deg*bias); G_k = h @ W_k (k=0..3) ----------
__global__ __launch_bounds__(256) void gemm_mfma_penta(
    const u16* __restrict__ A, const u16* __restrict__ W2t, const u16* __restrict__ Wt4,
    const float* __restrict__ bias, const int* __restrict__ degi,
    u16* __restrict__ G0, u16* __restrict__ G1,
    u16* __restrict__ G2, u16* __restrict__ G3, int M) {
  __shared__ u16 Alds[64 * 136];
  __shared__ u16 Wlds[128 * 136];
  int t = threadIdx.x;
  int base = blockIdx.x * 64;
#pragma unroll
  for (int i = 0; i < 8; ++i) {
    int idx = (i * 256 + t) * 8;
    int n = idx >> 7, k = idx & 127;
    uint4 v = *(const uint4*)(W2t + idx);
    *(uint4*)(Wlds + n * 136 + k) = v;
  }
#pragma unroll
  for (int i = 0; i < 4; ++i) {
    int idx = (i * 256 + t) * 8;
    int r = idx >> 7, k = idx & 127;
    int row = base + r;
    uint4 v = make_uint4(0, 0, 0, 0);
    if (row < M) v = *(const uint4*)(A + (size_t)row * 128 + k);
    *(uint4*)(Alds + r * 136 + k) = v;
  }
  __syncthreads();
  int wave = t >> 6, lane = t & 63;
  int m = lane & 15, quad = lane >> 4;
  int arow = wave * 16 + m;
  bfrag a[4];
#pragma unroll
  for (int ks = 0; ks < 4; ++ks)
    a[ks] = *(const bfrag*)(Alds + arow * 136 + ks * 32 + quad * 8);
  {
    f32x4 acc[8];
#pragma unroll
    for (int nt = 0; nt < 8; ++nt) acc[nt] = (f32x4){0.f, 0.f, 0.f, 0.f};
#pragma unroll
    for (int nt = 0; nt < 8; ++nt) {
      int n = nt * 16 + m;
#pragma unroll
      for (int ks = 0; ks < 4; ++ks) {
        bfrag b = *(const bfrag*)(Wlds + n * 136 + ks * 32 + quad * 8);
        acc[nt] = __builtin_amdgcn_mfma_f32_16x16x32_bf16(a[ks], b, acc[nt], 0, 0, 0);
      }
    }
#pragma unroll
    for (int nt = 0; nt < 8; ++nt) {
      int col = nt * 16 + m;
#pragma unroll
      for (int r = 0; r < 4; ++r) {
        int lrow = wave * 16 + quad * 4 + r;
        int row = base + lrow;
        float v = 0.f;
        if (row < M) v = fmaxf(acc[nt][r] + bias[col] * (float)degi[row], 0.f);
        Alds[lrow * 136 + col] = f2b(v);   // own wave's slab; in-wave DS ordering
      }
    }
  }
#pragma unroll
  for (int ks = 0; ks < 4; ++ks)
    a[ks] = *(const bfrag*)(Alds + arow * 136 + ks * 32 + quad * 8);
#pragma unroll
  for (int mat = 0; mat < 4; ++mat) {
    __syncthreads();
#pragma unroll
    for (int i = 0; i < 8; ++i) {
      int idx = (i * 256 + t) * 8;
      int n = idx >> 7, k = idx & 127;
      uint4 v = *(const uint4*)(Wt4 + mat * 16384 + idx);
      *(uint4*)(Wlds + n * 136 + k) = v;
    }
    __syncthreads();
    f32x4 acc[8];
#pragma unroll
    for (int nt = 0; nt < 8; ++nt) acc[nt] = (f32x4){0.f, 0.f, 0.f, 0.f};
#pragma unroll
    for (int nt = 0; nt < 8; ++nt) {
      int n = nt * 16 + m;
#pragma unroll
      for (int ks = 0; ks < 4; ++ks) {
        bfrag b = *(const bfrag*)(Wlds + n * 136 + ks * 32 + quad * 8);
        acc[nt] = __builtin_amdgcn_mfma_f32_16x16x32_bf16(a[ks], b, acc[nt], 0, 0, 0);
      }
    }
    u16* G = (mat == 0) ? G0 : (mat == 1) ? G1 : (mat == 2) ? G2 : G3;
#pragma unroll
    for (int nt = 0; nt < 8; ++nt) {
      int col = nt * 16 + m;
#pragma unroll
      for (int r = 0; r < 4; ++r) {
        int row = base + wave * 16 + quad * 4 + r;
        if (row < M) G[(size_t)row * 128 + col] = f2b(acc[nt][r]);
      }
    }
  }
}

// ---------- VALU GEMM (final 128->16) ----------
__global__ __launch_bounds__(128) void gemm_tail(
    const u16* __restrict__ A, const float* __restrict__ W, float* __restrict__ Cout,
    const float* __restrict__ bias, const int* __restrict__ degi, int M) {
  const int ROWS = 8;
  int t = threadIdx.x;
  int base = blockIdx.x * ROWS;
  __shared__ float Al[ROWS * 128];
  for (int i = t; i < ROWS * 128; i += 128) {
    int r = i >> 7, k = i & 127;
    int row = base + r;
    Al[i] = (row < M) ? b2f(A[(size_t)row * 128 + k]) : 0.f;
  }
  __syncthreads();
  int r = t >> 4, u = t & 15;
  int row = base + r;
  float acc = 0.f;
  for (int k = 0; k < 128; ++k) acc += Al[r * 128 + k] * W[k * 16 + u];
  if (row < M) {
    Cout[(size_t)row * 16 + u] = acc + bias[u] * (float)degi[row];
  }
}

// ---------- per-edge bodies (unified int4 records in LDS) ----------
__device__ __forceinline__ void tag_edge(const int4* __restrict__ rr, int j,
    const u16* __restrict__ g, int lane, float& x0, float& x1) {
  int4 r = rr[j];
  int s = rfl(r.x); float w = __uint_as_float(rfl(r.z));
  u32 h = *((const u32*)(g + (size_t)s * 128) + lane);
  x0 += w * bflo(h); x1 += w * bfhi(h);
}
__device__ __forceinline__ void ea_edge(const int4* __restrict__ rr, int j,
    const u16* __restrict__ q, const u16* __restrict__ P, int lane,
    float pb0, float pb1, float& x0, float& x1) {
  int4 r = rr[j];
  int s = rfl(r.x), i = rfl(r.y);
  u32 qv = *((const u32*)(q + (size_t)s * 128) + lane);
  u32 pv = *((const u32*)(P + (size_t)i * 128) + lane);
  x0 += fmaxf(pb0 + bflo(qv) + h2lo(pv), 0.f);
  x1 += fmaxf(pb1 + bfhi(qv) + h2hi(pv), 0.f);
}

// ---------- TAG gather v9: 1 node/wave, LDS-staged 64-record batches, 8-edge unroll ----------
template<bool FINAL>
__global__ __launch_bounds__(256) void tag_gather9(
    const u16* __restrict__ g, const u16* __restrict__ Cin,
    const float* __restrict__ bias, const float* __restrict__ dis,
    const int* __restrict__ rowptr, const int4* __restrict__ cr,
    u16* __restrict__ out, int N) {
  __shared__ int4 recs[4][64];
  int wave = threadIdx.x >> 6, lane = threadIdx.x & 63;
  int node = blockIdx.x * 4 + wave;
  if (node >= N) return;
  int e0 = rfl(rowptr[node]);
  int e1 = rfl(rowptr[node + 1]);
  int4* rr = recs[wave];
  float a0 = 0, a1 = 0, b0 = 0, b1 = 0;
  for (int base = e0; base < e1; base += 64) {
    if (base + lane < e1) rr[lane] = cr[base + lane];   // one 16B/lane coalesced load
    int cnt = min(64, e1 - base);
    int j = 0;
    for (; j + 8 <= cnt; j += 8) {
      tag_edge(rr, j + 0, g, lane, a0, a1);
      tag_edge(rr, j + 1, g, lane, b0, b1);
      tag_edge(rr, j + 2, g, lane, a0, a1);
      tag_edge(rr, j + 3, g, lane, b0, b1);
      tag_edge(rr, j + 4, g, lane, a0, a1);
      tag_edge(rr, j + 5, g, lane, b0, b1);
      tag_edge(rr, j + 6, g, lane, a0, a1);
      tag_edge(rr, j + 7, g, lane, b0, b1);
    }
    for (; j + 2 <= cnt; j += 2) {
      tag_edge(rr, j + 0, g, lane, a0, a1);
      tag_edge(rr, j + 1, g, lane, b0, b1);
    }
    if (j < cnt) tag_edge(rr, j, g, lane, a0, a1);
  }
  float dn = dis[node];
  float r0v = dn * (a0 + b0), r1v = dn * (a1 + b1);
  u32 cin = *((const u32*)(Cin + (size_t)node * 128) + lane);
  r0v += bflo(cin); r1v += bfhi(cin);
  if (FINAL) {
    float2 bv = *(const float2*)(bias + 2 * lane);
    r0v = fmaxf(r0v + bv.x, 0.f);
    r1v = fmaxf(r1v + bv.y, 0.f);
  }
  *((u32*)(out + (size_t)node * 128) + lane) = packb2(r0v, r1v);
}

// ---------- EA gather v9: 1 node/wave, LDS-staged records, 8-edge unroll ----------
__global__ __launch_bounds__(256) void ea_gather9(
    const u16* __restrict__ pb, const u16* __restrict__ q,
    const u16* __restrict__ P /*f16 [E,128]*/,
    const int* __restrict__ rowptr, const int4* __restrict__ cr,
    u16* __restrict__ Hsum, int N) {
  __shared__ int4 recs[4][64];
  int wave = threadIdx.x >> 6, lane = threadIdx.x & 63;
  int node = blockIdx.x * 4 + wave;
  if (node >= N) return;
  int e0 = rfl(rowptr[node]);
  int e1 = rfl(rowptr[node + 1]);
  int4* rr = recs[wave];
  u32 pbu = *((const u32*)(pb + (size_t)node * 128) + lane);
  float pb0 = bflo(pbu), pb1 = bfhi(pbu);
  float a0 = 0, a1 = 0, b0 = 0, b1 = 0;
  for (int base = e0; base < e1; base += 64) {
    if (base + lane < e1) rr[lane] = cr[base + lane];
    int cnt = min(64, e1 - base);
    int j = 0;
    for (; j + 8 <= cnt; j += 8) {
      ea_edge(rr, j + 0, q, P, lane, pb0, pb1, a0, a1);
      ea_edge(rr, j + 1, q, P, lane, pb0, pb1, b0, b1);
      ea_edge(rr, j + 2, q, P, lane, pb0, pb1, a0, a1);
      ea_edge(rr, j + 3, q, P, lane, pb0, pb1, b0, b1);
      ea_edge(rr, j + 4, q, P, lane, pb0, pb1, a0, a1);
      ea_edge(rr, j + 5, q, P, lane, pb0, pb1, b0, b1);
      ea_edge(rr, j + 6, q, P, lane, pb0, pb1, a0, a1);
      ea_edge(rr, j + 7, q, P, lane, pb0, pb1, b0, b1);
    }
    for (; j + 2 <= cnt; j += 2) {
      ea_edge(rr, j + 0, q, P, lane, pb0, pb1, a0, a1);
      ea_edge(rr, j + 1, q, P, lane, pb0, pb1, b0, b1);
    }
    if (j < cnt) ea_edge(rr, j, q, P, lane, pb0, pb1, a0, a1);
  }
  *((u32*)(Hsum + (size_t)node * 128) + lane) = packb2(a0 + b0, a1 + b1);
}

extern "C" void kernel_launch(void* const* d_in, const int* in_sizes, int n_in,
                              void* d_out, int out_size, void* d_ws, size_t ws_size,
                              hipStream_t stream) {
  const float* x      = (const float*)d_in[0];
  const float* mask   = (const float*)d_in[1];
  const float* ea     = (const float*)d_in[2];
  const int*   eidx   = (const int*)d_in[3];
  const float* m_w1   = (const float*)d_in[4];
  const float* m_b1   = (const float*)d_in[5];
  const float* m_w2   = (const float*)d_in[6];
  const float* m_b2   = (const float*)d_in[7];
  const float* ea0_w1 = (const float*)d_in[8];
  const float* ea0_b1 = (const float*)d_in[9];
  const float* ea0_w2 = (const float*)d_in[10];
  const float* ea0_b2 = (const float*)d_in[11];
  const float* tag0_w = (const float*)d_in[12];
  const float* tag0_b = (const float*)d_in[13];
  const float* ea1_w1 = (const float*)d_in[14];
  const float* ea1_b1 = (const float*)d_in[15];
  const float* ea1_w2 = (const float*)d_in[16];
  const float* ea1_b2 = (const float*)d_in[17];
  const float* tag1_w = (const float*)d_in[18];
  const float* tag1_b = (const float*)d_in[19];
  const float* ea2_w1 = (const float*)d_in[20];
  const float* ea2_b1 = (const float*)d_in[21];
  const float* ea2_w2 = (const float*)d_in[22];
  const float* ea2_b2 = (const float*)d_in[23];

  const int N = in_sizes[0] / 16;   // 20000
  const int E = in_sizes[2] / 16;   // 160000
  const int E2 = 2 * E;
  const int NB = (N + 255) / 256;

  char* w = (char*)d_ws;
  auto alloc = [&](size_t bytes) { char* p = w; w += (bytes + 255) & ~(size_t)255; return p; };
  int*   degi   = (int*)alloc((size_t)N * 4);
  int*   cursor = (int*)alloc((size_t)N * 4);
  int*   rowptr = (int*)alloc((size_t)(N + 1) * 4);
  int*   bsum   = (int*)alloc((size_t)256 * 4);
  float* dis    = (float*)alloc((size_t)N * 4);
  int4*  cr     = (int4*)alloc((size_t)E2 * 16);
  u16*   X0     = (u16*)alloc((size_t)N * 128 * 2);
  u16*   X1     = (u16*)alloc((size_t)N * 128 * 2);
  u16*   X2     = (u16*)alloc((size_t)N * 128 * 2);
  u16*   G0     = (u16*)alloc((size_t)N * 128 * 2);
  u16*   G1     = (u16*)alloc((size_t)N * 128 * 2);
  u16*   G2     = (u16*)alloc((size_t)N * 128 * 2);
  u16*   G3     = (u16*)alloc((size_t)N * 128 * 2);
  u16*   Wt     = (u16*)alloc((size_t)14 * 16384 * 2);
  u16*   P0     = (u16*)alloc((size_t)E * 128 * 2);
  u16*   P1     = (u16*)alloc((size_t)E * 128 * 2);
  u16*   P2     = (u16*)alloc((size_t)E * 128 * 2);
  (void)ws_size; (void)n_in; (void)out_size;

  const int EB = (E + 255) / 256;      // 625 proj chunks per table
  const int PB = 3 * EB;               // 1875 proj blocks
  const int CB = (E + 255) / 256;      // 625 count blocks
  const int FB = (E2 + 255) / 256;     // 1250 fill blocks
  const int HB = (N + 15) / 16;        // 1250 head blocks
  const int gm = (N + 63) / 64;
  const int g4 = (N + 3) / 4;
  const int gb = (N + 7) / 8;

  u16* WT_ea0w2  = Wt + 0 * 16384;
  u16* WT_tag0   = Wt + 1 * 16384;
  u16* WT_ea1d   = Wt + 5 * 16384;
  u16* WT_ea1s   = Wt + 6 * 16384;
  u16* WT_ea1w2  = Wt + 7 * 16384;
  u16* WT_tag1   = Wt + 8 * 16384;
  u16* WT_ea2d   = Wt + 12 * 16384;
  u16* WT_ea2s   = Wt + 13 * 16384;

  // ---- prologue: proj + count + weight prep (degi zeroed by memset) ----
  hipMemsetAsync(degi, 0, (size_t)N * 4, stream);
  prologue<<<PB + CB + 112, 256, 0, stream>>>(ea, eidx, ea0_w1, ea0_w2, tag0_w,
                                              ea1_w1, ea1_w2, tag1_w, ea2_w1,
                                              P0, P1, P2, degi, Wt, E, N, PB, CB, EB);
  scan1<<<NB, 256, 0, stream>>>(degi, bsum, N);
  scan23<<<NB, 256, 0, stream>>>(degi, bsum, rowptr, cursor, dis, NB, N);
  fill_head<<<FB + HB, 256, 0, stream>>>(eidx, cursor, dis, cr, E,
                                         mask, x, m_w1, m_b1, m_w2, m_b2,
                                         ea0_w1, ea0_b1, X0, X1, N, FB);

  // ---- EA0 + TAG0 GEMMs fused ----
  ea_gather9<<<g4, 256, 0, stream>>>(X0, X1, P0, rowptr, cr, X2, N);
  gemm_mfma_penta<<<gm, 256, 0, stream>>>(X2, WT_ea0w2, WT_tag0, ea0_b2, degi,
                                          G0, G1, G2, G3, N);
  tag_gather9<false><<<g4, 256, 0, stream>>>(G3, G2, nullptr, dis, rowptr, cr, X1, N);
  tag_gather9<false><<<g4, 256, 0, stream>>>(X1, G1, nullptr, dis, rowptr, cr, X2, N);
  tag_gather9<true><<<g4, 256, 0, stream>>>(X2, G0, tag0_b, dis, rowptr, cr, X0, N);  // h2 -> X0

  // ---- EA1 + TAG1 ----
  gemm_mfma_dual<<<gm, 256, 0, stream>>>(X0, WT_ea1d, WT_ea1s, X1, X2, ea1_b1, N);
  ea_gather9<<<g4, 256, 0, stream>>>(X1, X2, P1, rowptr, cr, G0, N);
  gemm_mfma_penta<<<gm, 256, 0, stream>>>(G0, WT_ea1w2, WT_tag1, ea1_b2, degi,
                                          G0, G1, G2, G3, N);   // in-place A=G0 safe
  tag_gather9<false><<<g4, 256, 0, stream>>>(G3, G2, nullptr, dis, rowptr, cr, X1, N);
  tag_gather9<false><<<g4, 256, 0, stream>>>(X1, G1, nullptr, dis, rowptr, cr, X2, N);
  tag_gather9<true><<<g4, 256, 0, stream>>>(X2, G0, tag1_b, dis, rowptr, cr, X0, N);  // h4 -> X0

  // ---- EA2 (final, out 16, fp32) ----
  gemm_mfma_dual<<<gm, 256, 0, stream>>>(X0, WT_ea2d, WT_ea2s, X1, X2, ea2_b1, N);
  ea_gather9<<<g4, 256, 0, stream>>>(X1, X2, P2, rowptr, cr, G0, N);
  gemm_tail<<<gb, 128, 0, stream>>>(G0, ea2_w2, (float*)d_out, ea2_b2, degi, N);
}

// Round 16
// 389.056 us; speedup vs baseline: 1.2624x; 1.0621x over previous
//
#include <hip/hip_runtime.h>

typedef unsigned short u16;
typedef unsigned char u8;
typedef unsigned int u32;

using bfrag  = __attribute__((ext_vector_type(8))) short;   // 8 bf16 (4 VGPRs)
using f32x2  = __attribute__((ext_vector_type(2))) float;
using f32x4  = __attribute__((ext_vector_type(4))) float;   // 4 fp32 acc
using f32x16 = __attribute__((ext_vector_type(16))) float;  // 16 fp32 acc (32x32 MFMA)

// ---------- bf16 / f16 / fp8 helpers ----------
__device__ __forceinline__ float b2f(u16 u) {
  union { u32 i; float f; } c; c.i = ((u32)u) << 16; return c.f;
}
__device__ __forceinline__ float bflo(u32 u) { union { u32 i; float f; } c; c.i = u << 16; return c.f; }
__device__ __forceinline__ float bfhi(u32 u) { union { u32 i; float f; } c; c.i = u & 0xffff0000u; return c.f; }
__device__ __forceinline__ u16 f2b(float f) {  // round-to-nearest-even
  union { float f; u32 i; } c; c.f = f;
  u32 x = c.i;
  u32 r = x + 0x7fffu + ((x >> 16) & 1u);
  return (u16)(r >> 16);
}
__device__ __forceinline__ u32 packb2(float x, float y) {
  return ((u32)f2b(x)) | (((u32)f2b(y)) << 16);
}
__device__ __forceinline__ int rfl(int v) { return __builtin_amdgcn_readfirstlane(v); }

// ---------- prologue: blocks [0,PB) proj (table x 256-edge chunk); [PB,PB+CB) count_deg; rest prep_wt ----------
__global__ __launch_bounds__(256) void prologue(
    const float* __restrict__ ea, const int* __restrict__ eidx,
    const float* __restrict__ ea0_w1, const float* __restrict__ ea0_w2,
    const float* __restrict__ tag0_w, const float* __restrict__ ea1_w1,
    const float* __restrict__ ea1_w2, const float* __restrict__ tag1_w,
    const float* __restrict__ ea2_w1,
    u8* __restrict__ P0, u8* __restrict__ P1, u8* __restrict__ P2,
    int* __restrict__ degi, u16* __restrict__ Wt, int E, int N,
    int PB, int CB, int EB) {
  int t = threadIdx.x;
  if (blockIdx.x < (unsigned)PB) {
    // ---- edge projection via MFMA 32x32x16: P[e,:] = ea[e,:16] @ W_tab (fp8 e4m3 out) ----
    __shared__ u16 Alds[256 * 16];   // 8 KB: 256 edges x 16 feats
    __shared__ u16 Wlds[2048];       // 4 KB: one table [128n][16k]
    int tab = blockIdx.x / EB;
    int chunk = blockIdx.x - tab * EB;
    int base = chunk * 256;
    int rows = E - base; if (rows > 256) rows = 256;
    const float* wsrc = (tab == 0) ? (ea0_w1 + 32 * 128)
                      : (tab == 1) ? (ea1_w1 + 256 * 128)
                                   : (ea2_w1 + 256 * 128);
    u8* P = (tab == 0) ? P0 : (tab == 1) ? P1 : P2;
#pragma unroll
    for (int i = 0; i < 8; ++i) {
      int idx = i * 256 + t;           // 0..2047
      int n = idx >> 4, k = idx & 15;
      Wlds[idx] = f2b(wsrc[k * 128 + n]);
    }
#pragma unroll
    for (int i = 0; i < 4; ++i) {
      int idx = (i * 256 + t) * 4;     // float index 0..4095
      float4 v = make_float4(0.f, 0.f, 0.f, 0.f);
      if ((idx >> 4) < rows) v = *(const float4*)(ea + (size_t)base * 16 + idx);
      ushort4 h;
      h.x = f2b(v.x); h.y = f2b(v.y); h.z = f2b(v.z); h.w = f2b(v.w);
      *(ushort4*)(Alds + idx) = h;
    }
    __syncthreads();
    int wave = t >> 6, lane = t & 63;
    int mm = lane & 31, kh = lane >> 5;
    // hoisted B fragments (adjacent-column pairs), reused across row-tiles
    bfrag b00 = *(const bfrag*)(Wlds + (2 * mm) * 16 + kh * 8);
    bfrag b01 = *(const bfrag*)(Wlds + (2 * mm + 1) * 16 + kh * 8);
    bfrag b10 = *(const bfrag*)(Wlds + (64 + 2 * mm) * 16 + kh * 8);
    bfrag b11 = *(const bfrag*)(Wlds + (64 + 2 * mm + 1) * 16 + kh * 8);
#pragma unroll
    for (int it = 0; it < 4; ++it) {
      int task = wave + it * 4;        // 0..15
      int rowt = (task >> 1) * 32;
      int ch = task & 1;
      int colt = ch * 64;
      bfrag a = *(const bfrag*)(Alds + (rowt + mm) * 16 + kh * 8);
      f32x16 acc0, acc1;
#pragma unroll
      for (int z = 0; z < 16; ++z) { acc0[z] = 0.f; acc1[z] = 0.f; }
      acc0 = __builtin_amdgcn_mfma_f32_32x32x16_bf16(a, ch ? b10 : b00, acc0, 0, 0, 0);
      acc1 = __builtin_amdgcn_mfma_f32_32x32x16_bf16(a, ch ? b11 : b01, acc1, 0, 0, 0);
#pragma unroll
      for (int reg = 0; reg < 16; ++reg) {
        int row = rowt + (reg & 3) + 8 * (reg >> 2) + 4 * kh;
        if (row < rows) {
          // fp8 e4m3 pack of the two adjacent columns -> u16 store
          u32 pk = (u32)__builtin_amdgcn_cvt_pk_fp8_f32(acc0[reg], acc1[reg], 0, false);
          *(u16*)(P + (size_t)(base + row) * 128 + colt + 2 * mm) = (u16)pk;
        }
      }
    }
    return;
  }
  if (blockIdx.x < (unsigned)(PB + CB)) {
    // ---- count_deg (degi pre-zeroed by memset) ----
    int e = (blockIdx.x - PB) * 256 + t;
    if (e < E) {
      atomicAdd(&degi[eidx[E + e]], 1);
      atomicAdd(&degi[eidx[e]], 1);
    }
    return;
  }
  // ---- prep_wt: 14x fp32 [128][128] -> bf16 [n][k] ----
  int wb = blockIdx.x - PB - CB;          // 0..111
  int mat = wb >> 3, chunk = wb & 7;
  const float* src;
  if      (mat == 0)  src = ea0_w2;
  else if (mat <= 4)  src = tag0_w + (mat - 1) * 16384;
  else if (mat == 5)  src = ea1_w1;
  else if (mat == 6)  src = ea1_w1 + 16384;
  else if (mat == 7)  src = ea1_w2;
  else if (mat <= 11) src = tag1_w + (mat - 8) * 16384;
  else if (mat == 12) src = ea2_w1;
  else                src = ea2_w1 + 16384;
  u16* dst = Wt + mat * 16384;
  for (int i = 0; i < 8; ++i) {
    int idx = chunk * 2048 + i * 256 + t;
    int k = idx >> 7, n = idx & 127;
    dst[n * 128 + k] = f2b(src[idx]);
  }
}

// ---------- parallel scan ----------
__global__ __launch_bounds__(256) void scan1(const int* __restrict__ degi,
                                             int* __restrict__ bsum, int N) {
  __shared__ int sh[256];
  int t = threadIdx.x;
  int gid = blockIdx.x * 256 + t;
  sh[t] = (gid < N) ? degi[gid] : 0;
  __syncthreads();
  for (int off = 128; off > 0; off >>= 1) {
    if (t < off) sh[t] += sh[t + off];
    __syncthreads();
  }
  if (t == 0) bsum[blockIdx.x] = sh[0];
}

// scan2+scan3 merged
__global__ __launch_bounds__(256) void scan23(const int* __restrict__ degi,
                                              const int* __restrict__ bsum,
                                              int* __restrict__ rowptr,
                                              int* __restrict__ cursor,
                                              float* __restrict__ dis, int nb, int N) {
  __shared__ int sh[256];
  int t = threadIdx.x;
  int v = (t < nb) ? bsum[t] : 0;
  sh[t] = v;
  __syncthreads();
  for (int off = 1; off < 256; off <<= 1) {
    int x = sh[t];
    int add = (t >= off) ? sh[t - off] : 0;
    __syncthreads();
    sh[t] = x + add;
    __syncthreads();
  }
  int blockoff = (blockIdx.x == 0) ? 0 : sh[blockIdx.x - 1];
  int total = sh[nb - 1];
  __syncthreads();
  int gid = blockIdx.x * 256 + t;
  int d = (gid < N) ? degi[gid] : 0;
  sh[t] = d;
  __syncthreads();
  for (int off = 1; off < 256; off <<= 1) {
    int x = sh[t];
    int add = (t >= off) ? sh[t - off] : 0;
    __syncthreads();
    sh[t] = x + add;
    __syncthreads();
  }
  if (gid < N) {
    int run = blockoff + sh[t] - d;
    rowptr[gid] = run;
    cursor[gid] = run;
    dis[gid] = d > 0 ? rsqrtf((float)d) : 0.0f;
  }
  if (blockIdx.x == 0 && t == 0) rowptr[N] = total;
}

// ---------- fill_head: blocks [0,FB) fill_csr (unified 16B records); [FB,FB+HB) head MLP ----------
__global__ __launch_bounds__(256) void fill_head(
    const int* __restrict__ eidx, int* __restrict__ cursor,
    const float* __restrict__ dis, int4* __restrict__ cr, int E,
    const float* __restrict__ mask, const float* __restrict__ x,
    const float* __restrict__ m_w1, const float* __restrict__ m_b1,
    const float* __restrict__ m_w2, const float* __restrict__ m_b2,
    const float* __restrict__ ea0_w1, const float* __restrict__ ea0_b1,
    u16* __restrict__ pb, u16* __restrict__ q, int M, int FB) {
  int t = threadIdx.x;
  if (blockIdx.x < (unsigned)FB) {
    int i = blockIdx.x * 256 + t;
    int E2 = 2 * E;
    if (i >= E2) return;
    int e = (i < E) ? i : i - E;
    int s, d;
    if (i < E) { s = eidx[e]; d = eidx[E + e]; }
    else       { s = eidx[E + e]; d = eidx[e]; }
    int pos = atomicAdd(&cursor[d], 1);
    cr[pos] = make_int4(s, e, __float_as_int(dis[s]), 0);
    return;
  }
  __shared__ float Ml[16 * 16];
  __shared__ float T1[16 * 128];
  __shared__ float H[16 * 16];
  int base = (blockIdx.x - FB) * 16;
  {
    int r = t >> 4, k = t & 15;
    int row = base + r;
    Ml[t] = (row < M) ? mask[(size_t)row * 16 + k] : 0.f;
  }
  __syncthreads();
  {
    int col = t & 127, h2 = t >> 7;
    float acc[8];
    float b1v = m_b1[col];
#pragma unroll
    for (int r = 0; r < 8; ++r) acc[r] = b1v;
    for (int k = 0; k < 16; ++k) {
      float w = m_w1[k * 128 + col];
#pragma unroll
      for (int r = 0; r < 8; ++r) acc[r] += Ml[(h2 * 8 + r) * 16 + k] * w;
    }
#pragma unroll
    for (int r = 0; r < 8; ++r) T1[(h2 * 8 + r) * 128 + col] = fmaxf(acc[r], 0.f);
  }
  __syncthreads();
  {
    int r = t >> 4, u = t & 15;
    float acc = m_b2[u];
    for (int k = 0; k < 128; ++k) acc += T1[r * 128 + k] * m_w2[k * 16 + u];
    int row = base + r;
    float xv = (row < M) ? x[(size_t)row * 16 + u] : 0.f;
    H[t] = acc + xv;
  }
  __syncthreads();
  {
    int col = t & 127, h2 = t >> 7;
    float aP[8], aQ[8];
    float b1v = ea0_b1[col];
#pragma unroll
    for (int r = 0; r < 8; ++r) { aP[r] = b1v; aQ[r] = 0.f; }
    for (int k = 0; k < 16; ++k) {
      float wd = ea0_w1[k * 128 + col];
      float ws = ea0_w1[(16 + k) * 128 + col];
#pragma unroll
      for (int r = 0; r < 8; ++r) {
        float h = H[(h2 * 8 + r) * 16 + k];
        aP[r] += h * wd;
        aQ[r] += h * ws;
      }
    }
#pragma unroll
    for (int r = 0; r < 8; ++r) {
      int row = base + h2 * 8 + r;
      if (row < M) {
        pb[(size_t)row * 128 + col] = f2b(aP[r]);
        q[(size_t)row * 128 + col]  = f2b(aQ[r]);
      }
    }
  }
}

// ---------- dual MFMA GEMM: C0 = A@W0 (+bias0), C1 = A@W1 (both bf16) ----------
__global__ __launch_bounds__(256) void gemm_mfma_dual(
    const u16* __restrict__ A, const u16* __restrict__ W0t, const u16* __restrict__ W1t,
    u16* __restrict__ C0, u16* __restrict__ C1, const float* __restrict__ bias0, int M) {
  __shared__ u16 Alds[64 * 136];
  __shared__ u16 Wlds[128 * 136];
  int t = threadIdx.x;
  int base = blockIdx.x * 64;
#pragma unroll
  for (int i = 0; i < 8; ++i) {
    int idx = (i * 256 + t) * 8;
    int n = idx >> 7, k = idx & 127;
    uint4 v = *(const uint4*)(W0t + idx);
    *(uint4*)(Wlds + n * 136 + k) = v;
  }
#pragma unroll
  for (int i = 0; i < 4; ++i) {
    int idx = (i * 256 + t) * 8;
    int r = idx >> 7, k = idx & 127;
    int row = base + r;
    uint4 v = make_uint4(0, 0, 0, 0);
    if (row < M) v = *(const uint4*)(A + (size_t)row * 128 + k);
    *(uint4*)(Alds + r * 136 + k) = v;
  }
  __syncthreads();
  int wave = t >> 6, lane = t & 63;
  int m = lane & 15, quad = lane >> 4;
  int arow = wave * 16 + m;
  bfrag a[4];
#pragma unroll
  for (int ks = 0; ks < 4; ++ks)
    a[ks] = *(const bfrag*)(Alds + arow * 136 + ks * 32 + quad * 8);
  f32x4 acc0[8], acc1[8];
#pragma unroll
  for (int nt = 0; nt < 8; ++nt) { acc0[nt] = (f32x4){0,0,0,0}; acc1[nt] = (f32x4){0,0,0,0}; }
#pragma unroll
  for (int nt = 0; nt < 8; ++nt) {
    int n = nt * 16 + m;
#pragma unroll
    for (int ks = 0; ks < 4; ++ks) {
      bfrag b = *(const bfrag*)(Wlds + n * 136 + ks * 32 + quad * 8);
      acc0[nt] = __builtin_amdgcn_mfma_f32_16x16x32_bf16(a[ks], b, acc0[nt], 0, 0, 0);
    }
  }
  __syncthreads();
#pragma unroll
  for (int i = 0; i < 8; ++i) {
    int idx = (i * 256 + t) * 8;
    int n = idx >> 7, k = idx & 127;
    uint4 v = *(const uint4*)(W1t + idx);
    *(uint4*)(Wlds + n * 136 + k) = v;
  }
  __syncthreads();
#pragma unroll
  for (int nt = 0; nt < 8; ++nt) {
    int n = nt * 16 + m;
#pragma unroll
    for (int ks = 0; ks < 4; ++ks) {
      bfrag b = *(const bfrag*)(Wlds + n * 136 + ks * 32 + quad * 8);
      acc1[nt] = __builtin_amdgcn_mfma_f32_16x16x32_bf16(a[ks], b, acc1[nt], 0, 0, 0);
    }
  }
#pragma unroll
  for (int nt = 0; nt < 8; ++nt) {
    int col = nt * 16 + m;
#pragma unroll
    for (int r = 0; r < 4; ++r) {
      int row = base + wave * 16 + quad * 4 + r;
      if (row < M) {
        float v0 = acc0[nt][r];
        if (bias0) v0 += bias0[col];
        C0[(size_t)row * 128 + col] = f2b(v0);
        C1[(size_t)row * 128 + col] = f2b(acc1[nt][r]);
      }
    }
  }
}

// ---------- penta MFMA GEMM: h = relu(A@W2 + deg*bias); G_k = h @ W_k (k=0..3) ----------
__global__ __launch_bounds__(256) void gemm_mfma_penta(
    const u16* __restrict__ A, const u16* __restrict__ W2t, const u16* __restrict__ Wt4,
    const float* __restrict__ bias, const int* __restrict__ degi,
    u16* __restrict__ G0, u16* __restrict__ G1,
    u16* __restrict__ G2, u16* __restrict__ G3, int M) {
  __shared__ u16 Alds[64 * 136];
  __shared__ u16 Wlds[128 * 136];
  int t = threadIdx.x;
  int base = blockIdx.x * 64;
#pragma unroll
  for (int i = 0; i < 8; ++i) {
    int idx = (i * 256 + t) * 8;
    int n = idx >> 7, k = idx & 127;
    uint4 v = *(const uint4*)(W2t + idx);
    *(uint4*)(Wlds + n * 136 + k) = v;
  }
#pragma unroll
  for (int i = 0; i < 4; ++i) {
    int idx = (i * 256 + t) * 8;
    int r = idx >> 7, k = idx & 127;
    int row = base + r;
    uint4 v = make_uint4(0, 0, 0, 0);
    if (row < M) v = *(const uint4*)(A + (size_t)row * 128 + k);
    *(uint4*)(Alds + r * 136 + k) = v;
  }
  __syncthreads();
  int wave = t >> 6, lane = t & 63;
  int m = lane & 15, quad = lane >> 4;
  int arow = wave * 16 + m;
  bfrag a[4];
#pragma unroll
  for (int ks = 0; ks < 4; ++ks)
    a[ks] = *(const bfrag*)(Alds + arow * 136 + ks * 32 + quad * 8);
  {
    f32x4 acc[8];
#pragma unroll
    for (int nt = 0; nt < 8; ++nt) acc[nt] = (f32x4){0.f, 0.f, 0.f, 0.f};
#pragma unroll
    for (int nt = 0; nt < 8; ++nt) {
      int n = nt * 16 + m;
#pragma unroll
      for (int ks = 0; ks < 4; ++ks) {
        bfrag b = *(const bfrag*)(Wlds + n * 136 + ks * 32 + quad * 8);
        acc[nt] = __builtin_amdgcn_mfma_f32_16x16x32_bf16(a[ks], b, acc[nt], 0, 0, 0);
      }
    }
#pragma unroll
    for (int nt = 0; nt < 8; ++nt) {
      int col = nt * 16 + m;
#pragma unroll
      for (int r = 0; r < 4; ++r) {
        int lrow = wave * 16 + quad * 4 + r;
        int row = base + lrow;
        float v = 0.f;
        if (row < M) v = fmaxf(acc[nt][r] + bias[col] * (float)degi[row], 0.f);
        Alds[lrow * 136 + col] = f2b(v);   // own wave's slab; in-wave DS ordering
      }
    }
  }
#pragma unroll
  for (int ks = 0; ks < 4; ++ks)
    a[ks] = *(const bfrag*)(Alds + arow * 136 + ks * 32 + quad * 8);
#pragma unroll
  for (int mat = 0; mat < 4; ++mat) {
    __syncthreads();
#pragma unroll
    for (int i = 0; i < 8; ++i) {
      int idx = (i * 256 + t) * 8;
      int n = idx >> 7, k = idx & 127;
      uint4 v = *(const uint4*)(Wt4 + mat * 16384 + idx);
      *(uint4*)(Wlds + n * 136 + k) = v;
    }
    __syncthreads();
    f32x4 acc[8];
#pragma unroll
    for (int nt = 0; nt < 8; ++nt) acc[nt] = (f32x4){0.f, 0.f, 0.f, 0.f};
#pragma unroll
    for (int nt = 0; nt < 8; ++nt) {
      int n = nt * 16 + m;
#pragma unroll
      for (int ks = 0; ks < 4; ++ks) {
        bfrag b = *(const bfrag*)(Wlds + n * 136 + ks * 32 + quad * 8);
        acc[nt] = __builtin_amdgcn_mfma_f32_16x16x32_bf16(a[ks], b, acc[nt], 0, 0, 0);
      }
    }
    u16* G = (mat == 0) ? G0 : (mat == 1) ? G1 : (mat == 2) ? G2 : G3;
#pragma unroll
    for (int nt = 0; nt < 8; ++nt) {
      int col = nt * 16 + m;
#pragma unroll
      for (int r = 0; r < 4; ++r) {
        int row = base + wave * 16 + quad * 4 + r;
        if (row < M) G[(size_t)row * 128 + col] = f2b(acc[nt][r]);
      }
    }
  }
}

// ---------- VALU GEMM (final 128->16) ----------
__global__ __launch_bounds__(128) void gemm_tail(
    const u16* __restrict__ A, const float* __restrict__ W, float* __restrict__ Cout,
    const float* __restrict__ bias, const int* __restrict__ degi, int M) {
  const int ROWS = 8;
  int t = threadIdx.x;
  int base = blockIdx.x * ROWS;
  __shared__ float Al[ROWS * 128];
  for (int i = t; i < ROWS * 128; i += 128) {
    int r = i >> 7, k = i & 127;
    int row = base + r;
    Al[i] = (row < M) ? b2f(A[(size_t)row * 128 + k]) : 0.f;
  }
  __syncthreads();
  int r = t >> 4, u = t & 15;
  int row = base + r;
  float acc = 0.f;
  for (int k = 0; k < 128; ++k) acc += Al[r * 128 + k] * W[k * 16 + u];
  if (row < M) {
    Cout[(size_t)row * 16 + u] = acc + bias[u] * (float)degi[row];
  }
}

// ---------- per-edge bodies (unified int4 records in LDS) ----------
__device__ __forceinline__ void tag_edge(const int4* __restrict__ rr, int j,
    const u16* __restrict__ g, int lane, float& x0, float& x1) {
  int4 r = rr[j];
  int s = rfl(r.x); float w = __uint_as_float(rfl(r.z));
  u32 h = *((const u32*)(g + (size_t)s * 128) + lane);
  x0 += w * bflo(h); x1 += w * bfhi(h);
}
__device__ __forceinline__ void ea_edge(const int4* __restrict__ rr, int j,
    const u16* __restrict__ q, const u8* __restrict__ P8, int lane,
    float pb0, float pb1, float& x0, float& x1) {
  int4 r = rr[j];
  int s = rfl(r.x), i = rfl(r.y);
  u32 qv = *((const u32*)(q + (size_t)s * 128) + lane);
  u16 pv = *((const u16*)(P8 + (size_t)i * 128) + lane);
  f32x2 pf = __builtin_amdgcn_cvt_pk_f32_fp8((int)pv, false);
  x0 += fmaxf(pb0 + bflo(qv) + pf.x, 0.f);
  x1 += fmaxf(pb1 + bfhi(qv) + pf.y, 0.f);
}

// ---------- TAG gather v9: 1 node/wave, LDS-staged 64-record batches, 8-edge unroll ----------
template<bool FINAL>
__global__ __launch_bounds__(256) void tag_gather9(
    const u16* __restrict__ g, const u16* __restrict__ Cin,
    const float* __restrict__ bias, const float* __restrict__ dis,
    const int* __restrict__ rowptr, const int4* __restrict__ cr,
    u16* __restrict__ out, int N) {
  __shared__ int4 recs[4][64];
  int wave = threadIdx.x >> 6, lane = threadIdx.x & 63;
  int node = blockIdx.x * 4 + wave;
  if (node >= N) return;
  int e0 = rfl(rowptr[node]);
  int e1 = rfl(rowptr[node + 1]);
  int4* rr = recs[wave];
  float a0 = 0, a1 = 0, b0 = 0, b1 = 0;
  for (int base = e0; base < e1; base += 64) {
    if (base + lane < e1) rr[lane] = cr[base + lane];
    int cnt = min(64, e1 - base);
    int j = 0;
    for (; j + 8 <= cnt; j += 8) {
      tag_edge(rr, j + 0, g, lane, a0, a1);
      tag_edge(rr, j + 1, g, lane, b0, b1);
      tag_edge(rr, j + 2, g, lane, a0, a1);
      tag_edge(rr, j + 3, g, lane, b0, b1);
      tag_edge(rr, j + 4, g, lane, a0, a1);
      tag_edge(rr, j + 5, g, lane, b0, b1);
      tag_edge(rr, j + 6, g, lane, a0, a1);
      tag_edge(rr, j + 7, g, lane, b0, b1);
    }
    for (; j + 2 <= cnt; j += 2) {
      tag_edge(rr, j + 0, g, lane, a0, a1);
      tag_edge(rr, j + 1, g, lane, b0, b1);
    }
    if (j < cnt) tag_edge(rr, j, g, lane, a0, a1);
  }
  float dn = dis[node];
  float r0v = dn * (a0 + b0), r1v = dn * (a1 + b1);
  u32 cin = *((const u32*)(Cin + (size_t)node * 128) + lane);
  r0v += bflo(cin); r1v += bfhi(cin);
  if (FINAL) {
    float2 bv = *(const float2*)(bias + 2 * lane);
    r0v = fmaxf(r0v + bv.x, 0.f);
    r1v = fmaxf(r1v + bv.y, 0.f);
  }
  *((u32*)(out + (size_t)node * 128) + lane) = packb2(r0v, r1v);
}

// ---------- EA gather v10: 1 node/wave, LDS-staged records, 8-edge unroll, fp8 P ----------
__global__ __launch_bounds__(256) void ea_gather10(
    const u16* __restrict__ pb, const u16* __restrict__ q,
    const u8* __restrict__ P /*fp8 [E,128]*/,
    const int* __restrict__ rowptr, const int4* __restrict__ cr,
    u16* __restrict__ Hsum, int N) {
  __shared__ int4 recs[4][64];
  int wave = threadIdx.x >> 6, lane = threadIdx.x & 63;
  int node = blockIdx.x * 4 + wave;
  if (node >= N) return;
  int e0 = rfl(rowptr[node]);
  int e1 = rfl(rowptr[node + 1]);
  int4* rr = recs[wave];
  u32 pbu = *((const u32*)(pb + (size_t)node * 128) + lane);
  float pb0 = bflo(pbu), pb1 = bfhi(pbu);
  float a0 = 0, a1 = 0, b0 = 0, b1 = 0;
  for (int base = e0; base < e1; base += 64) {
    if (base + lane < e1) rr[lane] = cr[base + lane];
    int cnt = min(64, e1 - base);
    int j = 0;
    for (; j + 8 <= cnt; j += 8) {
      ea_edge(rr, j + 0, q, P, lane, pb0, pb1, a0, a1);
      ea_edge(rr, j + 1, q, P, lane, pb0, pb1, b0, b1);
      ea_edge(rr, j + 2, q, P, lane, pb0, pb1, a0, a1);
      ea_edge(rr, j + 3, q, P, lane, pb0, pb1, b0, b1);
      ea_edge(rr, j + 4, q, P, lane, pb0, pb1, a0, a1);
      ea_edge(rr, j + 5, q, P, lane, pb0, pb1, b0, b1);
      ea_edge(rr, j + 6, q, P, lane, pb0, pb1, a0, a1);
      ea_edge(rr, j + 7, q, P, lane, pb0, pb1, b0, b1);
    }
    for (; j + 2 <= cnt; j += 2) {
      ea_edge(rr, j + 0, q, P, lane, pb0, pb1, a0, a1);
      ea_edge(rr, j + 1, q, P, lane, pb0, pb1, b0, b1);
    }
    if (j < cnt) ea_edge(rr, j, q, P, lane, pb0, pb1, a0, a1);
  }
  *((u32*)(Hsum + (size_t)node * 128) + lane) = packb2(a0 + b0, a1 + b1);
}

extern "C" void kernel_launch(void* const* d_in, const int* in_sizes, int n_in,
                              void* d_out, int out_size, void* d_ws, size_t ws_size,
                              hipStream_t stream) {
  const float* x      = (const float*)d_in[0];
  const float* mask   = (const float*)d_in[1];
  const float* ea     = (const float*)d_in[2];
  const int*   eidx   = (const int*)d_in[3];
  const float* m_w1   = (const float*)d_in[4];
  const float* m_b1   = (const float*)d_in[5];
  const float* m_w2   = (const float*)d_in[6];
  const float* m_b2   = (const float*)d_in[7];
  const float* ea0_w1 = (const float*)d_in[8];
  const float* ea0_b1 = (const float*)d_in[9];
  const float* ea0_w2 = (const float*)d_in[10];
  const float* ea0_b2 = (const float*)d_in[11];
  const float* tag0_w = (const float*)d_in[12];
  const float* tag0_b = (const float*)d_in[13];
  const float* ea1_w1 = (const float*)d_in[14];
  const float* ea1_b1 = (const float*)d_in[15];
  const float* ea1_w2 = (const float*)d_in[16];
  const float* ea1_b2 = (const float*)d_in[17];
  const float* tag1_w = (const float*)d_in[18];
  const float* tag1_b = (const float*)d_in[19];
  const float* ea2_w1 = (const float*)d_in[20];
  const float* ea2_b1 = (const float*)d_in[21];
  const float* ea2_w2 = (const float*)d_in[22];
  const float* ea2_b2 = (const float*)d_in[23];

  const int N = in_sizes[0] / 16;   // 20000
  const int E = in_sizes[2] / 16;   // 160000
  const int E2 = 2 * E;
  const int NB = (N + 255) / 256;

  char* w = (char*)d_ws;
  auto alloc = [&](size_t bytes) { char* p = w; w += (bytes + 255) & ~(size_t)255; return p; };
  int*   degi   = (int*)alloc((size_t)N * 4);
  int*   cursor = (int*)alloc((size_t)N * 4);
  int*   rowptr = (int*)alloc((size_t)(N + 1) * 4);
  int*   bsum   = (int*)alloc((size_t)256 * 4);
  float* dis    = (float*)alloc((size_t)N * 4);
  int4*  cr     = (int4*)alloc((size_t)E2 * 16);
  u16*   X0     = (u16*)alloc((size_t)N * 128 * 2);
  u16*   X1     = (u16*)alloc((size_t)N * 128 * 2);
  u16*   X2     = (u16*)alloc((size_t)N * 128 * 2);
  u16*   G0     = (u16*)alloc((size_t)N * 128 * 2);
  u16*   G1     = (u16*)alloc((size_t)N * 128 * 2);
  u16*   G2     = (u16*)alloc((size_t)N * 128 * 2);
  u16*   G3     = (u16*)alloc((size_t)N * 128 * 2);
  u16*   Wt     = (u16*)alloc((size_t)14 * 16384 * 2);
  u8*    P0     = (u8*)alloc((size_t)E * 128);
  u8*    P1     = (u8*)alloc((size_t)E * 128);
  u8*    P2     = (u8*)alloc((size_t)E * 128);
  (void)ws_size; (void)n_in; (void)out_size;

  const int EB = (E + 255) / 256;      // 625 proj chunks per table
  const int PB = 3 * EB;               // 1875 proj blocks
  const int CB = (E + 255) / 256;      // 625 count blocks
  const int FB = (E2 + 255) / 256;     // 1250 fill blocks
  const int HB = (N + 15) / 16;        // 1250 head blocks
  const int gm = (N + 63) / 64;
  const int g4 = (N + 3) / 4;
  const int gb = (N + 7) / 8;

  u16* WT_ea0w2  = Wt + 0 * 16384;
  u16* WT_tag0   = Wt + 1 * 16384;
  u16* WT_ea1d   = Wt + 5 * 16384;
  u16* WT_ea1s   = Wt + 6 * 16384;
  u16* WT_ea1w2  = Wt + 7 * 16384;
  u16* WT_tag1   = Wt + 8 * 16384;
  u16* WT_ea2d   = Wt + 12 * 16384;
  u16* WT_ea2s   = Wt + 13 * 16384;

  // ---- prologue: proj + count + weight prep (degi zeroed by memset) ----
  hipMemsetAsync(degi, 0, (size_t)N * 4, stream);
  prologue<<<PB + CB + 112, 256, 0, stream>>>(ea, eidx, ea0_w1, ea0_w2, tag0_w,
                                              ea1_w1, ea1_w2, tag1_w, ea2_w1,
                                              P0, P1, P2, degi, Wt, E, N, PB, CB, EB);
  scan1<<<NB, 256, 0, stream>>>(degi, bsum, N);
  scan23<<<NB, 256, 0, stream>>>(degi, bsum, rowptr, cursor, dis, NB, N);
  fill_head<<<FB + HB, 256, 0, stream>>>(eidx, cursor, dis, cr, E,
                                         mask, x, m_w1, m_b1, m_w2, m_b2,
                                         ea0_w1, ea0_b1, X0, X1, N, FB);

  // ---- EA0 + TAG0 GEMMs fused ----
  ea_gather10<<<g4, 256, 0, stream>>>(X0, X1, P0, rowptr, cr, X2, N);
  gemm_mfma_penta<<<gm, 256, 0, stream>>>(X2, WT_ea0w2, WT_tag0, ea0_b2, degi,
                                          G0, G1, G2, G3, N);
  tag_gather9<false><<<g4, 256, 0, stream>>>(G3, G2, nullptr, dis, rowptr, cr, X1, N);
  tag_gather9<false><<<g4, 256, 0, stream>>>(X1, G1, nullptr, dis, rowptr, cr, X2, N);
  tag_gather9<true><<<g4, 256, 0, stream>>>(X2, G0, tag0_b, dis, rowptr, cr, X0, N);  // h2 -> X0

  // ---- EA1 + TAG1 ----
  gemm_mfma_dual<<<gm, 256, 0, stream>>>(X0, WT_ea1d, WT_ea1s, X1, X2, ea1_b1, N);
  ea_gather10<<<g4, 256, 0, stream>>>(X1, X2, P1, rowptr, cr, G0, N);
  gemm_mfma_penta<<<gm, 256, 0, stream>>>(G0, WT_ea1w2, WT_tag1, ea1_b2, degi,
                                          G0, G1, G2, G3, N);   // in-place A=G0 safe
  tag_gather9<false><<<g4, 256, 0, stream>>>(G3, G2, nullptr, dis, rowptr, cr, X1, N);
  tag_gather9<false><<<g4, 256, 0, stream>>>(X1, G1, nullptr, dis, rowptr, cr, X2, N);
  tag_gather9<true><<<g4, 256, 0, stream>>>(X2, G0, tag1_b, dis, rowptr, cr, X0, N);  // h4 -> X0

  // ---- EA2 (final, out 16, fp32) ----
  gemm_mfma_dual<<<gm, 256, 0, stream>>>(X0, WT_ea2d, WT_ea2s, X1, X2, ea2_b1, N);
  ea_gather10<<<g4, 256, 0, stream>>>(X1, X2, P2, rowptr, cr, G0, N);
  gemm_tail<<<gb, 128, 0, stream>>>(G0, ea2_w2, (float*)d_out, ea2_b2, degi, N);
}